// Round 12
// baseline (6533.590 us; speedup 1.0000x reference)
//
#include <hip/hip_runtime.h>
#include <math.h>

#define B_ 8
#define S_ 900
#define V_ 11
#define H_ 512
#define NH_ 8
#define HD_ 64
#define INNER_ 1536
#define STEPS_ 2
#define NTOK (B_*S_)
#define EPS_ 1e-5f
#define THETA_ 10000.0f
#define ESCALE_ 22.627416997969522f
#define SCALE_ 0.125f
#define PT_ 70   // attention LDS pitch (ushorts): 140B = 35 banks, <=2-way conflicts (free)

typedef __attribute__((ext_vector_type(8))) short bh8;
typedef __attribute__((ext_vector_type(4))) float f32x4;
typedef __attribute__((ext_vector_type(4))) unsigned short us4;

union bfu { bh8 v; unsigned short s[8]; us4 q[2]; };

__device__ inline unsigned short f2bf(float x) {
  unsigned u = __builtin_bit_cast(unsigned, x);
  return (unsigned short)((u + 0x7FFFu + ((u >> 16) & 1u)) >> 16);
}
__device__ inline float b2f(unsigned short s) {
  return __builtin_bit_cast(float, (unsigned)s << 16);
}

// async global->LDS, 16B per lane; LDS dest = wave-uniform base + lane*16
__device__ inline void gld16(const unsigned short* g, unsigned short* l) {
  __builtin_amdgcn_global_load_lds(
      (const __attribute__((address_space(1))) void*)(g),
      (__attribute__((address_space(3))) void*)(l), 16, 0, 0);
}

__device__ inline bh8 lds16(const unsigned short* p) {
  bfu u;
  u.q[0] = *(const us4*)p;
  u.q[1] = *(const us4*)(p + 4);
  return u.v;
}
__device__ inline void sts16(unsigned short* p, bfu u) {
  *(us4*)p = u.q[0];
  *(us4*)(p + 4) = u.q[1];
}

__device__ inline float wave_sum64(float x) {
#pragma unroll
  for (int off = 32; off > 0; off >>= 1) x += __shfl_xor(x, off, 64);
  return x;
}

__device__ inline float quad_sum(float x) {
  x += __shfl_xor(x, 1, 64);
  x += __shfl_xor(x, 2, 64);
  return x;
}

// ---------------- small kernels ----------------

__global__ void k_zero(float* p, int n) {
  int i = blockIdx.x * blockDim.x + threadIdx.x;
  if (i < n) p[i] = 0.f;
}

__global__ void k_rope_tables(float* cs, float* sn) {
  int idx = blockIdx.x * blockDim.x + threadIdx.x;
  if (idx >= S_ * 32) return;
  int s = idx >> 5, i = idx & 31;
  float freq = powf(THETA_, -(float)i / 32.0f);
  float ang = (float)s * freq;
  cs[idx] = cosf(ang);
  sn[idx] = sinf(ang);
}

__global__ void k_softmax_logits(const float* __restrict__ logits, float* __restrict__ P) {
  int t = blockIdx.x * blockDim.x + threadIdx.x;
  if (t >= NTOK) return;
  float x[V_];
  float m = -1e30f;
#pragma unroll
  for (int v = 0; v < V_; ++v) { x[v] = logits[t * V_ + v]; m = fmaxf(m, x[v]); }
  float ssum = 0.f;
#pragma unroll
  for (int v = 0; v < V_; ++v) { x[v] = expf(x[v] - m); ssum += x[v]; }
  float inv = 1.f / ssum;
#pragma unroll
  for (int v = 0; v < V_; ++v) P[t * V_ + v] = x[v] * inv;
}

// h0 -> fp32 + bf16
__global__ void k_h0(const float* __restrict__ P, const float* __restrict__ E,
                     const int* __restrict__ inp, float* __restrict__ h0,
                     unsigned short* __restrict__ h016) {
  int t = blockIdx.x;
  int tid = threadIdx.x;
  __shared__ float p[V_];
  __shared__ int iw;
  if (tid < V_) p[tid] = P[t * V_ + tid];
  if (tid == 0) iw = inp[t];
  __syncthreads();
  for (int h = tid; h < H_; h += blockDim.x) {
    float acc = E[iw * H_ + h];
#pragma unroll
    for (int v = 0; v < V_; ++v) acc += p[v] * E[v * H_ + h];
    float val = ESCALE_ * acc;
    h0[(size_t)t * H_ + h] = val;
    h016[(size_t)t * H_ + h] = f2bf(val);
  }
}

__global__ void k_gfill(const float* __restrict__ ew, float* __restrict__ G) {
  int idx = blockIdx.x * blockDim.x + threadIdx.x;
  if (idx < NTOK * H_) G[idx] = ew[idx & (H_ - 1)];
}

// fp32 -> bf16 cast, 8 elems/thread
__global__ void k_cast8(const float* __restrict__ X, unsigned short* __restrict__ Y, int n8) {
  int i = blockIdx.x * blockDim.x + threadIdx.x;
  if (i >= n8) return;
  const float4* p = (const float4*)(X + (size_t)i * 8);
  float4 a = p[0], b = p[1];
  bfu o;
  o.s[0] = f2bf(a.x); o.s[1] = f2bf(a.y); o.s[2] = f2bf(a.z); o.s[3] = f2bf(a.w);
  o.s[4] = f2bf(b.x); o.s[5] = f2bf(b.y); o.s[6] = f2bf(b.z); o.s[7] = f2bf(b.w);
  *(bh8*)(Y + (size_t)i * 8) = o.v;
}

// ---------------- weight transpose-convert: W[K][N] fp32 -> WT[N][K] bf16 ----------------

__global__ void k_wt(const float* __restrict__ W, unsigned short* __restrict__ WT, int K, int N) {
  __shared__ float t[32][33];
  int k0 = blockIdx.y * 32, n0 = blockIdx.x * 32;
  int tx = threadIdx.x, ty = threadIdx.y;
#pragma unroll
  for (int i = 0; i < 4; ++i)
    t[ty + 8 * i][tx] = W[(size_t)(k0 + ty + 8 * i) * N + n0 + tx];
  __syncthreads();
#pragma unroll
  for (int i = 0; i < 4; ++i)
    WT[(size_t)(n0 + ty + 8 * i) * K + k0 + tx] = f2bf(t[tx][ty + 8 * i]);
}

// ---------------- MFMA GEMM: C[M,N] = A[M,K] @ B^T (A,B bf16; B stored [N][K]) ----------------

template <int TM, int SILU_A, int ADD, int CBF, int ROPE, int SILUBWD>
__global__ __launch_bounds__(256) void k_gemm(const unsigned short* __restrict__ A16,
                                              const unsigned short* __restrict__ Bt,
                                              const float* __restrict__ Dm,
                                              float* __restrict__ Cf,
                                              unsigned short* __restrict__ C16,
                                              unsigned short* __restrict__ GU,
                                              const float* __restrict__ Cs,
                                              const float* __restrict__ Sn,
                                              int M, int N, int K, int lda) {
  __shared__ unsigned short As[TM][32];
  __shared__ unsigned short Bs[128][32];
  constexpr int FR = TM / 32;
  int tid = threadIdx.x;
  int m0 = blockIdx.y * TM, n0 = blockIdx.x * 128;
  int wid = tid >> 6, lane = tid & 63;
  int wr = (wid >> 1) * (FR * 16), wc = (wid & 1) * 64;
  int lr = lane & 15, lg = lane >> 4;
  int srow = lane >> 2, sck = (lane & 3) * 8;
  f32x4 acc[FR][4] = {};
  for (int k0 = 0; k0 < K; k0 += 32) {
    __syncthreads();
#pragma unroll
    for (int half = 0; half < TM / 64; ++half) {
      if (SILU_A) {
        int row = (tid >> 2) + 64 * half;
        int ck = (tid & 3) * 8;
        int gr = m0 + row; gr = gr < M ? gr : M - 1;
        const unsigned short* src = &A16[(size_t)gr * lda + k0 + ck];
        bfu pa;
#pragma unroll
        for (int j = 0; j < 8; ++j) {
          float g = b2f(src[j]), u = b2f(src[INNER_ + j]);
          pa.s[j] = f2bf((g / (1.f + __expf(-g))) * u);
        }
        *(bh8*)&As[row][ck] = pa.v;
      } else {
        int gr = m0 + 64 * half + wid * 16 + srow; gr = gr < M ? gr : M - 1;
        gld16(&A16[(size_t)gr * lda + k0 + sck], &As[64 * half + wid * 16][0]);
      }
    }
#pragma unroll
    for (int i = 0; i < 2; ++i) {
      int bb = wid * 2 + i;
      gld16(&Bt[(size_t)(n0 + bb * 16 + srow) * K + k0 + sck], &Bs[bb * 16][0]);
    }
    __syncthreads();
    bh8 av[FR], bv[4];
#pragma unroll
    for (int fr = 0; fr < FR; ++fr) av[fr] = *(const bh8*)&As[wr + fr * 16 + lr][lg * 8];
#pragma unroll
    for (int fc = 0; fc < 4; ++fc) bv[fc] = *(const bh8*)&Bs[wc + fc * 16 + lr][lg * 8];
#pragma unroll
    for (int fr = 0; fr < FR; ++fr)
#pragma unroll
      for (int fc = 0; fc < 4; ++fc)
        acc[fr][fc] = __builtin_amdgcn_mfma_f32_16x16x32_bf16(av[fr], bv[fc], acc[fr][fc], 0, 0, 0);
  }
  bool rope_on = ROPE && (((n0 + wc) >> 6) < 16);
#pragma unroll
  for (int fr = 0; fr < FR; ++fr) {
    int r0 = m0 + wr + fr * 16 + lg * 4;
#pragma unroll
    for (int i = 0; i < 4; ++i) {
      int gr = r0 + i;
      if (gr >= M) continue;
      float c0 = 1.f, s0 = 0.f, c1 = 1.f, s1 = 0.f;
      if (ROPE) {
        if (rope_on) {
          int s = gr % S_;
          c0 = Cs[s * 32 + lr];      s0 = Sn[s * 32 + lr];
          c1 = Cs[s * 32 + 16 + lr]; s1 = Sn[s * 32 + 16 + lr];
        }
      }
#pragma unroll
      for (int fc = 0; fc < 4; ++fc) {
        int gc = n0 + wc + fc * 16 + lr;
        float out = acc[fr][fc][i];
        if (ROPE) {
          float part = acc[fr][fc ^ 2][i];
          float cc = (fc & 1) ? c1 : c0;
          float ss = (fc & 1) ? s1 : s0;
          out = (fc < 2) ? (out * cc - part * ss) : (out * cc + part * ss);
        }
        if (ADD) out += Dm[(size_t)gr * N + gc];
        if (SILUBWD) {
          size_t gb = (size_t)gr * (size_t)(2 * INNER_) + gc;
          float g = b2f(GU[gb]), u = b2f(GU[gb + INNER_]);
          float sig = 1.f / (1.f + __expf(-g));
          GU[gb] = f2bf(out * u * sig * (1.f + g * (1.f - sig)));
          GU[gb + INNER_] = f2bf(out * g * sig);
        } else if (CBF) {
          C16[(size_t)gr * N + gc] = f2bf(out);
        } else {
          Cf[(size_t)gr * N + gc] = out;
        }
      }
    }
  }
}

// ---------------- MFMA flash attention (bf16 QKV, bf16 O), prefetch-pipelined ----------------
// QKV16 layout [t][24][64] ushorts: Q at slot h (roped), K at 8+h (roped), V at 16+h.

__global__ __launch_bounds__(256) void k_attn_fwd3(const unsigned short* __restrict__ QKV,
                                                   unsigned short* __restrict__ AO,
                                                   float* __restrict__ MB,
                                                   float* __restrict__ LB) {
  __shared__ unsigned short Ks[64][PT_];
  __shared__ unsigned short VT[64][PT_];
  __shared__ unsigned short Ps[4][16][PT_];
  int tid = threadIdx.x;
  int h = blockIdx.y, b = blockIdx.z;
  int w = tid >> 6, lane = tid & 63;
  int lr = lane & 15, lg = lane >> 4;
  int q0 = blockIdx.x * 64 + w * 16;
  int sr = tid >> 2, sc0 = (tid & 3) * 16;          // K stage coords
  int vd0 = (tid & 15) * 4, vk0 = (tid >> 4) * 4;   // VT stage coords

  bh8 qf[2];
  {
    int qr = q0 + lr; if (qr >= S_) qr = S_ - 1;
    const unsigned short* qp = &QKV[((size_t)(b * S_ + qr) * 24 + h) * 64 + lg * 8];
    qf[0] = *(const bh8*)qp;
    qf[1] = *(const bh8*)(qp + 32);
  }
  f32x4 accO[4] = {};
  float m[4], lsum[4];
#pragma unroll
  for (int i = 0; i < 4; ++i) { m[i] = -1e30f; lsum[i] = 0.f; }

  // prefetch tile 0
  bfu kA, kB;
  us4 vR[4];
  {
    int src = sr;
    size_t ts = (size_t)b * S_ + (src < S_ ? src : S_ - 1);
    const unsigned short* gp = &QKV[(ts * 24 + 8 + h) * 64 + sc0];
    kA.v = *(const bh8*)gp;
    kB.v = *(const bh8*)(gp + 8);
#pragma unroll
    for (int j = 0; j < 4; ++j) {
      int s2 = vk0 + j;
      size_t t2 = (size_t)b * S_ + (s2 < S_ ? s2 : S_ - 1);
      vR[j] = *(const us4*)&QKV[(t2 * 24 + 16 + h) * 64 + vd0];
    }
  }

  for (int kt = 0; kt < S_; kt += 64) {
    __syncthreads();
    sts16(&Ks[sr][sc0], kA);
    sts16(&Ks[sr][sc0 + 8], kB);
#pragma unroll
    for (int dd = 0; dd < 4; ++dd) {
      us4 pk = {vR[0][dd], vR[1][dd], vR[2][dd], vR[3][dd]};
      *(us4*)&VT[vd0 + dd][vk0] = pk;
    }
    if (kt + 64 < S_) {  // prefetch next tile
      int src = kt + 64 + sr;
      size_t ts = (size_t)b * S_ + (src < S_ ? src : S_ - 1);
      const unsigned short* gp = &QKV[(ts * 24 + 8 + h) * 64 + sc0];
      kA.v = *(const bh8*)gp;
      kB.v = *(const bh8*)(gp + 8);
#pragma unroll
      for (int j = 0; j < 4; ++j) {
        int s2 = kt + 64 + vk0 + j;
        size_t t2 = (size_t)b * S_ + (s2 < S_ ? s2 : S_ - 1);
        vR[j] = *(const us4*)&QKV[(t2 * 24 + 16 + h) * 64 + vd0];
      }
    }
    __syncthreads();
    f32x4 accS[4] = {};
#pragma unroll
    for (int ks = 0; ks < 2; ++ks)
#pragma unroll
      for (int fk = 0; fk < 4; ++fk)
        accS[fk] = __builtin_amdgcn_mfma_f32_16x16x32_bf16(qf[ks], lds16(&Ks[fk * 16 + lr][ks * 32 + lg * 8]), accS[fk], 0, 0, 0);
    float sc[4][4], pmax[4];
#pragma unroll
    for (int i = 0; i < 4; ++i) pmax[i] = -1e30f;
#pragma unroll
    for (int fk = 0; fk < 4; ++fk)
#pragma unroll
      for (int i = 0; i < 4; ++i) {
        float s = accS[fk][i] * SCALE_;
        if (kt + fk * 16 + lr >= S_) s = -1e30f;
        sc[fk][i] = s;
        pmax[i] = fmaxf(pmax[i], s);
      }
#pragma unroll
    for (int i = 0; i < 4; ++i) {
      float v = pmax[i];
      v = fmaxf(v, __shfl_xor(v, 1, 64));
      v = fmaxf(v, __shfl_xor(v, 2, 64));
      v = fmaxf(v, __shfl_xor(v, 4, 64));
      v = fmaxf(v, __shfl_xor(v, 8, 64));
      pmax[i] = v;
    }
    float psum[4];
#pragma unroll
    for (int i = 0; i < 4; ++i) {
      float mn = fmaxf(m[i], pmax[i]);
      float eo = __expf(m[i] - mn);
      m[i] = mn;
      lsum[i] *= eo;
#pragma unroll
      for (int fd = 0; fd < 4; ++fd) accO[fd][i] *= eo;
      psum[i] = 0.f;
    }
#pragma unroll
    for (int fk = 0; fk < 4; ++fk)
#pragma unroll
      for (int i = 0; i < 4; ++i) {
        float p = __expf(sc[fk][i] - m[i]);
        sc[fk][i] = p;
        psum[i] += p;
      }
#pragma unroll
    for (int i = 0; i < 4; ++i) {
      float v = psum[i];
      v += __shfl_xor(v, 1, 64);
      v += __shfl_xor(v, 2, 64);
      v += __shfl_xor(v, 4, 64);
      v += __shfl_xor(v, 8, 64);
      lsum[i] += v;
    }
#pragma unroll
    for (int fk = 0; fk < 4; ++fk)
#pragma unroll
      for (int i = 0; i < 4; ++i)
        Ps[w][lg * 4 + i][fk * 16 + lr] = f2bf(sc[fk][i]);
#pragma unroll
    for (int ks = 0; ks < 2; ++ks) {
      bh8 ap = lds16(&Ps[w][lr][ks * 32 + lg * 8]);
#pragma unroll
      for (int fd = 0; fd < 4; ++fd)
        accO[fd] = __builtin_amdgcn_mfma_f32_16x16x32_bf16(ap, lds16(&VT[fd * 16 + lr][ks * 32 + lg * 8]), accO[fd], 0, 0, 0);
    }
  }
#pragma unroll
  for (int i = 0; i < 4; ++i) {
    int q = q0 + lg * 4 + i;
    if (q < S_) {
      float linv = 1.f / lsum[i];
      size_t obase = (size_t)(b * S_ + q) * H_ + h * 64;
#pragma unroll
      for (int fd = 0; fd < 4; ++fd) AO[obase + fd * 16 + lr] = f2bf(accO[fd][i] * linv);
      if (lr == 0) {
        MB[((size_t)b * NH_ + h) * S_ + q] = m[i];
        LB[((size_t)b * NH_ + h) * S_ + q] = linv;
      }
    }
  }
}

// delta[b,h,q] = dot(dO_row, O_row), both bf16
__global__ __launch_bounds__(256) void k_delta(const unsigned short* __restrict__ O,
                                               const unsigned short* __restrict__ dO,
                                               float* __restrict__ DB) {
  int tid = threadIdx.x;
  int h = blockIdx.y, b = blockIdx.z;
  int r = blockIdx.x * 64 + (tid >> 2), part = tid & 3;
  if (r >= S_) return;
  size_t base = (size_t)(b * S_ + r) * H_ + h * 64 + part * 16;
  bfu o0, o1, d0, d1;
  o0.v = *(const bh8*)&O[base];  o1.v = *(const bh8*)&O[base + 8];
  d0.v = *(const bh8*)&dO[base]; d1.v = *(const bh8*)&dO[base + 8];
  float s = 0.f;
#pragma unroll
  for (int j = 0; j < 8; ++j)
    s += b2f(o0.s[j]) * b2f(d0.s[j]) + b2f(o1.s[j]) * b2f(d1.s[j]);
  s = quad_sum(s);
  if (part == 0) DB[((size_t)b * NH_ + h) * S_ + r] = s;
}

// dQ pass; fused inverse-RoPE on output; prefetch-pipelined
__global__ __launch_bounds__(256) void k_attn_bwd_dq3(const unsigned short* __restrict__ QKV,
                                                      const unsigned short* __restrict__ dO,
                                                      const float* __restrict__ MB,
                                                      const float* __restrict__ LB,
                                                      const float* __restrict__ DB,
                                                      const float* __restrict__ Cs,
                                                      const float* __restrict__ Sn,
                                                      unsigned short* __restrict__ dQKV) {
  __shared__ unsigned short Ks[64][PT_];
  __shared__ unsigned short Vs[64][PT_];
  __shared__ unsigned short KT[64][PT_];
  __shared__ unsigned short Ps[4][16][PT_];
  int tid = threadIdx.x;
  int h = blockIdx.y, b = blockIdx.z;
  int w = tid >> 6, lane = tid & 63;
  int lr = lane & 15, lg = lane >> 4;
  int q0 = blockIdx.x * 64 + w * 16;
  size_t sbase = ((size_t)b * NH_ + h) * S_;
  int sr = tid >> 2, sc0 = (tid & 3) * 16;
  int vd0 = (tid & 15) * 4, vk0 = (tid >> 4) * 4;

  bh8 qf[2], dof[2];
  {
    int qr = q0 + lr; if (qr >= S_) qr = S_ - 1;
    const unsigned short* qp = &QKV[((size_t)(b * S_ + qr) * 24 + h) * 64 + lg * 8];
    const unsigned short* dp = &dO[(size_t)(b * S_ + qr) * H_ + h * 64 + lg * 8];
    qf[0] = *(const bh8*)qp;  qf[1] = *(const bh8*)(qp + 32);
    dof[0] = *(const bh8*)dp; dof[1] = *(const bh8*)(dp + 32);
  }
  float mrow[4], lrow[4], drow[4];
#pragma unroll
  for (int i = 0; i < 4; ++i) {
    int q = q0 + lg * 4 + i; if (q >= S_) q = S_ - 1;
    mrow[i] = MB[sbase + q];
    lrow[i] = LB[sbase + q];
    drow[i] = DB[sbase + q];
  }
  f32x4 accQ[4] = {};

  // prefetch tile 0
  bfu pA{}, pB{}, pC{}, pD{};
  us4 rv[4];
  {
    int src = sr;
    bool vld = src < S_;
    size_t ts = (size_t)b * S_ + (vld ? src : S_ - 1);
    const unsigned short* kp = &QKV[(ts * 24 + 8 + h) * 64 + sc0];
    if (vld) {
      pA.v = *(const bh8*)kp;
      pB.v = *(const bh8*)(kp + 8);
      pC.v = *(const bh8*)(kp + 512);
      pD.v = *(const bh8*)(kp + 520);
    }
#pragma unroll
    for (int j = 0; j < 4; ++j) {
      int s2 = vk0 + j;
      bool v2 = s2 < S_;
      size_t t2 = (size_t)b * S_ + (v2 ? s2 : S_ - 1);
      us4 t = *(const us4*)&QKV[(t2 * 24 + 8 + h) * 64 + vd0];
      if (!v2) t = us4{0, 0, 0, 0};
      rv[j] = t;
    }
  }

  for (int kt = 0; kt < S_; kt += 64) {
    __syncthreads();
    sts16(&Ks[sr][sc0], pA); sts16(&Ks[sr][sc0 + 8], pB);
    sts16(&Vs[sr][sc0], pC); sts16(&Vs[sr][sc0 + 8], pD);
#pragma unroll
    for (int dd = 0; dd < 4; ++dd) {
      us4 pk = {rv[0][dd], rv[1][dd], rv[2][dd], rv[3][dd]};
      *(us4*)&KT[vd0 + dd][vk0] = pk;
    }
    if (kt + 64 < S_) {  // prefetch next
      int src = kt + 64 + sr;
      bool vld = src < S_;
      size_t ts = (size_t)b * S_ + (vld ? src : S_ - 1);
      const unsigned short* kp = &QKV[(ts * 24 + 8 + h) * 64 + sc0];
      pA = bfu{}; pB = bfu{}; pC = bfu{}; pD = bfu{};
      if (vld) {
        pA.v = *(const bh8*)kp;
        pB.v = *(const bh8*)(kp + 8);
        pC.v = *(const bh8*)(kp + 512);
        pD.v = *(const bh8*)(kp + 520);
      }
#pragma unroll
      for (int j = 0; j < 4; ++j) {
        int s2 = kt + 64 + vk0 + j;
        bool v2 = s2 < S_;
        size_t t2 = (size_t)b * S_ + (v2 ? s2 : S_ - 1);
        us4 t = *(const us4*)&QKV[(t2 * 24 + 8 + h) * 64 + vd0];
        if (!v2) t = us4{0, 0, 0, 0};
        rv[j] = t;
      }
    }
    __syncthreads();
    f32x4 aS[4] = {}, aD[4] = {};
#pragma unroll
    for (int ks = 0; ks < 2; ++ks)
#pragma unroll
      for (int fk = 0; fk < 4; ++fk) {
        aS[fk] = __builtin_amdgcn_mfma_f32_16x16x32_bf16(qf[ks], lds16(&Ks[fk * 16 + lr][ks * 32 + lg * 8]), aS[fk], 0, 0, 0);
        aD[fk] = __builtin_amdgcn_mfma_f32_16x16x32_bf16(dof[ks], lds16(&Vs[fk * 16 + lr][ks * 32 + lg * 8]), aD[fk], 0, 0, 0);
      }
#pragma unroll
    for (int fk = 0; fk < 4; ++fk)
#pragma unroll
      for (int i = 0; i < 4; ++i) {
        float p = __expf(aS[fk][i] * SCALE_ - mrow[i]) * lrow[i];
        float ds = p * (aD[fk][i] - drow[i]);
        Ps[w][lg * 4 + i][fk * 16 + lr] = f2bf(ds);
      }
#pragma unroll
    for (int ks = 0; ks < 2; ++ks) {
      bh8 ap = lds16(&Ps[w][lr][ks * 32 + lg * 8]);
#pragma unroll
      for (int fd = 0; fd < 4; ++fd)
        accQ[fd] = __builtin_amdgcn_mfma_f32_16x16x32_bf16(ap, lds16(&KT[fd * 16 + lr][ks * 32 + lg * 8]), accQ[fd], 0, 0, 0);
    }
  }
#pragma unroll
  for (int i = 0; i < 4; ++i) {
    int q = q0 + lg * 4 + i;
    if (q < S_) {
      size_t obase = ((size_t)(b * S_ + q) * 24 + h) * 64;
      float c0 = Cs[q * 32 + lr], s0 = Sn[q * 32 + lr];
      float c1 = Cs[q * 32 + 16 + lr], s1 = Sn[q * 32 + 16 + lr];
#pragma unroll
      for (int fd = 0; fd < 4; ++fd) {
        float x = SCALE_ * accQ[fd][i];
        float p = SCALE_ * accQ[fd ^ 2][i];
        float cc = (fd & 1) ? c1 : c0;
        float ss = (fd & 1) ? s1 : s0;
        float out = (fd < 2) ? (x * cc + p * ss) : (x * cc - p * ss);
        dQKV[obase + fd * 16 + lr] = f2bf(out);
      }
    }
  }
}

// dK + dV pass; fused inverse-RoPE on dK; prefetch-pipelined
__global__ __launch_bounds__(256) void k_attn_bwd_kv3(const unsigned short* __restrict__ QKV,
                                                      const unsigned short* __restrict__ dO,
                                                      const float* __restrict__ MB,
                                                      const float* __restrict__ LB,
                                                      const float* __restrict__ DB,
                                                      const float* __restrict__ Cs,
                                                      const float* __restrict__ Sn,
                                                      unsigned short* __restrict__ dQKV) {
  __shared__ unsigned short Qs[64][PT_];
  __shared__ unsigned short dOs[64][PT_];
  __shared__ unsigned short QT[64][PT_];
  __shared__ unsigned short dOT[64][PT_];
  __shared__ unsigned short Ps[4][16][PT_];
  __shared__ float sM[64], sL[64], sD[64];
  int tid = threadIdx.x;
  int h = blockIdx.y, b = blockIdx.z;
  int w = tid >> 6, lane = tid & 63;
  int lr = lane & 15, lg = lane >> 4;
  int k0w = blockIdx.x * 64 + w * 16;
  size_t sbase = ((size_t)b * NH_ + h) * S_;
  int sr = tid >> 2, sc0 = (tid & 3) * 16;
  int vd0 = (tid & 15) * 4, vk0 = (tid >> 4) * 4;

  bh8 kf[2], vf[2];
  {
    int kr = k0w + lr; if (kr >= S_) kr = S_ - 1;
    const unsigned short* kp = &QKV[((size_t)(b * S_ + kr) * 24 + 8 + h) * 64 + lg * 8];
    kf[0] = *(const bh8*)kp;        kf[1] = *(const bh8*)(kp + 32);
    vf[0] = *(const bh8*)(kp + 512); vf[1] = *(const bh8*)(kp + 544);
  }
  f32x4 accK[4] = {}, accV[4] = {};

  // prefetch tile 0
  bfu pA, pB, pC{}, pD{};
  us4 rq[4], rd[4];
  float stM = 0.f, stL = 0.f, stD = 0.f;
  {
    int src = sr;
    bool vld = src < S_;
    size_t ts = (size_t)b * S_ + (vld ? src : S_ - 1);
    const unsigned short* qp = &QKV[(ts * 24 + h) * 64 + sc0];
    const unsigned short* dp = &dO[ts * H_ + h * 64 + sc0];
    pA.v = *(const bh8*)qp;
    pB.v = *(const bh8*)(qp + 8);
    if (vld) {
      pC.v = *(const bh8*)dp;
      pD.v = *(const bh8*)(dp + 8);
    }
#pragma unroll
    for (int j = 0; j < 4; ++j) {
      int s2 = vk0 + j;
      bool v2 = s2 < S_;
      size_t t2 = (size_t)b * S_ + (v2 ? s2 : S_ - 1);
      rq[j] = *(const us4*)&QKV[(t2 * 24 + h) * 64 + vd0];
      us4 td = *(const us4*)&dO[t2 * H_ + h * 64 + vd0];
      if (!v2) td = us4{0, 0, 0, 0};
      rd[j] = td;
    }
    if (tid < 64) {
      bool v2 = tid < S_;
      int sc = v2 ? tid : S_ - 1;
      stM = MB[sbase + sc];
      stL = LB[sbase + sc];
      stD = v2 ? DB[sbase + sc] : 0.f;
    }
  }

  for (int qt = 0; qt < S_; qt += 64) {
    __syncthreads();
    sts16(&Qs[sr][sc0], pA);  sts16(&Qs[sr][sc0 + 8], pB);
    sts16(&dOs[sr][sc0], pC); sts16(&dOs[sr][sc0 + 8], pD);
#pragma unroll
    for (int dd = 0; dd < 4; ++dd) {
      us4 pq = {rq[0][dd], rq[1][dd], rq[2][dd], rq[3][dd]};
      us4 pd = {rd[0][dd], rd[1][dd], rd[2][dd], rd[3][dd]};
      *(us4*)&QT[vd0 + dd][vk0] = pq;
      *(us4*)&dOT[vd0 + dd][vk0] = pd;
    }
    if (tid < 64) {
      sM[tid] = stM;
      sL[tid] = stL;
      sD[tid] = stD;
    }
    if (qt + 64 < S_) {  // prefetch next
      int src = qt + 64 + sr;
      bool vld = src < S_;
      size_t ts = (size_t)b * S_ + (vld ? src : S_ - 1);
      const unsigned short* qp = &QKV[(ts * 24 + h) * 64 + sc0];
      const unsigned short* dp = &dO[ts * H_ + h * 64 + sc0];
      pA.v = *(const bh8*)qp;
      pB.v = *(const bh8*)(qp + 8);
      pC = bfu{}; pD = bfu{};
      if (vld) {
        pC.v = *(const bh8*)dp;
        pD.v = *(const bh8*)(dp + 8);
      }
#pragma unroll
      for (int j = 0; j < 4; ++j) {
        int s2 = qt + 64 + vk0 + j;
        bool v2 = s2 < S_;
        size_t t2 = (size_t)b * S_ + (v2 ? s2 : S_ - 1);
        rq[j] = *(const us4*)&QKV[(t2 * 24 + h) * 64 + vd0];
        us4 td = *(const us4*)&dO[t2 * H_ + h * 64 + vd0];
        if (!v2) td = us4{0, 0, 0, 0};
        rd[j] = td;
      }
      if (tid < 64) {
        int s2 = qt + 64 + tid;
        bool v2 = s2 < S_;
        int sc = v2 ? s2 : S_ - 1;
        stM = MB[sbase + sc];
        stL = LB[sbase + sc];
        stD = v2 ? DB[sbase + sc] : 0.f;
      }
    }
    __syncthreads();
    f32x4 aS[4] = {}, aD[4] = {};
#pragma unroll
    for (int ks = 0; ks < 2; ++ks)
#pragma unroll
      for (int fq = 0; fq < 4; ++fq) {
        aS[fq] = __builtin_amdgcn_mfma_f32_16x16x32_bf16(kf[ks], lds16(&Qs[fq * 16 + lr][ks * 32 + lg * 8]), aS[fq], 0, 0, 0);
        aD[fq] = __builtin_amdgcn_mfma_f32_16x16x32_bf16(vf[ks], lds16(&dOs[fq * 16 + lr][ks * 32 + lg * 8]), aD[fq], 0, 0, 0);
      }
    float pv[4][4];
#pragma unroll
    for (int fq = 0; fq < 4; ++fq) {
      float mq = sM[fq * 16 + lr], lq = sL[fq * 16 + lr];
#pragma unroll
      for (int i = 0; i < 4; ++i) {
        float p = __expf(aS[fq][i] * SCALE_ - mq) * lq;
        pv[fq][i] = p;
        Ps[w][lg * 4 + i][fq * 16 + lr] = f2bf(p);
      }
    }
#pragma unroll
    for (int qs = 0; qs < 2; ++qs) {
      bh8 ap = lds16(&Ps[w][lr][qs * 32 + lg * 8]);
#pragma unroll
      for (int fd = 0; fd < 4; ++fd)
        accV[fd] = __builtin_amdgcn_mfma_f32_16x16x32_bf16(ap, lds16(&dOT[fd * 16 + lr][qs * 32 + lg * 8]), accV[fd], 0, 0, 0);
    }
#pragma unroll
    for (int fq = 0; fq < 4; ++fq) {
      float dq = sD[fq * 16 + lr];
#pragma unroll
      for (int i = 0; i < 4; ++i)
        Ps[w][lg * 4 + i][fq * 16 + lr] = f2bf(pv[fq][i] * (aD[fq][i] - dq));
    }
#pragma unroll
    for (int qs = 0; qs < 2; ++qs) {
      bh8 ap = lds16(&Ps[w][lr][qs * 32 + lg * 8]);
#pragma unroll
      for (int fd = 0; fd < 4; ++fd)
        accK[fd] = __builtin_amdgcn_mfma_f32_16x16x32_bf16(ap, lds16(&QT[fd * 16 + lr][qs * 32 + lg * 8]), accK[fd], 0, 0, 0);
    }
  }
#pragma unroll
  for (int i = 0; i < 4; ++i) {
    int k = k0w + lg * 4 + i;
    if (k < S_) {
      size_t obase = ((size_t)(b * S_ + k) * 24 + 8 + h) * 64;
      float c0 = Cs[k * 32 + lr], s0 = Sn[k * 32 + lr];
      float c1 = Cs[k * 32 + 16 + lr], s1 = Sn[k * 32 + 16 + lr];
#pragma unroll
      for (int fd = 0; fd < 4; ++fd) {
        float x = SCALE_ * accK[fd][i];
        float p = SCALE_ * accK[fd ^ 2][i];
        float cc = (fd & 1) ? c1 : c0;
        float ss = (fd & 1) ? s1 : s0;
        float out = (fd < 2) ? (x * cc + p * ss) : (x * cc - p * ss);
        dQKV[obase + fd * 16 + lr] = f2bf(out);
        dQKV[obase + 512 + fd * 16 + lr] = f2bf(accV[fd][i]);
      }
    }
  }
}

// ---------------- RMS norm fwd/bwd (dual fp32+bf16 outputs) ----------------

__global__ __launch_bounds__(256) void k_rms_fwd(const float* __restrict__ X, float* __restrict__ Y,
                                                 unsigned short* __restrict__ Y16) {
  int t = blockIdx.x, tid = threadIdx.x;
  float x0 = X[(size_t)t * H_ + tid], x1 = X[(size_t)t * H_ + tid + 256];
  __shared__ float red[256];
  red[tid] = x0 * x0 + x1 * x1;
  __syncthreads();
  for (int s = 128; s > 0; s >>= 1) {
    if (tid < s) red[tid] += red[tid + s];
    __syncthreads();
  }
  float r = rsqrtf(red[0] / H_ + EPS_);
  float y0 = x0 * r, y1 = x1 * r;
  Y[(size_t)t * H_ + tid] = y0;
  Y[(size_t)t * H_ + tid + 256] = y1;
  Y16[(size_t)t * H_ + tid] = f2bf(y0);
  Y16[(size_t)t * H_ + tid + 256] = f2bf(y1);
}

__global__ __launch_bounds__(256) void k_rms_bwd(const float* __restrict__ X,
                                                 const float* __restrict__ GY,
                                                 float* __restrict__ GX,
                                                 unsigned short* __restrict__ GX16) {
  int t = blockIdx.x, tid = threadIdx.x;
  float x0 = X[(size_t)t * H_ + tid], x1 = X[(size_t)t * H_ + tid + 256];
  float g0 = GY[(size_t)t * H_ + tid], g1 = GY[(size_t)t * H_ + tid + 256];
  __shared__ float r1[256], r2[256];
  r1[tid] = x0 * x0 + x1 * x1;
  r2[tid] = x0 * g0 + x1 * g1;
  __syncthreads();
  for (int s = 128; s > 0; s >>= 1) {
    if (tid < s) { r1[tid] += r1[tid + s]; r2[tid] += r2[tid + s]; }
    __syncthreads();
  }
  float r = rsqrtf(r1[0] / H_ + EPS_);
  float coef = r * r * r * r2[0] / (float)H_;
  float o0 = r * g0 - coef * x0, o1 = r * g1 - coef * x1;
  GX[(size_t)t * H_ + tid] = o0;
  GX[(size_t)t * H_ + tid + 256] = o1;
  GX16[(size_t)t * H_ + tid] = f2bf(o0);
  GX16[(size_t)t * H_ + tid + 256] = f2bf(o1);
}

// ---------------- logits update ----------------

__global__ __launch_bounds__(64) void k_logits_update(const float* __restrict__ G,
                                                      const float* __restrict__ E,
                                                      const float* __restrict__ P,
                                                      const float* __restrict__ alpha,
                                                      float* __restrict__ logits) {
  int t = blockIdx.x, lane = threadIdx.x;
  float dp[V_];
#pragma unroll
  for (int v = 0; v < V_; ++v) dp[v] = 0.f;
  for (int hh = lane; hh < H_; hh += 64) {
    float gh = G[(size_t)t * H_ + hh];
#pragma unroll
    for (int v = 0; v < V_; ++v) dp[v] += gh * E[v * H_ + hh];
  }
#pragma unroll
  for (int v = 0; v < V_; ++v) dp[v] = wave_sum64(dp[v]) * ESCALE_;
  float dot = 0.f;
  float pv[V_];
#pragma unroll
  for (int v = 0; v < V_; ++v) {
    pv[v] = P[t * V_ + v];
    dot += pv[v] * dp[v];
  }
  float a = fmaxf(alpha[0], 1e-4f);
  if (lane < V_) logits[t * V_ + lane] -= a * pv[lane] * (dp[lane] - dot);
}

// ---------------- host-side orchestration ----------------

struct Ctx {
  unsigned short *Q16, *Q016, *dQ16, *GU16, *DO16, *AO16, *AO016, *X116, *UDX16, *U016;
  float *X1, *X2, *X20, *G, *UDX, *P, *MB, *LB, *DB, *MB0, *LB0, *CS, *SN;
  const unsigned short *WTqkv[2], *WTo[2], *WTgu[2], *WTd[2];
  const unsigned short *WSqkv[2], *WSo[2], *WSgu[2], *WSd[2];
  hipStream_t st;
};

static void block_forward(Ctx& c, int l, const float* hin, const unsigned short* hin16,
                          float* hout, unsigned short* qb, unsigned short* ao,
                          float* mb, float* lb, float* x2buf, unsigned short* u16buf) {
  k_gemm<128, 0, 0, 1, 1, 0><<<dim3(3 * H_ / 128, (NTOK + 127) / 128), 256, 0, c.st>>>(
      hin16, c.WTqkv[l], nullptr, nullptr, qb, nullptr, c.CS, c.SN, NTOK, 3 * H_, H_, H_);
  k_attn_fwd3<<<dim3((S_ + 63) / 64, NH_, B_), 256, 0, c.st>>>(qb, ao, mb, lb);
  k_gemm<64, 0, 1, 0, 0, 0><<<dim3(H_ / 128, (NTOK + 63) / 64), 256, 0, c.st>>>(
      ao, c.WTo[l], hin, c.X1, nullptr, nullptr, nullptr, nullptr, NTOK, H_, H_, H_);
  k_rms_fwd<<<NTOK, 256, 0, c.st>>>(c.X1, c.UDX, u16buf);
  k_gemm<128, 0, 0, 1, 0, 0><<<dim3(2 * INNER_ / 128, (NTOK + 127) / 128), 256, 0, c.st>>>(
      u16buf, c.WTgu[l], nullptr, nullptr, c.GU16, nullptr, nullptr, nullptr, NTOK, 2 * INNER_, H_, H_);
  k_gemm<64, 1, 1, 0, 0, 0><<<dim3(H_ / 128, (NTOK + 63) / 64), 256, 0, c.st>>>(
      c.GU16, c.WTd[l], c.UDX, x2buf, nullptr, nullptr, nullptr, nullptr, NTOK, H_, INNER_, 2 * INNER_);
  if (hout) k_rms_fwd<<<NTOK, 256, 0, c.st>>>(x2buf, hout, c.UDX16);
}

static void block_backward(Ctx& c, int l, const float* hin, const unsigned short* hin16,
                           unsigned short* qb, unsigned short* ao, float* mb, float* lb,
                           bool full) {
  const float* x2src;
  if (full) {
    block_forward(c, l, hin, hin16, nullptr, qb, ao, mb, lb, c.X2, c.UDX16);
    x2src = c.X2;
  } else {
    k_gemm<64, 0, 1, 0, 0, 0><<<dim3(H_ / 128, (NTOK + 63) / 64), 256, 0, c.st>>>(
        ao, c.WTo[l], hin, c.X1, nullptr, nullptr, nullptr, nullptr, NTOK, H_, H_, H_);
    k_gemm<128, 0, 0, 1, 0, 0><<<dim3(2 * INNER_ / 128, (NTOK + 127) / 128), 256, 0, c.st>>>(
        c.U016, c.WTgu[l], nullptr, nullptr, c.GU16, nullptr, nullptr, nullptr, NTOK, 2 * INNER_, H_, H_);
    x2src = c.X20;
  }
  k_rms_bwd<<<NTOK, 256, 0, c.st>>>(x2src, c.G, c.UDX, c.UDX16);
  k_gemm<128, 0, 0, 0, 0, 1><<<dim3(INNER_ / 128, (NTOK + 127) / 128), 256, 0, c.st>>>(
      c.UDX16, c.WSd[l], nullptr, nullptr, nullptr, c.GU16, nullptr, nullptr, NTOK, INNER_, H_, H_);
  k_gemm<64, 0, 1, 0, 0, 0><<<dim3(H_ / 128, (NTOK + 63) / 64), 256, 0, c.st>>>(
      c.GU16, c.WSgu[l], c.UDX, c.G, nullptr, nullptr, nullptr, nullptr, NTOK, H_, 2 * INNER_, 2 * INNER_);
  k_rms_bwd<<<NTOK, 256, 0, c.st>>>(c.X1, c.G, c.UDX, c.UDX16);
  k_gemm<64, 0, 0, 1, 0, 0><<<dim3(H_ / 128, (NTOK + 63) / 64), 256, 0, c.st>>>(
      c.UDX16, c.WSo[l], nullptr, nullptr, c.DO16, nullptr, nullptr, nullptr, NTOK, H_, H_, H_);
  dim3 agrid((S_ + 63) / 64, NH_, B_);
  k_delta<<<agrid, 256, 0, c.st>>>(ao, c.DO16, c.DB);
  k_attn_bwd_dq3<<<agrid, 256, 0, c.st>>>(qb, c.DO16, mb, lb, c.DB, c.CS, c.SN, c.dQ16);
  k_attn_bwd_kv3<<<agrid, 256, 0, c.st>>>(qb, c.DO16, mb, lb, c.DB, c.CS, c.SN, c.dQ16);
  k_gemm<64, 0, 1, 0, 0, 0><<<dim3(H_ / 128, (NTOK + 63) / 64), 256, 0, c.st>>>(
      c.dQ16, c.WSqkv[l], c.UDX, c.G, nullptr, nullptr, nullptr, nullptr, NTOK, H_, 3 * H_, 3 * H_);
}

extern "C" void kernel_launch(void* const* d_in, const int* in_sizes, int n_in,
                              void* d_out, int out_size, void* d_ws, size_t ws_size,
                              hipStream_t stream) {
  const int* inputs = (const int*)d_in[0];
  const float* E = (const float*)d_in[2];
  const float* ew = (const float*)d_in[3];
  const float* qkvw = (const float*)d_in[4];
  const float* ow = (const float*)d_in[5];
  const float* guw = (const float*)d_in[6];
  const float* dw = (const float*)d_in[7];
  const float* alpha = (const float*)d_in[8];
  float* logits = (float*)d_out;

  const size_t WT_FLOATS = 3407872;
  const size_t NEED =
      3 * ((size_t)NTOK * 3 * H_ / 2) +
      ((size_t)NTOK * INNER_) +
      5 * ((size_t)NTOK * H_) +
      6 * ((size_t)NTOK * H_ / 2) +
      ((size_t)NTOK * V_) +
      5 * ((size_t)B_ * NH_ * S_) +
      2 * ((size_t)S_ * 32) +
      2 * WT_FLOATS;
  if (ws_size < NEED * sizeof(float)) {
    k_zero<<<(NTOK * V_ + 255) / 256, 256, 0, stream>>>(logits, NTOK * V_);
    return;
  }

  float* f = (float*)d_ws;
  Ctx c;
  c.st = stream;
  c.Q16 = (unsigned short*)f;  f += (size_t)NTOK * 3 * H_ / 2;
  c.Q016 = (unsigned short*)f; f += (size_t)NTOK * 3 * H_ / 2;
  c.dQ16 = (unsigned short*)f; f += (size_t)NTOK * 3 * H_ / 2;
  c.GU16 = (unsigned short*)f; f += (size_t)NTOK * INNER_;
  c.X1 = f;   f += (size_t)NTOK * H_;
  c.X2 = f;   f += (size_t)NTOK * H_;
  c.X20 = f;  f += (size_t)NTOK * H_;
  c.G = f;    f += (size_t)NTOK * H_;
  c.UDX = f;  f += (size_t)NTOK * H_;
  c.AO16 = (unsigned short*)f;  f += (size_t)NTOK * H_ / 2;
  c.AO016 = (unsigned short*)f; f += (size_t)NTOK * H_ / 2;
  c.DO16 = (unsigned short*)f;  f += (size_t)NTOK * H_ / 2;
  c.X116 = (unsigned short*)f;  f += (size_t)NTOK * H_ / 2;
  c.UDX16 = (unsigned short*)f; f += (size_t)NTOK * H_ / 2;
  c.U016 = (unsigned short*)f;  f += (size_t)NTOK * H_ / 2;
  c.P = f;    f += (size_t)NTOK * V_;
  c.MB = f;   f += (size_t)B_ * NH_ * S_;
  c.LB = f;   f += (size_t)B_ * NH_ * S_;
  c.DB = f;   f += (size_t)B_ * NH_ * S_;
  c.MB0 = f;  f += (size_t)B_ * NH_ * S_;
  c.LB0 = f;  f += (size_t)B_ * NH_ * S_;
  c.CS = f;   f += (size_t)S_ * 32;
  c.SN = f;   f += (size_t)S_ * 32;
  unsigned short* wt = (unsigned short*)f;

  const size_t LQKV = (size_t)H_ * 3 * H_;
  const size_t LO = (size_t)H_ * H_;
  const size_t LGU = (size_t)H_ * 2 * INNER_;
  const size_t LD = (size_t)INNER_ * H_;

  for (int l = 0; l < 2; ++l) {
    c.WTqkv[l] = wt;
    k_wt<<<dim3(3 * H_ / 32, H_ / 32), dim3(32, 8), 0, stream>>>(qkvw + l * LQKV, wt, H_, 3 * H_);
    wt += LQKV;
    c.WTo[l] = wt;
    k_wt<<<dim3(H_ / 32, H_ / 32), dim3(32, 8), 0, stream>>>(ow + l * LO, wt, H_, H_);
    wt += LO;
    c.WTgu[l] = wt;
    k_wt<<<dim3(2 * INNER_ / 32, H_ / 32), dim3(32, 8), 0, stream>>>(guw + l * LGU, wt, H_, 2 * INNER_);
    wt += LGU;
    c.WTd[l] = wt;
    k_wt<<<dim3(H_ / 32, INNER_ / 32), dim3(32, 8), 0, stream>>>(dw + l * LD, wt, INNER_, H_);
    wt += LD;
  }
  {
    unsigned short* ws = wt;
    k_cast8<<<(int)((2 * LQKV / 8 + 255) / 256), 256, 0, stream>>>(qkvw, ws, (int)(2 * LQKV / 8));
    c.WSqkv[0] = ws; c.WSqkv[1] = ws + LQKV; ws += 2 * LQKV;
    k_cast8<<<(int)((2 * LO / 8 + 255) / 256), 256, 0, stream>>>(ow, ws, (int)(2 * LO / 8));
    c.WSo[0] = ws; c.WSo[1] = ws + LO; ws += 2 * LO;
    k_cast8<<<(int)((2 * LGU / 8 + 255) / 256), 256, 0, stream>>>(guw, ws, (int)(2 * LGU / 8));
    c.WSgu[0] = ws; c.WSgu[1] = ws + LGU; ws += 2 * LGU;
    k_cast8<<<(int)((2 * LD / 8 + 255) / 256), 256, 0, stream>>>(dw, ws, (int)(2 * LD / 8));
    c.WSd[0] = ws; c.WSd[1] = ws + LD;
  }

  k_zero<<<(NTOK * V_ + 255) / 256, 256, 0, stream>>>(logits, NTOK * V_);
  k_rope_tables<<<(S_ * 32 + 255) / 256, 256, 0, stream>>>(c.CS, c.SN);

  for (int step = 0; step < STEPS_; ++step) {
    k_softmax_logits<<<(NTOK + 255) / 256, 256, 0, stream>>>(logits, c.P);
    k_h0<<<NTOK, 256, 0, stream>>>(c.P, E, inputs, c.X1, c.X116);
    block_forward(c, 0, c.X1, c.X116, c.UDX, c.Q016, c.AO016, c.MB0, c.LB0, c.X20, c.U016);
    k_gfill<<<(NTOK * H_ + 255) / 256, 256, 0, stream>>>(ew, c.G);
    block_backward(c, 1, c.UDX, c.UDX16, c.Q16, c.AO16, c.MB, c.LB, true);
    k_h0<<<NTOK, 256, 0, stream>>>(c.P, E, inputs, c.X1, c.X116);
    block_backward(c, 0, c.X1, c.X116, c.Q016, c.AO016, c.MB0, c.LB0, false);
    k_logits_update<<<NTOK, 64, 0, stream>>>(c.G, E, c.P, alpha, logits);
  }
}

// Round 13
// 2413.332 us; speedup vs baseline: 2.7073x; 2.7073x over previous
//
#include <hip/hip_runtime.h>
#include <math.h>

#define B_ 8
#define S_ 900
#define V_ 11
#define H_ 512
#define NH_ 8
#define HD_ 64
#define INNER_ 1536
#define STEPS_ 2
#define NTOK (B_*S_)
#define EPS_ 1e-5f
#define THETA_ 10000.0f
#define ESCALE_ 22.627416997969522f
#define SCALE_ 0.125f
#define PT_ 68   // attention LDS pitch (ushorts): 136B rows, 8B-aligned (b64 floor pattern)

typedef __attribute__((ext_vector_type(8))) short bh8;
typedef __attribute__((ext_vector_type(4))) float f32x4;
typedef __attribute__((ext_vector_type(4))) unsigned short us4;

union bfu { bh8 v; unsigned short s[8]; us4 q[2]; };

__device__ inline unsigned short f2bf(float x) {
  unsigned u = __builtin_bit_cast(unsigned, x);
  return (unsigned short)((u + 0x7FFFu + ((u >> 16) & 1u)) >> 16);
}
__device__ inline float b2f(unsigned short s) {
  return __builtin_bit_cast(float, (unsigned)s << 16);
}

// async global->LDS, 16B per lane; LDS dest = wave-uniform base + lane*16
__device__ inline void gld16(const unsigned short* g, unsigned short* l) {
  __builtin_amdgcn_global_load_lds(
      (const __attribute__((address_space(1))) void*)(g),
      (__attribute__((address_space(3))) void*)(l), 16, 0, 0);
}

__device__ inline bh8 lds16(const unsigned short* p) {
  bfu u;
  u.q[0] = *(const us4*)p;
  u.q[1] = *(const us4*)(p + 4);
  return u.v;
}
__device__ inline void sts16(unsigned short* p, bfu u) {
  *(us4*)p = u.q[0];
  *(us4*)(p + 4) = u.q[1];
}

__device__ inline float wave_sum64(float x) {
#pragma unroll
  for (int off = 32; off > 0; off >>= 1) x += __shfl_xor(x, off, 64);
  return x;
}

__device__ inline float quad_sum(float x) {
  x += __shfl_xor(x, 1, 64);
  x += __shfl_xor(x, 2, 64);
  return x;
}

// ---------------- small kernels ----------------

__global__ void k_zero(float* p, int n) {
  int i = blockIdx.x * blockDim.x + threadIdx.x;
  if (i < n) p[i] = 0.f;
}

__global__ void k_rope_tables(float* cs, float* sn) {
  int idx = blockIdx.x * blockDim.x + threadIdx.x;
  if (idx >= S_ * 32) return;
  int s = idx >> 5, i = idx & 31;
  float freq = powf(THETA_, -(float)i / 32.0f);
  float ang = (float)s * freq;
  cs[idx] = cosf(ang);
  sn[idx] = sinf(ang);
}

__global__ void k_softmax_logits(const float* __restrict__ logits, float* __restrict__ P) {
  int t = blockIdx.x * blockDim.x + threadIdx.x;
  if (t >= NTOK) return;
  float x[V_];
  float m = -1e30f;
#pragma unroll
  for (int v = 0; v < V_; ++v) { x[v] = logits[t * V_ + v]; m = fmaxf(m, x[v]); }
  float ssum = 0.f;
#pragma unroll
  for (int v = 0; v < V_; ++v) { x[v] = expf(x[v] - m); ssum += x[v]; }
  float inv = 1.f / ssum;
#pragma unroll
  for (int v = 0; v < V_; ++v) P[t * V_ + v] = x[v] * inv;
}

// h0 -> fp32 + bf16
__global__ void k_h0(const float* __restrict__ P, const float* __restrict__ E,
                     const int* __restrict__ inp, float* __restrict__ h0,
                     unsigned short* __restrict__ h016) {
  int t = blockIdx.x;
  int tid = threadIdx.x;
  __shared__ float p[V_];
  __shared__ int iw;
  if (tid < V_) p[tid] = P[t * V_ + tid];
  if (tid == 0) iw = inp[t];
  __syncthreads();
  for (int h = tid; h < H_; h += blockDim.x) {
    float acc = E[iw * H_ + h];
#pragma unroll
    for (int v = 0; v < V_; ++v) acc += p[v] * E[v * H_ + h];
    float val = ESCALE_ * acc;
    h0[(size_t)t * H_ + h] = val;
    h016[(size_t)t * H_ + h] = f2bf(val);
  }
}

__global__ void k_gfill(const float* __restrict__ ew, float* __restrict__ G) {
  int idx = blockIdx.x * blockDim.x + threadIdx.x;
  if (idx < NTOK * H_) G[idx] = ew[idx & (H_ - 1)];
}

// fp32 -> bf16 cast, 8 elems/thread
__global__ void k_cast8(const float* __restrict__ X, unsigned short* __restrict__ Y, int n8) {
  int i = blockIdx.x * blockDim.x + threadIdx.x;
  if (i >= n8) return;
  const float4* p = (const float4*)(X + (size_t)i * 8);
  float4 a = p[0], b = p[1];
  bfu o;
  o.s[0] = f2bf(a.x); o.s[1] = f2bf(a.y); o.s[2] = f2bf(a.z); o.s[3] = f2bf(a.w);
  o.s[4] = f2bf(b.x); o.s[5] = f2bf(b.y); o.s[6] = f2bf(b.z); o.s[7] = f2bf(b.w);
  *(bh8*)(Y + (size_t)i * 8) = o.v;
}

// ---------------- weight transpose-convert: W[K][N] fp32 -> WT[N][K] bf16 ----------------

__global__ void k_wt(const float* __restrict__ W, unsigned short* __restrict__ WT, int K, int N) {
  __shared__ float t[32][33];
  int k0 = blockIdx.y * 32, n0 = blockIdx.x * 32;
  int tx = threadIdx.x, ty = threadIdx.y;
#pragma unroll
  for (int i = 0; i < 4; ++i)
    t[ty + 8 * i][tx] = W[(size_t)(k0 + ty + 8 * i) * N + n0 + tx];
  __syncthreads();
#pragma unroll
  for (int i = 0; i < 4; ++i)
    WT[(size_t)(n0 + ty + 8 * i) * K + k0 + tx] = f2bf(t[tx][ty + 8 * i]);
}

// ---------------- MFMA GEMM: C[M,N] = A[M,K] @ B^T (A,B bf16; B stored [N][K]) ----------------

template <int TM, int SILU_A, int ADD, int CBF, int ROPE, int SILUBWD>
__global__ __launch_bounds__(256) void k_gemm(const unsigned short* __restrict__ A16,
                                              const unsigned short* __restrict__ Bt,
                                              const float* __restrict__ Dm,
                                              float* __restrict__ Cf,
                                              unsigned short* __restrict__ C16,
                                              unsigned short* __restrict__ GU,
                                              const float* __restrict__ Cs,
                                              const float* __restrict__ Sn,
                                              int M, int N, int K, int lda) {
  __shared__ unsigned short As[TM][32];
  __shared__ unsigned short Bs[128][32];
  constexpr int FR = TM / 32;
  int tid = threadIdx.x;
  int m0 = blockIdx.y * TM, n0 = blockIdx.x * 128;
  int wid = tid >> 6, lane = tid & 63;
  int wr = (wid >> 1) * (FR * 16), wc = (wid & 1) * 64;
  int lr = lane & 15, lg = lane >> 4;
  int srow = lane >> 2, sck = (lane & 3) * 8;
  f32x4 acc[FR][4] = {};
  for (int k0 = 0; k0 < K; k0 += 32) {
    __syncthreads();
#pragma unroll
    for (int half = 0; half < TM / 64; ++half) {
      if (SILU_A) {
        int row = (tid >> 2) + 64 * half;
        int ck = (tid & 3) * 8;
        int gr = m0 + row; gr = gr < M ? gr : M - 1;
        const unsigned short* src = &A16[(size_t)gr * lda + k0 + ck];
        bfu pa;
#pragma unroll
        for (int j = 0; j < 8; ++j) {
          float g = b2f(src[j]), u = b2f(src[INNER_ + j]);
          pa.s[j] = f2bf((g / (1.f + __expf(-g))) * u);
        }
        *(bh8*)&As[row][ck] = pa.v;
      } else {
        int gr = m0 + 64 * half + wid * 16 + srow; gr = gr < M ? gr : M - 1;
        gld16(&A16[(size_t)gr * lda + k0 + sck], &As[64 * half + wid * 16][0]);
      }
    }
#pragma unroll
    for (int i = 0; i < 2; ++i) {
      int bb = wid * 2 + i;
      gld16(&Bt[(size_t)(n0 + bb * 16 + srow) * K + k0 + sck], &Bs[bb * 16][0]);
    }
    __syncthreads();
    bh8 av[FR], bv[4];
#pragma unroll
    for (int fr = 0; fr < FR; ++fr) av[fr] = *(const bh8*)&As[wr + fr * 16 + lr][lg * 8];
#pragma unroll
    for (int fc = 0; fc < 4; ++fc) bv[fc] = *(const bh8*)&Bs[wc + fc * 16 + lr][lg * 8];
#pragma unroll
    for (int fr = 0; fr < FR; ++fr)
#pragma unroll
      for (int fc = 0; fc < 4; ++fc)
        acc[fr][fc] = __builtin_amdgcn_mfma_f32_16x16x32_bf16(av[fr], bv[fc], acc[fr][fc], 0, 0, 0);
  }
  bool rope_on = ROPE && (((n0 + wc) >> 6) < 16);
#pragma unroll
  for (int fr = 0; fr < FR; ++fr) {
    int r0 = m0 + wr + fr * 16 + lg * 4;
#pragma unroll
    for (int i = 0; i < 4; ++i) {
      int gr = r0 + i;
      if (gr >= M) continue;
      float c0 = 1.f, s0 = 0.f, c1 = 1.f, s1 = 0.f;
      if (ROPE) {
        if (rope_on) {
          int s = gr % S_;
          c0 = Cs[s * 32 + lr];      s0 = Sn[s * 32 + lr];
          c1 = Cs[s * 32 + 16 + lr]; s1 = Sn[s * 32 + 16 + lr];
        }
      }
#pragma unroll
      for (int fc = 0; fc < 4; ++fc) {
        int gc = n0 + wc + fc * 16 + lr;
        float out = acc[fr][fc][i];
        if (ROPE) {
          float part = acc[fr][fc ^ 2][i];
          float cc = (fc & 1) ? c1 : c0;
          float ss = (fc & 1) ? s1 : s0;
          out = (fc < 2) ? (out * cc - part * ss) : (out * cc + part * ss);
        }
        if (ADD) out += Dm[(size_t)gr * N + gc];
        if (SILUBWD) {
          size_t gb = (size_t)gr * (size_t)(2 * INNER_) + gc;
          float g = b2f(GU[gb]), u = b2f(GU[gb + INNER_]);
          float sig = 1.f / (1.f + __expf(-g));
          GU[gb] = f2bf(out * u * sig * (1.f + g * (1.f - sig)));
          GU[gb + INNER_] = f2bf(out * g * sig);
        } else if (CBF) {
          C16[(size_t)gr * N + gc] = f2bf(out);
        } else {
          Cf[(size_t)gr * N + gc] = out;
        }
      }
    }
  }
}

// ---------------- MFMA flash attention (bf16 QKV, bf16 O), prefetch-under-compute ----------------
// Loop shape: barrier; regs->LDS; barrier; ISSUE next-tile loads; compute.
// Loads stay in flight across the compute phase; the next iteration's first
// barrier (implicit vmcnt(0) drain) guarantees completion before consumption.

__global__ __launch_bounds__(256) void k_attn_fwd3(const unsigned short* __restrict__ QKV,
                                                   unsigned short* __restrict__ AO,
                                                   float* __restrict__ MB,
                                                   float* __restrict__ LB) {
  __shared__ unsigned short Ks[64][PT_];
  __shared__ unsigned short VT[64][PT_];
  __shared__ unsigned short Ps[4][16][PT_];
  int tid = threadIdx.x;
  int h = blockIdx.y, b = blockIdx.z;
  int w = tid >> 6, lane = tid & 63;
  int lr = lane & 15, lg = lane >> 4;
  int q0 = blockIdx.x * 64 + w * 16;
  int sr = tid >> 2, sc0 = (tid & 3) * 16;
  int vd0 = (tid & 15) * 4, vk0 = (tid >> 4) * 4;

  bh8 qf[2];
  {
    int qr = q0 + lr; if (qr >= S_) qr = S_ - 1;
    const unsigned short* qp = &QKV[((size_t)(b * S_ + qr) * 24 + h) * 64 + lg * 8];
    qf[0] = *(const bh8*)qp;
    qf[1] = *(const bh8*)(qp + 32);
  }
  f32x4 accO[4] = {};
  float m[4], lsum[4];
#pragma unroll
  for (int i = 0; i < 4; ++i) { m[i] = -1e30f; lsum[i] = 0.f; }

  // prefetch tile 0
  bfu kA, kB;
  us4 vR[4];
  {
    int src = sr;
    size_t ts = (size_t)b * S_ + (src < S_ ? src : S_ - 1);
    const unsigned short* gp = &QKV[(ts * 24 + 8 + h) * 64 + sc0];
    kA.v = *(const bh8*)gp;
    kB.v = *(const bh8*)(gp + 8);
#pragma unroll
    for (int j = 0; j < 4; ++j) {
      int s2 = vk0 + j;
      size_t t2 = (size_t)b * S_ + (s2 < S_ ? s2 : S_ - 1);
      vR[j] = *(const us4*)&QKV[(t2 * 24 + 16 + h) * 64 + vd0];
    }
  }

  for (int kt = 0; kt < S_; kt += 64) {
    __syncthreads();
    sts16(&Ks[sr][sc0], kA);
    sts16(&Ks[sr][sc0 + 8], kB);
#pragma unroll
    for (int dd = 0; dd < 4; ++dd) {
      us4 pk = {vR[0][dd], vR[1][dd], vR[2][dd], vR[3][dd]};
      *(us4*)&VT[vd0 + dd][vk0] = pk;
    }
    __syncthreads();
    if (kt + 64 < S_) {  // issue next-tile loads: in flight under compute
      int src = kt + 64 + sr;
      size_t ts = (size_t)b * S_ + (src < S_ ? src : S_ - 1);
      const unsigned short* gp = &QKV[(ts * 24 + 8 + h) * 64 + sc0];
      kA.v = *(const bh8*)gp;
      kB.v = *(const bh8*)(gp + 8);
#pragma unroll
      for (int j = 0; j < 4; ++j) {
        int s2 = kt + 64 + vk0 + j;
        size_t t2 = (size_t)b * S_ + (s2 < S_ ? s2 : S_ - 1);
        vR[j] = *(const us4*)&QKV[(t2 * 24 + 16 + h) * 64 + vd0];
      }
    }
    f32x4 accS[4] = {};
#pragma unroll
    for (int ks = 0; ks < 2; ++ks)
#pragma unroll
      for (int fk = 0; fk < 4; ++fk)
        accS[fk] = __builtin_amdgcn_mfma_f32_16x16x32_bf16(qf[ks], lds16(&Ks[fk * 16 + lr][ks * 32 + lg * 8]), accS[fk], 0, 0, 0);
    float sc[4][4], pmax[4];
#pragma unroll
    for (int i = 0; i < 4; ++i) pmax[i] = -1e30f;
#pragma unroll
    for (int fk = 0; fk < 4; ++fk)
#pragma unroll
      for (int i = 0; i < 4; ++i) {
        float s = accS[fk][i] * SCALE_;
        if (kt + fk * 16 + lr >= S_) s = -1e30f;
        sc[fk][i] = s;
        pmax[i] = fmaxf(pmax[i], s);
      }
#pragma unroll
    for (int i = 0; i < 4; ++i) {
      float v = pmax[i];
      v = fmaxf(v, __shfl_xor(v, 1, 64));
      v = fmaxf(v, __shfl_xor(v, 2, 64));
      v = fmaxf(v, __shfl_xor(v, 4, 64));
      v = fmaxf(v, __shfl_xor(v, 8, 64));
      pmax[i] = v;
    }
    float psum[4];
#pragma unroll
    for (int i = 0; i < 4; ++i) {
      float mn = fmaxf(m[i], pmax[i]);
      float eo = __expf(m[i] - mn);
      m[i] = mn;
      lsum[i] *= eo;
#pragma unroll
      for (int fd = 0; fd < 4; ++fd) accO[fd][i] *= eo;
      psum[i] = 0.f;
    }
#pragma unroll
    for (int fk = 0; fk < 4; ++fk)
#pragma unroll
      for (int i = 0; i < 4; ++i) {
        float p = __expf(sc[fk][i] - m[i]);
        sc[fk][i] = p;
        psum[i] += p;
      }
#pragma unroll
    for (int i = 0; i < 4; ++i) {
      float v = psum[i];
      v += __shfl_xor(v, 1, 64);
      v += __shfl_xor(v, 2, 64);
      v += __shfl_xor(v, 4, 64);
      v += __shfl_xor(v, 8, 64);
      lsum[i] += v;
    }
#pragma unroll
    for (int fk = 0; fk < 4; ++fk)
#pragma unroll
      for (int i = 0; i < 4; ++i)
        Ps[w][lg * 4 + i][fk * 16 + lr] = f2bf(sc[fk][i]);
#pragma unroll
    for (int ks = 0; ks < 2; ++ks) {
      bh8 ap = lds16(&Ps[w][lr][ks * 32 + lg * 8]);
#pragma unroll
      for (int fd = 0; fd < 4; ++fd)
        accO[fd] = __builtin_amdgcn_mfma_f32_16x16x32_bf16(ap, lds16(&VT[fd * 16 + lr][ks * 32 + lg * 8]), accO[fd], 0, 0, 0);
    }
  }
#pragma unroll
  for (int i = 0; i < 4; ++i) {
    int q = q0 + lg * 4 + i;
    if (q < S_) {
      float linv = 1.f / lsum[i];
      size_t obase = (size_t)(b * S_ + q) * H_ + h * 64;
#pragma unroll
      for (int fd = 0; fd < 4; ++fd) AO[obase + fd * 16 + lr] = f2bf(accO[fd][i] * linv);
      if (lr == 0) {
        MB[((size_t)b * NH_ + h) * S_ + q] = m[i];
        LB[((size_t)b * NH_ + h) * S_ + q] = linv;
      }
    }
  }
}

// delta[b,h,q] = dot(dO_row, O_row), both bf16
__global__ __launch_bounds__(256) void k_delta(const unsigned short* __restrict__ O,
                                               const unsigned short* __restrict__ dO,
                                               float* __restrict__ DB) {
  int tid = threadIdx.x;
  int h = blockIdx.y, b = blockIdx.z;
  int r = blockIdx.x * 64 + (tid >> 2), part = tid & 3;
  if (r >= S_) return;
  size_t base = (size_t)(b * S_ + r) * H_ + h * 64 + part * 16;
  bfu o0, o1, d0, d1;
  o0.v = *(const bh8*)&O[base];  o1.v = *(const bh8*)&O[base + 8];
  d0.v = *(const bh8*)&dO[base]; d1.v = *(const bh8*)&dO[base + 8];
  float s = 0.f;
#pragma unroll
  for (int j = 0; j < 8; ++j)
    s += b2f(o0.s[j]) * b2f(d0.s[j]) + b2f(o1.s[j]) * b2f(d1.s[j]);
  s = quad_sum(s);
  if (part == 0) DB[((size_t)b * NH_ + h) * S_ + r] = s;
}

// dQ pass; fused inverse-RoPE on output; prefetch-under-compute
__global__ __launch_bounds__(256) void k_attn_bwd_dq3(const unsigned short* __restrict__ QKV,
                                                      const unsigned short* __restrict__ dO,
                                                      const float* __restrict__ MB,
                                                      const float* __restrict__ LB,
                                                      const float* __restrict__ DB,
                                                      const float* __restrict__ Cs,
                                                      const float* __restrict__ Sn,
                                                      unsigned short* __restrict__ dQKV) {
  __shared__ unsigned short Ks[64][PT_];
  __shared__ unsigned short Vs[64][PT_];
  __shared__ unsigned short KT[64][PT_];
  __shared__ unsigned short Ps[4][16][PT_];
  int tid = threadIdx.x;
  int h = blockIdx.y, b = blockIdx.z;
  int w = tid >> 6, lane = tid & 63;
  int lr = lane & 15, lg = lane >> 4;
  int q0 = blockIdx.x * 64 + w * 16;
  size_t sbase = ((size_t)b * NH_ + h) * S_;
  int sr = tid >> 2, sc0 = (tid & 3) * 16;
  int vd0 = (tid & 15) * 4, vk0 = (tid >> 4) * 4;

  bh8 qf[2], dof[2];
  {
    int qr = q0 + lr; if (qr >= S_) qr = S_ - 1;
    const unsigned short* qp = &QKV[((size_t)(b * S_ + qr) * 24 + h) * 64 + lg * 8];
    const unsigned short* dp = &dO[(size_t)(b * S_ + qr) * H_ + h * 64 + lg * 8];
    qf[0] = *(const bh8*)qp;  qf[1] = *(const bh8*)(qp + 32);
    dof[0] = *(const bh8*)dp; dof[1] = *(const bh8*)(dp + 32);
  }
  float mrow[4], lrow[4], drow[4];
#pragma unroll
  for (int i = 0; i < 4; ++i) {
    int q = q0 + lg * 4 + i; if (q >= S_) q = S_ - 1;
    mrow[i] = MB[sbase + q];
    lrow[i] = LB[sbase + q];
    drow[i] = DB[sbase + q];
  }
  f32x4 accQ[4] = {};

  // prefetch tile 0
  bfu pA{}, pB{}, pC{}, pD{};
  us4 rv[4];
  {
    int src = sr;
    bool vld = src < S_;
    size_t ts = (size_t)b * S_ + (vld ? src : S_ - 1);
    const unsigned short* kp = &QKV[(ts * 24 + 8 + h) * 64 + sc0];
    if (vld) {
      pA.v = *(const bh8*)kp;
      pB.v = *(const bh8*)(kp + 8);
      pC.v = *(const bh8*)(kp + 512);
      pD.v = *(const bh8*)(kp + 520);
    }
#pragma unroll
    for (int j = 0; j < 4; ++j) {
      int s2 = vk0 + j;
      bool v2 = s2 < S_;
      size_t t2 = (size_t)b * S_ + (v2 ? s2 : S_ - 1);
      us4 t = *(const us4*)&QKV[(t2 * 24 + 8 + h) * 64 + vd0];
      if (!v2) t = us4{0, 0, 0, 0};
      rv[j] = t;
    }
  }

  for (int kt = 0; kt < S_; kt += 64) {
    __syncthreads();
    sts16(&Ks[sr][sc0], pA); sts16(&Ks[sr][sc0 + 8], pB);
    sts16(&Vs[sr][sc0], pC); sts16(&Vs[sr][sc0 + 8], pD);
#pragma unroll
    for (int dd = 0; dd < 4; ++dd) {
      us4 pk = {rv[0][dd], rv[1][dd], rv[2][dd], rv[3][dd]};
      *(us4*)&KT[vd0 + dd][vk0] = pk;
    }
    __syncthreads();
    if (kt + 64 < S_) {  // issue next-tile loads: in flight under compute
      int src = kt + 64 + sr;
      bool vld = src < S_;
      size_t ts = (size_t)b * S_ + (vld ? src : S_ - 1);
      const unsigned short* kp = &QKV[(ts * 24 + 8 + h) * 64 + sc0];
      pA = bfu{}; pB = bfu{}; pC = bfu{}; pD = bfu{};
      if (vld) {
        pA.v = *(const bh8*)kp;
        pB.v = *(const bh8*)(kp + 8);
        pC.v = *(const bh8*)(kp + 512);
        pD.v = *(const bh8*)(kp + 520);
      }
#pragma unroll
      for (int j = 0; j < 4; ++j) {
        int s2 = kt + 64 + vk0 + j;
        bool v2 = s2 < S_;
        size_t t2 = (size_t)b * S_ + (v2 ? s2 : S_ - 1);
        us4 t = *(const us4*)&QKV[(t2 * 24 + 8 + h) * 64 + vd0];
        if (!v2) t = us4{0, 0, 0, 0};
        rv[j] = t;
      }
    }
    f32x4 aS[4] = {}, aD[4] = {};
#pragma unroll
    for (int ks = 0; ks < 2; ++ks)
#pragma unroll
      for (int fk = 0; fk < 4; ++fk) {
        aS[fk] = __builtin_amdgcn_mfma_f32_16x16x32_bf16(qf[ks], lds16(&Ks[fk * 16 + lr][ks * 32 + lg * 8]), aS[fk], 0, 0, 0);
        aD[fk] = __builtin_amdgcn_mfma_f32_16x16x32_bf16(dof[ks], lds16(&Vs[fk * 16 + lr][ks * 32 + lg * 8]), aD[fk], 0, 0, 0);
      }
#pragma unroll
    for (int fk = 0; fk < 4; ++fk)
#pragma unroll
      for (int i = 0; i < 4; ++i) {
        float p = __expf(aS[fk][i] * SCALE_ - mrow[i]) * lrow[i];
        float ds = p * (aD[fk][i] - drow[i]);
        Ps[w][lg * 4 + i][fk * 16 + lr] = f2bf(ds);
      }
#pragma unroll
    for (int ks = 0; ks < 2; ++ks) {
      bh8 ap = lds16(&Ps[w][lr][ks * 32 + lg * 8]);
#pragma unroll
      for (int fd = 0; fd < 4; ++fd)
        accQ[fd] = __builtin_amdgcn_mfma_f32_16x16x32_bf16(ap, lds16(&KT[fd * 16 + lr][ks * 32 + lg * 8]), accQ[fd], 0, 0, 0);
    }
  }
#pragma unroll
  for (int i = 0; i < 4; ++i) {
    int q = q0 + lg * 4 + i;
    if (q < S_) {
      size_t obase = ((size_t)(b * S_ + q) * 24 + h) * 64;
      float c0 = Cs[q * 32 + lr], s0 = Sn[q * 32 + lr];
      float c1 = Cs[q * 32 + 16 + lr], s1 = Sn[q * 32 + 16 + lr];
#pragma unroll
      for (int fd = 0; fd < 4; ++fd) {
        float x = SCALE_ * accQ[fd][i];
        float p = SCALE_ * accQ[fd ^ 2][i];
        float cc = (fd & 1) ? c1 : c0;
        float ss = (fd & 1) ? s1 : s0;
        float out = (fd < 2) ? (x * cc + p * ss) : (x * cc - p * ss);
        dQKV[obase + fd * 16 + lr] = f2bf(out);
      }
    }
  }
}

// dK + dV pass; fused inverse-RoPE on dK; prefetch-under-compute
__global__ __launch_bounds__(256) void k_attn_bwd_kv3(const unsigned short* __restrict__ QKV,
                                                      const unsigned short* __restrict__ dO,
                                                      const float* __restrict__ MB,
                                                      const float* __restrict__ LB,
                                                      const float* __restrict__ DB,
                                                      const float* __restrict__ Cs,
                                                      const float* __restrict__ Sn,
                                                      unsigned short* __restrict__ dQKV) {
  __shared__ unsigned short Qs[64][PT_];
  __shared__ unsigned short dOs[64][PT_];
  __shared__ unsigned short QT[64][PT_];
  __shared__ unsigned short dOT[64][PT_];
  __shared__ unsigned short Ps[4][16][PT_];
  __shared__ float sM[64], sL[64], sD[64];
  int tid = threadIdx.x;
  int h = blockIdx.y, b = blockIdx.z;
  int w = tid >> 6, lane = tid & 63;
  int lr = lane & 15, lg = lane >> 4;
  int k0w = blockIdx.x * 64 + w * 16;
  size_t sbase = ((size_t)b * NH_ + h) * S_;
  int sr = tid >> 2, sc0 = (tid & 3) * 16;
  int vd0 = (tid & 15) * 4, vk0 = (tid >> 4) * 4;

  bh8 kf[2], vf[2];
  {
    int kr = k0w + lr; if (kr >= S_) kr = S_ - 1;
    const unsigned short* kp = &QKV[((size_t)(b * S_ + kr) * 24 + 8 + h) * 64 + lg * 8];
    kf[0] = *(const bh8*)kp;        kf[1] = *(const bh8*)(kp + 32);
    vf[0] = *(const bh8*)(kp + 512); vf[1] = *(const bh8*)(kp + 544);
  }
  f32x4 accK[4] = {}, accV[4] = {};

  // prefetch tile 0
  bfu pA, pB, pC{}, pD{};
  us4 rq[4], rd[4];
  float stM = 0.f, stL = 0.f, stD = 0.f;
  {
    int src = sr;
    bool vld = src < S_;
    size_t ts = (size_t)b * S_ + (vld ? src : S_ - 1);
    const unsigned short* qp = &QKV[(ts * 24 + h) * 64 + sc0];
    const unsigned short* dp = &dO[ts * H_ + h * 64 + sc0];
    pA.v = *(const bh8*)qp;
    pB.v = *(const bh8*)(qp + 8);
    if (vld) {
      pC.v = *(const bh8*)dp;
      pD.v = *(const bh8*)(dp + 8);
    }
#pragma unroll
    for (int j = 0; j < 4; ++j) {
      int s2 = vk0 + j;
      bool v2 = s2 < S_;
      size_t t2 = (size_t)b * S_ + (v2 ? s2 : S_ - 1);
      rq[j] = *(const us4*)&QKV[(t2 * 24 + h) * 64 + vd0];
      us4 td = *(const us4*)&dO[t2 * H_ + h * 64 + vd0];
      if (!v2) td = us4{0, 0, 0, 0};
      rd[j] = td;
    }
    if (tid < 64) {
      bool v2 = tid < S_;
      int sc = v2 ? tid : S_ - 1;
      stM = MB[sbase + sc];
      stL = LB[sbase + sc];
      stD = v2 ? DB[sbase + sc] : 0.f;
    }
  }

  for (int qt = 0; qt < S_; qt += 64) {
    __syncthreads();
    sts16(&Qs[sr][sc0], pA);  sts16(&Qs[sr][sc0 + 8], pB);
    sts16(&dOs[sr][sc0], pC); sts16(&dOs[sr][sc0 + 8], pD);
#pragma unroll
    for (int dd = 0; dd < 4; ++dd) {
      us4 pq = {rq[0][dd], rq[1][dd], rq[2][dd], rq[3][dd]};
      us4 pd = {rd[0][dd], rd[1][dd], rd[2][dd], rd[3][dd]};
      *(us4*)&QT[vd0 + dd][vk0] = pq;
      *(us4*)&dOT[vd0 + dd][vk0] = pd;
    }
    if (tid < 64) {
      sM[tid] = stM;
      sL[tid] = stL;
      sD[tid] = stD;
    }
    __syncthreads();
    if (qt + 64 < S_) {  // issue next-tile loads: in flight under compute
      int src = qt + 64 + sr;
      bool vld = src < S_;
      size_t ts = (size_t)b * S_ + (vld ? src : S_ - 1);
      const unsigned short* qp = &QKV[(ts * 24 + h) * 64 + sc0];
      const unsigned short* dp = &dO[ts * H_ + h * 64 + sc0];
      pA.v = *(const bh8*)qp;
      pB.v = *(const bh8*)(qp + 8);
      pC = bfu{}; pD = bfu{};
      if (vld) {
        pC.v = *(const bh8*)dp;
        pD.v = *(const bh8*)(dp + 8);
      }
#pragma unroll
      for (int j = 0; j < 4; ++j) {
        int s2 = qt + 64 + vk0 + j;
        bool v2 = s2 < S_;
        size_t t2 = (size_t)b * S_ + (v2 ? s2 : S_ - 1);
        rq[j] = *(const us4*)&QKV[(t2 * 24 + h) * 64 + vd0];
        us4 td = *(const us4*)&dO[t2 * H_ + h * 64 + vd0];
        if (!v2) td = us4{0, 0, 0, 0};
        rd[j] = td;
      }
      if (tid < 64) {
        int s2 = qt + 64 + tid;
        bool v2 = s2 < S_;
        int sc = v2 ? s2 : S_ - 1;
        stM = MB[sbase + sc];
        stL = LB[sbase + sc];
        stD = v2 ? DB[sbase + sc] : 0.f;
      }
    }
    f32x4 aS[4] = {}, aD[4] = {};
#pragma unroll
    for (int ks = 0; ks < 2; ++ks)
#pragma unroll
      for (int fq = 0; fq < 4; ++fq) {
        aS[fq] = __builtin_amdgcn_mfma_f32_16x16x32_bf16(kf[ks], lds16(&Qs[fq * 16 + lr][ks * 32 + lg * 8]), aS[fq], 0, 0, 0);
        aD[fq] = __builtin_amdgcn_mfma_f32_16x16x32_bf16(vf[ks], lds16(&dOs[fq * 16 + lr][ks * 32 + lg * 8]), aD[fq], 0, 0, 0);
      }
    float pv[4][4];
#pragma unroll
    for (int fq = 0; fq < 4; ++fq) {
      float mq = sM[fq * 16 + lr], lq = sL[fq * 16 + lr];
#pragma unroll
      for (int i = 0; i < 4; ++i) {
        float p = __expf(aS[fq][i] * SCALE_ - mq) * lq;
        pv[fq][i] = p;
        Ps[w][lg * 4 + i][fq * 16 + lr] = f2bf(p);
      }
    }
#pragma unroll
    for (int qs = 0; qs < 2; ++qs) {
      bh8 ap = lds16(&Ps[w][lr][qs * 32 + lg * 8]);
#pragma unroll
      for (int fd = 0; fd < 4; ++fd)
        accV[fd] = __builtin_amdgcn_mfma_f32_16x16x32_bf16(ap, lds16(&dOT[fd * 16 + lr][qs * 32 + lg * 8]), accV[fd], 0, 0, 0);
    }
#pragma unroll
    for (int fq = 0; fq < 4; ++fq) {
      float dq = sD[fq * 16 + lr];
#pragma unroll
      for (int i = 0; i < 4; ++i)
        Ps[w][lg * 4 + i][fq * 16 + lr] = f2bf(pv[fq][i] * (aD[fq][i] - dq));
    }
#pragma unroll
    for (int qs = 0; qs < 2; ++qs) {
      bh8 ap = lds16(&Ps[w][lr][qs * 32 + lg * 8]);
#pragma unroll
      for (int fd = 0; fd < 4; ++fd)
        accK[fd] = __builtin_amdgcn_mfma_f32_16x16x32_bf16(ap, lds16(&QT[fd * 16 + lr][qs * 32 + lg * 8]), accK[fd], 0, 0, 0);
    }
  }
#pragma unroll
  for (int i = 0; i < 4; ++i) {
    int k = k0w + lg * 4 + i;
    if (k < S_) {
      size_t obase = ((size_t)(b * S_ + k) * 24 + 8 + h) * 64;
      float c0 = Cs[k * 32 + lr], s0 = Sn[k * 32 + lr];
      float c1 = Cs[k * 32 + 16 + lr], s1 = Sn[k * 32 + 16 + lr];
#pragma unroll
      for (int fd = 0; fd < 4; ++fd) {
        float x = SCALE_ * accK[fd][i];
        float p = SCALE_ * accK[fd ^ 2][i];
        float cc = (fd & 1) ? c1 : c0;
        float ss = (fd & 1) ? s1 : s0;
        float out = (fd < 2) ? (x * cc + p * ss) : (x * cc - p * ss);
        dQKV[obase + fd * 16 + lr] = f2bf(out);
        dQKV[obase + 512 + fd * 16 + lr] = f2bf(accV[fd][i]);
      }
    }
  }
}

// ---------------- RMS norm fwd/bwd (dual fp32+bf16 outputs) ----------------

__global__ __launch_bounds__(256) void k_rms_fwd(const float* __restrict__ X, float* __restrict__ Y,
                                                 unsigned short* __restrict__ Y16) {
  int t = blockIdx.x, tid = threadIdx.x;
  float x0 = X[(size_t)t * H_ + tid], x1 = X[(size_t)t * H_ + tid + 256];
  __shared__ float red[256];
  red[tid] = x0 * x0 + x1 * x1;
  __syncthreads();
  for (int s = 128; s > 0; s >>= 1) {
    if (tid < s) red[tid] += red[tid + s];
    __syncthreads();
  }
  float r = rsqrtf(red[0] / H_ + EPS_);
  float y0 = x0 * r, y1 = x1 * r;
  Y[(size_t)t * H_ + tid] = y0;
  Y[(size_t)t * H_ + tid + 256] = y1;
  Y16[(size_t)t * H_ + tid] = f2bf(y0);
  Y16[(size_t)t * H_ + tid + 256] = f2bf(y1);
}

__global__ __launch_bounds__(256) void k_rms_bwd(const float* __restrict__ X,
                                                 const float* __restrict__ GY,
                                                 float* __restrict__ GX,
                                                 unsigned short* __restrict__ GX16) {
  int t = blockIdx.x, tid = threadIdx.x;
  float x0 = X[(size_t)t * H_ + tid], x1 = X[(size_t)t * H_ + tid + 256];
  float g0 = GY[(size_t)t * H_ + tid], g1 = GY[(size_t)t * H_ + tid + 256];
  __shared__ float r1[256], r2[256];
  r1[tid] = x0 * x0 + x1 * x1;
  r2[tid] = x0 * g0 + x1 * g1;
  __syncthreads();
  for (int s = 128; s > 0; s >>= 1) {
    if (tid < s) { r1[tid] += r1[tid + s]; r2[tid] += r2[tid + s]; }
    __syncthreads();
  }
  float r = rsqrtf(r1[0] / H_ + EPS_);
  float coef = r * r * r * r2[0] / (float)H_;
  float o0 = r * g0 - coef * x0, o1 = r * g1 - coef * x1;
  GX[(size_t)t * H_ + tid] = o0;
  GX[(size_t)t * H_ + tid + 256] = o1;
  GX16[(size_t)t * H_ + tid] = f2bf(o0);
  GX16[(size_t)t * H_ + tid + 256] = f2bf(o1);
}

// ---------------- logits update ----------------

__global__ __launch_bounds__(64) void k_logits_update(const float* __restrict__ G,
                                                      const float* __restrict__ E,
                                                      const float* __restrict__ P,
                                                      const float* __restrict__ alpha,
                                                      float* __restrict__ logits) {
  int t = blockIdx.x, lane = threadIdx.x;
  float dp[V_];
#pragma unroll
  for (int v = 0; v < V_; ++v) dp[v] = 0.f;
  for (int hh = lane; hh < H_; hh += 64) {
    float gh = G[(size_t)t * H_ + hh];
#pragma unroll
    for (int v = 0; v < V_; ++v) dp[v] += gh * E[v * H_ + hh];
  }
#pragma unroll
  for (int v = 0; v < V_; ++v) dp[v] = wave_sum64(dp[v]) * ESCALE_;
  float dot = 0.f;
  float pv[V_];
#pragma unroll
  for (int v = 0; v < V_; ++v) {
    pv[v] = P[t * V_ + v];
    dot += pv[v] * dp[v];
  }
  float a = fmaxf(alpha[0], 1e-4f);
  if (lane < V_) logits[t * V_ + lane] -= a * pv[lane] * (dp[lane] - dot);
}

// ---------------- host-side orchestration ----------------

struct Ctx {
  unsigned short *Q16, *Q016, *dQ16, *GU16, *DO16, *AO16, *AO016, *X116, *UDX16, *U016;
  float *X1, *X2, *X20, *G, *UDX, *P, *MB, *LB, *DB, *MB0, *LB0, *CS, *SN;
  const unsigned short *WTqkv[2], *WTo[2], *WTgu[2], *WTd[2];
  const unsigned short *WSqkv[2], *WSo[2], *WSgu[2], *WSd[2];
  hipStream_t st;
};

static void block_forward(Ctx& c, int l, const float* hin, const unsigned short* hin16,
                          float* hout, unsigned short* qb, unsigned short* ao,
                          float* mb, float* lb, float* x2buf, unsigned short* u16buf) {
  k_gemm<128, 0, 0, 1, 1, 0><<<dim3(3 * H_ / 128, (NTOK + 127) / 128), 256, 0, c.st>>>(
      hin16, c.WTqkv[l], nullptr, nullptr, qb, nullptr, c.CS, c.SN, NTOK, 3 * H_, H_, H_);
  k_attn_fwd3<<<dim3((S_ + 63) / 64, NH_, B_), 256, 0, c.st>>>(qb, ao, mb, lb);
  k_gemm<64, 0, 1, 0, 0, 0><<<dim3(H_ / 128, (NTOK + 63) / 64), 256, 0, c.st>>>(
      ao, c.WTo[l], hin, c.X1, nullptr, nullptr, nullptr, nullptr, NTOK, H_, H_, H_);
  k_rms_fwd<<<NTOK, 256, 0, c.st>>>(c.X1, c.UDX, u16buf);
  k_gemm<128, 0, 0, 1, 0, 0><<<dim3(2 * INNER_ / 128, (NTOK + 127) / 128), 256, 0, c.st>>>(
      u16buf, c.WTgu[l], nullptr, nullptr, c.GU16, nullptr, nullptr, nullptr, NTOK, 2 * INNER_, H_, H_);
  k_gemm<64, 1, 1, 0, 0, 0><<<dim3(H_ / 128, (NTOK + 63) / 64), 256, 0, c.st>>>(
      c.GU16, c.WTd[l], c.UDX, x2buf, nullptr, nullptr, nullptr, nullptr, NTOK, H_, INNER_, 2 * INNER_);
  if (hout) k_rms_fwd<<<NTOK, 256, 0, c.st>>>(x2buf, hout, c.UDX16);
}

static void block_backward(Ctx& c, int l, const float* hin, const unsigned short* hin16,
                           unsigned short* qb, unsigned short* ao, float* mb, float* lb,
                           bool full) {
  const float* x2src;
  if (full) {
    block_forward(c, l, hin, hin16, nullptr, qb, ao, mb, lb, c.X2, c.UDX16);
    x2src = c.X2;
  } else {
    k_gemm<64, 0, 1, 0, 0, 0><<<dim3(H_ / 128, (NTOK + 63) / 64), 256, 0, c.st>>>(
        ao, c.WTo[l], hin, c.X1, nullptr, nullptr, nullptr, nullptr, NTOK, H_, H_, H_);
    k_gemm<128, 0, 0, 1, 0, 0><<<dim3(2 * INNER_ / 128, (NTOK + 127) / 128), 256, 0, c.st>>>(
        c.U016, c.WTgu[l], nullptr, nullptr, c.GU16, nullptr, nullptr, nullptr, NTOK, 2 * INNER_, H_, H_);
    x2src = c.X20;
  }
  k_rms_bwd<<<NTOK, 256, 0, c.st>>>(x2src, c.G, c.UDX, c.UDX16);
  k_gemm<128, 0, 0, 0, 0, 1><<<dim3(INNER_ / 128, (NTOK + 127) / 128), 256, 0, c.st>>>(
      c.UDX16, c.WSd[l], nullptr, nullptr, nullptr, c.GU16, nullptr, nullptr, NTOK, INNER_, H_, H_);
  k_gemm<64, 0, 1, 0, 0, 0><<<dim3(H_ / 128, (NTOK + 63) / 64), 256, 0, c.st>>>(
      c.GU16, c.WSgu[l], c.UDX, c.G, nullptr, nullptr, nullptr, nullptr, NTOK, H_, 2 * INNER_, 2 * INNER_);
  k_rms_bwd<<<NTOK, 256, 0, c.st>>>(c.X1, c.G, c.UDX, c.UDX16);
  k_gemm<64, 0, 0, 1, 0, 0><<<dim3(H_ / 128, (NTOK + 63) / 64), 256, 0, c.st>>>(
      c.UDX16, c.WSo[l], nullptr, nullptr, c.DO16, nullptr, nullptr, nullptr, NTOK, H_, H_, H_);
  dim3 agrid((S_ + 63) / 64, NH_, B_);
  k_delta<<<agrid, 256, 0, c.st>>>(ao, c.DO16, c.DB);
  k_attn_bwd_dq3<<<agrid, 256, 0, c.st>>>(qb, c.DO16, mb, lb, c.DB, c.CS, c.SN, c.dQ16);
  k_attn_bwd_kv3<<<agrid, 256, 0, c.st>>>(qb, c.DO16, mb, lb, c.DB, c.CS, c.SN, c.dQ16);
  k_gemm<64, 0, 1, 0, 0, 0><<<dim3(H_ / 128, (NTOK + 63) / 64), 256, 0, c.st>>>(
      c.dQ16, c.WSqkv[l], c.UDX, c.G, nullptr, nullptr, nullptr, nullptr, NTOK, H_, 3 * H_, 3 * H_);
}

extern "C" void kernel_launch(void* const* d_in, const int* in_sizes, int n_in,
                              void* d_out, int out_size, void* d_ws, size_t ws_size,
                              hipStream_t stream) {
  const int* inputs = (const int*)d_in[0];
  const float* E = (const float*)d_in[2];
  const float* ew = (const float*)d_in[3];
  const float* qkvw = (const float*)d_in[4];
  const float* ow = (const float*)d_in[5];
  const float* guw = (const float*)d_in[6];
  const float* dw = (const float*)d_in[7];
  const float* alpha = (const float*)d_in[8];
  float* logits = (float*)d_out;

  const size_t WT_FLOATS = 3407872;
  const size_t NEED =
      3 * ((size_t)NTOK * 3 * H_ / 2) +
      ((size_t)NTOK * INNER_) +
      5 * ((size_t)NTOK * H_) +
      6 * ((size_t)NTOK * H_ / 2) +
      ((size_t)NTOK * V_) +
      5 * ((size_t)B_ * NH_ * S_) +
      2 * ((size_t)S_ * 32) +
      2 * WT_FLOATS;
  if (ws_size < NEED * sizeof(float)) {
    k_zero<<<(NTOK * V_ + 255) / 256, 256, 0, stream>>>(logits, NTOK * V_);
    return;
  }

  float* f = (float*)d_ws;
  Ctx c;
  c.st = stream;
  c.Q16 = (unsigned short*)f;  f += (size_t)NTOK * 3 * H_ / 2;
  c.Q016 = (unsigned short*)f; f += (size_t)NTOK * 3 * H_ / 2;
  c.dQ16 = (unsigned short*)f; f += (size_t)NTOK * 3 * H_ / 2;
  c.GU16 = (unsigned short*)f; f += (size_t)NTOK * INNER_;
  c.X1 = f;   f += (size_t)NTOK * H_;
  c.X2 = f;   f += (size_t)NTOK * H_;
  c.X20 = f;  f += (size_t)NTOK * H_;
  c.G = f;    f += (size_t)NTOK * H_;
  c.UDX = f;  f += (size_t)NTOK * H_;
  c.AO16 = (unsigned short*)f;  f += (size_t)NTOK * H_ / 2;
  c.AO016 = (unsigned short*)f; f += (size_t)NTOK * H_ / 2;
  c.DO16 = (unsigned short*)f;  f += (size_t)NTOK * H_ / 2;
  c.X116 = (unsigned short*)f;  f += (size_t)NTOK * H_ / 2;
  c.UDX16 = (unsigned short*)f; f += (size_t)NTOK * H_ / 2;
  c.U016 = (unsigned short*)f;  f += (size_t)NTOK * H_ / 2;
  c.P = f;    f += (size_t)NTOK * V_;
  c.MB = f;   f += (size_t)B_ * NH_ * S_;
  c.LB = f;   f += (size_t)B_ * NH_ * S_;
  c.DB = f;   f += (size_t)B_ * NH_ * S_;
  c.MB0 = f;  f += (size_t)B_ * NH_ * S_;
  c.LB0 = f;  f += (size_t)B_ * NH_ * S_;
  c.CS = f;   f += (size_t)S_ * 32;
  c.SN = f;   f += (size_t)S_ * 32;
  unsigned short* wt = (unsigned short*)f;

  const size_t LQKV = (size_t)H_ * 3 * H_;
  const size_t LO = (size_t)H_ * H_;
  const size_t LGU = (size_t)H_ * 2 * INNER_;
  const size_t LD = (size_t)INNER_ * H_;

  for (int l = 0; l < 2; ++l) {
    c.WTqkv[l] = wt;
    k_wt<<<dim3(3 * H_ / 32, H_ / 32), dim3(32, 8), 0, stream>>>(qkvw + l * LQKV, wt, H_, 3 * H_);
    wt += LQKV;
    c.WTo[l] = wt;
    k_wt<<<dim3(H_ / 32, H_ / 32), dim3(32, 8), 0, stream>>>(ow + l * LO, wt, H_, H_);
    wt += LO;
    c.WTgu[l] = wt;
    k_wt<<<dim3(2 * INNER_ / 32, H_ / 32), dim3(32, 8), 0, stream>>>(guw + l * LGU, wt, H_, 2 * INNER_);
    wt += LGU;
    c.WTd[l] = wt;
    k_wt<<<dim3(H_ / 32, INNER_ / 32), dim3(32, 8), 0, stream>>>(dw + l * LD, wt, INNER_, H_);
    wt += LD;
  }
  {
    unsigned short* ws = wt;
    k_cast8<<<(int)((2 * LQKV / 8 + 255) / 256), 256, 0, stream>>>(qkvw, ws, (int)(2 * LQKV / 8));
    c.WSqkv[0] = ws; c.WSqkv[1] = ws + LQKV; ws += 2 * LQKV;
    k_cast8<<<(int)((2 * LO / 8 + 255) / 256), 256, 0, stream>>>(ow, ws, (int)(2 * LO / 8));
    c.WSo[0] = ws; c.WSo[1] = ws + LO; ws += 2 * LO;
    k_cast8<<<(int)((2 * LGU / 8 + 255) / 256), 256, 0, stream>>>(guw, ws, (int)(2 * LGU / 8));
    c.WSgu[0] = ws; c.WSgu[1] = ws + LGU; ws += 2 * LGU;
    k_cast8<<<(int)((2 * LD / 8 + 255) / 256), 256, 0, stream>>>(dw, ws, (int)(2 * LD / 8));
    c.WSd[0] = ws; c.WSd[1] = ws + LD;
  }

  k_zero<<<(NTOK * V_ + 255) / 256, 256, 0, stream>>>(logits, NTOK * V_);
  k_rope_tables<<<(S_ * 32 + 255) / 256, 256, 0, stream>>>(c.CS, c.SN);

  for (int step = 0; step < STEPS_; ++step) {
    k_softmax_logits<<<(NTOK + 255) / 256, 256, 0, stream>>>(logits, c.P);
    k_h0<<<NTOK, 256, 0, stream>>>(c.P, E, inputs, c.X1, c.X116);
    block_forward(c, 0, c.X1, c.X116, c.UDX, c.Q016, c.AO016, c.MB0, c.LB0, c.X20, c.U016);
    k_gfill<<<(NTOK * H_ + 255) / 256, 256, 0, stream>>>(ew, c.G);
    block_backward(c, 1, c.UDX, c.UDX16, c.Q16, c.AO16, c.MB, c.LB, true);
    k_h0<<<NTOK, 256, 0, stream>>>(c.P, E, inputs, c.X1, c.X116);
    block_backward(c, 0, c.X1, c.X116, c.Q016, c.AO016, c.MB0, c.LB0, false);
    k_logits_update<<<NTOK, 64, 0, stream>>>(c.G, E, c.P, alpha, logits);
  }
}

// Round 14
// 2355.964 us; speedup vs baseline: 2.7732x; 1.0243x over previous
//
#include <hip/hip_runtime.h>
#include <math.h>

#define B_ 8
#define S_ 900
#define V_ 11
#define H_ 512
#define NH_ 8
#define HD_ 64
#define INNER_ 1536
#define STEPS_ 2
#define NTOK (B_*S_)
#define EPS_ 1e-5f
#define THETA_ 10000.0f
#define ESCALE_ 22.627416997969522f
#define SCALE_ 0.125f
#define PT_ 68   // attention LDS pitch (ushorts): 136B rows, 8B-aligned (b64 floor pattern)

typedef __attribute__((ext_vector_type(8))) short bh8;
typedef __attribute__((ext_vector_type(4))) float f32x4;
typedef __attribute__((ext_vector_type(4))) unsigned short us4;

union bfu { bh8 v; unsigned short s[8]; us4 q[2]; };

__device__ inline unsigned short f2bf(float x) {
  unsigned u = __builtin_bit_cast(unsigned, x);
  return (unsigned short)((u + 0x7FFFu + ((u >> 16) & 1u)) >> 16);
}
__device__ inline float b2f(unsigned short s) {
  return __builtin_bit_cast(float, (unsigned)s << 16);
}

// async global->LDS, 16B per lane; LDS dest = wave-uniform base + lane*16
__device__ inline void gld16(const unsigned short* g, unsigned short* l) {
  __builtin_amdgcn_global_load_lds(
      (const __attribute__((address_space(1))) void*)(g),
      (__attribute__((address_space(3))) void*)(l), 16, 0, 0);
}

__device__ inline bh8 lds16(const unsigned short* p) {
  bfu u;
  u.q[0] = *(const us4*)p;
  u.q[1] = *(const us4*)(p + 4);
  return u.v;
}
__device__ inline void sts16(unsigned short* p, bfu u) {
  *(us4*)p = u.q[0];
  *(us4*)(p + 4) = u.q[1];
}

__device__ inline float wave_sum64(float x) {
#pragma unroll
  for (int off = 32; off > 0; off >>= 1) x += __shfl_xor(x, off, 64);
  return x;
}

__device__ inline float quad_sum(float x) {
  x += __shfl_xor(x, 1, 64);
  x += __shfl_xor(x, 2, 64);
  return x;
}

// ---------------- small kernels ----------------

__global__ void k_zero(float* p, int n) {
  int i = blockIdx.x * blockDim.x + threadIdx.x;
  if (i < n) p[i] = 0.f;
}

__global__ void k_rope_tables(float* cs, float* sn) {
  int idx = blockIdx.x * blockDim.x + threadIdx.x;
  if (idx >= S_ * 32) return;
  int s = idx >> 5, i = idx & 31;
  float freq = powf(THETA_, -(float)i / 32.0f);
  float ang = (float)s * freq;
  cs[idx] = cosf(ang);
  sn[idx] = sinf(ang);
}

__global__ void k_softmax_logits(const float* __restrict__ logits, float* __restrict__ P) {
  int t = blockIdx.x * blockDim.x + threadIdx.x;
  if (t >= NTOK) return;
  float x[V_];
  float m = -1e30f;
#pragma unroll
  for (int v = 0; v < V_; ++v) { x[v] = logits[t * V_ + v]; m = fmaxf(m, x[v]); }
  float ssum = 0.f;
#pragma unroll
  for (int v = 0; v < V_; ++v) { x[v] = expf(x[v] - m); ssum += x[v]; }
  float inv = 1.f / ssum;
#pragma unroll
  for (int v = 0; v < V_; ++v) P[t * V_ + v] = x[v] * inv;
}

// h0 -> fp32 + bf16
__global__ void k_h0(const float* __restrict__ P, const float* __restrict__ E,
                     const int* __restrict__ inp, float* __restrict__ h0,
                     unsigned short* __restrict__ h016) {
  int t = blockIdx.x;
  int tid = threadIdx.x;
  __shared__ float p[V_];
  __shared__ int iw;
  if (tid < V_) p[tid] = P[t * V_ + tid];
  if (tid == 0) iw = inp[t];
  __syncthreads();
  for (int h = tid; h < H_; h += blockDim.x) {
    float acc = E[iw * H_ + h];
#pragma unroll
    for (int v = 0; v < V_; ++v) acc += p[v] * E[v * H_ + h];
    float val = ESCALE_ * acc;
    h0[(size_t)t * H_ + h] = val;
    h016[(size_t)t * H_ + h] = f2bf(val);
  }
}

__global__ void k_gfill(const float* __restrict__ ew, float* __restrict__ G) {
  int idx = blockIdx.x * blockDim.x + threadIdx.x;
  if (idx < NTOK * H_) G[idx] = ew[idx & (H_ - 1)];
}

// fp32 -> bf16 cast, 8 elems/thread
__global__ void k_cast8(const float* __restrict__ X, unsigned short* __restrict__ Y, int n8) {
  int i = blockIdx.x * blockDim.x + threadIdx.x;
  if (i >= n8) return;
  const float4* p = (const float4*)(X + (size_t)i * 8);
  float4 a = p[0], b = p[1];
  bfu o;
  o.s[0] = f2bf(a.x); o.s[1] = f2bf(a.y); o.s[2] = f2bf(a.z); o.s[3] = f2bf(a.w);
  o.s[4] = f2bf(b.x); o.s[5] = f2bf(b.y); o.s[6] = f2bf(b.z); o.s[7] = f2bf(b.w);
  *(bh8*)(Y + (size_t)i * 8) = o.v;
}

// ---------------- weight transpose-convert: W[K][N] fp32 -> WT[N][K] bf16 ----------------

__global__ void k_wt(const float* __restrict__ W, unsigned short* __restrict__ WT, int K, int N) {
  __shared__ float t[32][33];
  int k0 = blockIdx.y * 32, n0 = blockIdx.x * 32;
  int tx = threadIdx.x, ty = threadIdx.y;
#pragma unroll
  for (int i = 0; i < 4; ++i)
    t[ty + 8 * i][tx] = W[(size_t)(k0 + ty + 8 * i) * N + n0 + tx];
  __syncthreads();
#pragma unroll
  for (int i = 0; i < 4; ++i)
    WT[(size_t)(n0 + ty + 8 * i) * K + k0 + tx] = f2bf(t[tx][ty + 8 * i]);
}

// ---------------- MFMA GEMM: C[M,N] = A[M,K] @ B^T (A,B bf16; B stored [N][K]) ----------------
// BK=64 as TWO independent 32-col sub-tiles sharing one barrier pair (halves sync overhead;
// per-sub-tile LDS layout identical to the proven conflict-free [rows][32] pattern).

template <int TM, int SILU_A, int ADD, int CBF, int ROPE, int SILUBWD>
__global__ __launch_bounds__(256) void k_gemm(const unsigned short* __restrict__ A16,
                                              const unsigned short* __restrict__ Bt,
                                              const float* __restrict__ Dm,
                                              float* __restrict__ Cf,
                                              unsigned short* __restrict__ C16,
                                              unsigned short* __restrict__ GU,
                                              const float* __restrict__ Cs,
                                              const float* __restrict__ Sn,
                                              int M, int N, int K, int lda) {
  __shared__ unsigned short As[2][TM][32];
  __shared__ unsigned short Bs[2][128][32];
  constexpr int FR = TM / 32;
  int tid = threadIdx.x;
  int m0 = blockIdx.y * TM, n0 = blockIdx.x * 128;
  int wid = tid >> 6, lane = tid & 63;
  int wr = (wid >> 1) * (FR * 16), wc = (wid & 1) * 64;
  int lr = lane & 15, lg = lane >> 4;
  int srow = lane >> 2, sck = (lane & 3) * 8;
  f32x4 acc[FR][4] = {};
  for (int k0 = 0; k0 < K; k0 += 64) {
    __syncthreads();
#pragma unroll
    for (int sub = 0; sub < 2; ++sub) {
      int kk = k0 + sub * 32;
#pragma unroll
      for (int half = 0; half < TM / 64; ++half) {
        if (SILU_A) {
          int row = (tid >> 2) + 64 * half;
          int ck = (tid & 3) * 8;
          int gr = m0 + row; gr = gr < M ? gr : M - 1;
          const unsigned short* src = &A16[(size_t)gr * lda + kk + ck];
          bfu pa;
#pragma unroll
          for (int j = 0; j < 8; ++j) {
            float g = b2f(src[j]), u = b2f(src[INNER_ + j]);
            pa.s[j] = f2bf((g / (1.f + __expf(-g))) * u);
          }
          *(bh8*)&As[sub][row][ck] = pa.v;
        } else {
          int gr = m0 + 64 * half + wid * 16 + srow; gr = gr < M ? gr : M - 1;
          gld16(&A16[(size_t)gr * lda + kk + sck], &As[sub][64 * half + wid * 16][0]);
        }
      }
#pragma unroll
      for (int i = 0; i < 2; ++i) {
        int bb = wid * 2 + i;
        gld16(&Bt[(size_t)(n0 + bb * 16 + srow) * K + kk + sck], &Bs[sub][bb * 16][0]);
      }
    }
    __syncthreads();
#pragma unroll
    for (int sub = 0; sub < 2; ++sub) {
      bh8 av[FR], bv[4];
#pragma unroll
      for (int fr = 0; fr < FR; ++fr) av[fr] = *(const bh8*)&As[sub][wr + fr * 16 + lr][lg * 8];
#pragma unroll
      for (int fc = 0; fc < 4; ++fc) bv[fc] = *(const bh8*)&Bs[sub][wc + fc * 16 + lr][lg * 8];
#pragma unroll
      for (int fr = 0; fr < FR; ++fr)
#pragma unroll
        for (int fc = 0; fc < 4; ++fc)
          acc[fr][fc] = __builtin_amdgcn_mfma_f32_16x16x32_bf16(av[fr], bv[fc], acc[fr][fc], 0, 0, 0);
    }
  }
  bool rope_on = ROPE && (((n0 + wc) >> 6) < 16);
#pragma unroll
  for (int fr = 0; fr < FR; ++fr) {
    int r0 = m0 + wr + fr * 16 + lg * 4;
#pragma unroll
    for (int i = 0; i < 4; ++i) {
      int gr = r0 + i;
      if (gr >= M) continue;
      float c0 = 1.f, s0 = 0.f, c1 = 1.f, s1 = 0.f;
      if (ROPE) {
        if (rope_on) {
          int s = gr % S_;
          c0 = Cs[s * 32 + lr];      s0 = Sn[s * 32 + lr];
          c1 = Cs[s * 32 + 16 + lr]; s1 = Sn[s * 32 + 16 + lr];
        }
      }
#pragma unroll
      for (int fc = 0; fc < 4; ++fc) {
        int gc = n0 + wc + fc * 16 + lr;
        float out = acc[fr][fc][i];
        if (ROPE) {
          float part = acc[fr][fc ^ 2][i];
          float cc = (fc & 1) ? c1 : c0;
          float ss = (fc & 1) ? s1 : s0;
          out = (fc < 2) ? (out * cc - part * ss) : (out * cc + part * ss);
        }
        if (ADD) out += Dm[(size_t)gr * N + gc];
        if (SILUBWD) {
          size_t gb = (size_t)gr * (size_t)(2 * INNER_) + gc;
          float g = b2f(GU[gb]), u = b2f(GU[gb + INNER_]);
          float sig = 1.f / (1.f + __expf(-g));
          GU[gb] = f2bf(out * u * sig * (1.f + g * (1.f - sig)));
          GU[gb + INNER_] = f2bf(out * g * sig);
        } else if (CBF) {
          C16[(size_t)gr * N + gc] = f2bf(out);
        } else {
          Cf[(size_t)gr * N + gc] = out;
        }
      }
    }
  }
}

// ---------------- MFMA flash attention (bf16 QKV, bf16 O), prefetch-under-compute ----------------

__global__ __launch_bounds__(256) void k_attn_fwd3(const unsigned short* __restrict__ QKV,
                                                   unsigned short* __restrict__ AO,
                                                   float* __restrict__ MB,
                                                   float* __restrict__ LB) {
  __shared__ unsigned short Ks[64][PT_];
  __shared__ unsigned short VT[64][PT_];
  __shared__ unsigned short Ps[4][16][PT_];
  int tid = threadIdx.x;
  int h = blockIdx.y, b = blockIdx.z;
  int w = tid >> 6, lane = tid & 63;
  int lr = lane & 15, lg = lane >> 4;
  int q0 = blockIdx.x * 64 + w * 16;
  int sr = tid >> 2, sc0 = (tid & 3) * 16;
  int vd0 = (tid & 15) * 4, vk0 = (tid >> 4) * 4;

  bh8 qf[2];
  {
    int qr = q0 + lr; if (qr >= S_) qr = S_ - 1;
    const unsigned short* qp = &QKV[((size_t)(b * S_ + qr) * 24 + h) * 64 + lg * 8];
    qf[0] = *(const bh8*)qp;
    qf[1] = *(const bh8*)(qp + 32);
  }
  f32x4 accO[4] = {};
  float m[4], lsum[4];
#pragma unroll
  for (int i = 0; i < 4; ++i) { m[i] = -1e30f; lsum[i] = 0.f; }

  bfu kA, kB;
  us4 vR[4];
  {
    int src = sr;
    size_t ts = (size_t)b * S_ + (src < S_ ? src : S_ - 1);
    const unsigned short* gp = &QKV[(ts * 24 + 8 + h) * 64 + sc0];
    kA.v = *(const bh8*)gp;
    kB.v = *(const bh8*)(gp + 8);
#pragma unroll
    for (int j = 0; j < 4; ++j) {
      int s2 = vk0 + j;
      size_t t2 = (size_t)b * S_ + (s2 < S_ ? s2 : S_ - 1);
      vR[j] = *(const us4*)&QKV[(t2 * 24 + 16 + h) * 64 + vd0];
    }
  }

  for (int kt = 0; kt < S_; kt += 64) {
    __syncthreads();
    sts16(&Ks[sr][sc0], kA);
    sts16(&Ks[sr][sc0 + 8], kB);
#pragma unroll
    for (int dd = 0; dd < 4; ++dd) {
      us4 pk = {vR[0][dd], vR[1][dd], vR[2][dd], vR[3][dd]};
      *(us4*)&VT[vd0 + dd][vk0] = pk;
    }
    __syncthreads();
    if (kt + 64 < S_) {
      int src = kt + 64 + sr;
      size_t ts = (size_t)b * S_ + (src < S_ ? src : S_ - 1);
      const unsigned short* gp = &QKV[(ts * 24 + 8 + h) * 64 + sc0];
      kA.v = *(const bh8*)gp;
      kB.v = *(const bh8*)(gp + 8);
#pragma unroll
      for (int j = 0; j < 4; ++j) {
        int s2 = kt + 64 + vk0 + j;
        size_t t2 = (size_t)b * S_ + (s2 < S_ ? s2 : S_ - 1);
        vR[j] = *(const us4*)&QKV[(t2 * 24 + 16 + h) * 64 + vd0];
      }
    }
    f32x4 accS[4] = {};
#pragma unroll
    for (int ks = 0; ks < 2; ++ks)
#pragma unroll
      for (int fk = 0; fk < 4; ++fk)
        accS[fk] = __builtin_amdgcn_mfma_f32_16x16x32_bf16(qf[ks], lds16(&Ks[fk * 16 + lr][ks * 32 + lg * 8]), accS[fk], 0, 0, 0);
    float sc[4][4], pmax[4];
#pragma unroll
    for (int i = 0; i < 4; ++i) pmax[i] = -1e30f;
#pragma unroll
    for (int fk = 0; fk < 4; ++fk)
#pragma unroll
      for (int i = 0; i < 4; ++i) {
        float s = accS[fk][i] * SCALE_;
        if (kt + fk * 16 + lr >= S_) s = -1e30f;
        sc[fk][i] = s;
        pmax[i] = fmaxf(pmax[i], s);
      }
#pragma unroll
    for (int i = 0; i < 4; ++i) {
      float v = pmax[i];
      v = fmaxf(v, __shfl_xor(v, 1, 64));
      v = fmaxf(v, __shfl_xor(v, 2, 64));
      v = fmaxf(v, __shfl_xor(v, 4, 64));
      v = fmaxf(v, __shfl_xor(v, 8, 64));
      pmax[i] = v;
    }
    float psum[4];
#pragma unroll
    for (int i = 0; i < 4; ++i) {
      float mn = fmaxf(m[i], pmax[i]);
      float eo = __expf(m[i] - mn);
      m[i] = mn;
      lsum[i] *= eo;
#pragma unroll
      for (int fd = 0; fd < 4; ++fd) accO[fd][i] *= eo;
      psum[i] = 0.f;
    }
#pragma unroll
    for (int fk = 0; fk < 4; ++fk)
#pragma unroll
      for (int i = 0; i < 4; ++i) {
        float p = __expf(sc[fk][i] - m[i]);
        sc[fk][i] = p;
        psum[i] += p;
      }
#pragma unroll
    for (int i = 0; i < 4; ++i) {
      float v = psum[i];
      v += __shfl_xor(v, 1, 64);
      v += __shfl_xor(v, 2, 64);
      v += __shfl_xor(v, 4, 64);
      v += __shfl_xor(v, 8, 64);
      lsum[i] += v;
    }
#pragma unroll
    for (int fk = 0; fk < 4; ++fk)
#pragma unroll
      for (int i = 0; i < 4; ++i)
        Ps[w][lg * 4 + i][fk * 16 + lr] = f2bf(sc[fk][i]);
#pragma unroll
    for (int ks = 0; ks < 2; ++ks) {
      bh8 ap = lds16(&Ps[w][lr][ks * 32 + lg * 8]);
#pragma unroll
      for (int fd = 0; fd < 4; ++fd)
        accO[fd] = __builtin_amdgcn_mfma_f32_16x16x32_bf16(ap, lds16(&VT[fd * 16 + lr][ks * 32 + lg * 8]), accO[fd], 0, 0, 0);
    }
  }
#pragma unroll
  for (int i = 0; i < 4; ++i) {
    int q = q0 + lg * 4 + i;
    if (q < S_) {
      float linv = 1.f / lsum[i];
      size_t obase = (size_t)(b * S_ + q) * H_ + h * 64;
#pragma unroll
      for (int fd = 0; fd < 4; ++fd) AO[obase + fd * 16 + lr] = f2bf(accO[fd][i] * linv);
      if (lr == 0) {
        MB[((size_t)b * NH_ + h) * S_ + q] = m[i];
        LB[((size_t)b * NH_ + h) * S_ + q] = linv;
      }
    }
  }
}

// delta[b,h,q] = dot(dO_row, O_row), both bf16
__global__ __launch_bounds__(256) void k_delta(const unsigned short* __restrict__ O,
                                               const unsigned short* __restrict__ dO,
                                               float* __restrict__ DB) {
  int tid = threadIdx.x;
  int h = blockIdx.y, b = blockIdx.z;
  int r = blockIdx.x * 64 + (tid >> 2), part = tid & 3;
  if (r >= S_) return;
  size_t base = (size_t)(b * S_ + r) * H_ + h * 64 + part * 16;
  bfu o0, o1, d0, d1;
  o0.v = *(const bh8*)&O[base];  o1.v = *(const bh8*)&O[base + 8];
  d0.v = *(const bh8*)&dO[base]; d1.v = *(const bh8*)&dO[base + 8];
  float s = 0.f;
#pragma unroll
  for (int j = 0; j < 8; ++j)
    s += b2f(o0.s[j]) * b2f(d0.s[j]) + b2f(o1.s[j]) * b2f(d1.s[j]);
  s = quad_sum(s);
  if (part == 0) DB[((size_t)b * NH_ + h) * S_ + r] = s;
}

// dQ pass; fused inverse-RoPE on output; prefetch-under-compute
__global__ __launch_bounds__(256) void k_attn_bwd_dq3(const unsigned short* __restrict__ QKV,
                                                      const unsigned short* __restrict__ dO,
                                                      const float* __restrict__ MB,
                                                      const float* __restrict__ LB,
                                                      const float* __restrict__ DB,
                                                      const float* __restrict__ Cs,
                                                      const float* __restrict__ Sn,
                                                      unsigned short* __restrict__ dQKV) {
  __shared__ unsigned short Ks[64][PT_];
  __shared__ unsigned short Vs[64][PT_];
  __shared__ unsigned short KT[64][PT_];
  __shared__ unsigned short Ps[4][16][PT_];
  int tid = threadIdx.x;
  int h = blockIdx.y, b = blockIdx.z;
  int w = tid >> 6, lane = tid & 63;
  int lr = lane & 15, lg = lane >> 4;
  int q0 = blockIdx.x * 64 + w * 16;
  size_t sbase = ((size_t)b * NH_ + h) * S_;
  int sr = tid >> 2, sc0 = (tid & 3) * 16;
  int vd0 = (tid & 15) * 4, vk0 = (tid >> 4) * 4;

  bh8 qf[2], dof[2];
  {
    int qr = q0 + lr; if (qr >= S_) qr = S_ - 1;
    const unsigned short* qp = &QKV[((size_t)(b * S_ + qr) * 24 + h) * 64 + lg * 8];
    const unsigned short* dp = &dO[(size_t)(b * S_ + qr) * H_ + h * 64 + lg * 8];
    qf[0] = *(const bh8*)qp;  qf[1] = *(const bh8*)(qp + 32);
    dof[0] = *(const bh8*)dp; dof[1] = *(const bh8*)(dp + 32);
  }
  float mrow[4], lrow[4], drow[4];
#pragma unroll
  for (int i = 0; i < 4; ++i) {
    int q = q0 + lg * 4 + i; if (q >= S_) q = S_ - 1;
    mrow[i] = MB[sbase + q];
    lrow[i] = LB[sbase + q];
    drow[i] = DB[sbase + q];
  }
  f32x4 accQ[4] = {};

  bfu pA{}, pB{}, pC{}, pD{};
  us4 rv[4];
  {
    int src = sr;
    bool vld = src < S_;
    size_t ts = (size_t)b * S_ + (vld ? src : S_ - 1);
    const unsigned short* kp = &QKV[(ts * 24 + 8 + h) * 64 + sc0];
    if (vld) {
      pA.v = *(const bh8*)kp;
      pB.v = *(const bh8*)(kp + 8);
      pC.v = *(const bh8*)(kp + 512);
      pD.v = *(const bh8*)(kp + 520);
    }
#pragma unroll
    for (int j = 0; j < 4; ++j) {
      int s2 = vk0 + j;
      bool v2 = s2 < S_;
      size_t t2 = (size_t)b * S_ + (v2 ? s2 : S_ - 1);
      us4 t = *(const us4*)&QKV[(t2 * 24 + 8 + h) * 64 + vd0];
      if (!v2) t = us4{0, 0, 0, 0};
      rv[j] = t;
    }
  }

  for (int kt = 0; kt < S_; kt += 64) {
    __syncthreads();
    sts16(&Ks[sr][sc0], pA); sts16(&Ks[sr][sc0 + 8], pB);
    sts16(&Vs[sr][sc0], pC); sts16(&Vs[sr][sc0 + 8], pD);
#pragma unroll
    for (int dd = 0; dd < 4; ++dd) {
      us4 pk = {rv[0][dd], rv[1][dd], rv[2][dd], rv[3][dd]};
      *(us4*)&KT[vd0 + dd][vk0] = pk;
    }
    __syncthreads();
    if (kt + 64 < S_) {
      int src = kt + 64 + sr;
      bool vld = src < S_;
      size_t ts = (size_t)b * S_ + (vld ? src : S_ - 1);
      const unsigned short* kp = &QKV[(ts * 24 + 8 + h) * 64 + sc0];
      pA = bfu{}; pB = bfu{}; pC = bfu{}; pD = bfu{};
      if (vld) {
        pA.v = *(const bh8*)kp;
        pB.v = *(const bh8*)(kp + 8);
        pC.v = *(const bh8*)(kp + 512);
        pD.v = *(const bh8*)(kp + 520);
      }
#pragma unroll
      for (int j = 0; j < 4; ++j) {
        int s2 = kt + 64 + vk0 + j;
        bool v2 = s2 < S_;
        size_t t2 = (size_t)b * S_ + (v2 ? s2 : S_ - 1);
        us4 t = *(const us4*)&QKV[(t2 * 24 + 8 + h) * 64 + vd0];
        if (!v2) t = us4{0, 0, 0, 0};
        rv[j] = t;
      }
    }
    f32x4 aS[4] = {}, aD[4] = {};
#pragma unroll
    for (int ks = 0; ks < 2; ++ks)
#pragma unroll
      for (int fk = 0; fk < 4; ++fk) {
        aS[fk] = __builtin_amdgcn_mfma_f32_16x16x32_bf16(qf[ks], lds16(&Ks[fk * 16 + lr][ks * 32 + lg * 8]), aS[fk], 0, 0, 0);
        aD[fk] = __builtin_amdgcn_mfma_f32_16x16x32_bf16(dof[ks], lds16(&Vs[fk * 16 + lr][ks * 32 + lg * 8]), aD[fk], 0, 0, 0);
      }
#pragma unroll
    for (int fk = 0; fk < 4; ++fk)
#pragma unroll
      for (int i = 0; i < 4; ++i) {
        float p = __expf(aS[fk][i] * SCALE_ - mrow[i]) * lrow[i];
        float ds = p * (aD[fk][i] - drow[i]);
        Ps[w][lg * 4 + i][fk * 16 + lr] = f2bf(ds);
      }
#pragma unroll
    for (int ks = 0; ks < 2; ++ks) {
      bh8 ap = lds16(&Ps[w][lr][ks * 32 + lg * 8]);
#pragma unroll
      for (int fd = 0; fd < 4; ++fd)
        accQ[fd] = __builtin_amdgcn_mfma_f32_16x16x32_bf16(ap, lds16(&KT[fd * 16 + lr][ks * 32 + lg * 8]), accQ[fd], 0, 0, 0);
    }
  }
#pragma unroll
  for (int i = 0; i < 4; ++i) {
    int q = q0 + lg * 4 + i;
    if (q < S_) {
      size_t obase = ((size_t)(b * S_ + q) * 24 + h) * 64;
      float c0 = Cs[q * 32 + lr], s0 = Sn[q * 32 + lr];
      float c1 = Cs[q * 32 + 16 + lr], s1 = Sn[q * 32 + 16 + lr];
#pragma unroll
      for (int fd = 0; fd < 4; ++fd) {
        float x = SCALE_ * accQ[fd][i];
        float p = SCALE_ * accQ[fd ^ 2][i];
        float cc = (fd & 1) ? c1 : c0;
        float ss = (fd & 1) ? s1 : s0;
        float out = (fd < 2) ? (x * cc + p * ss) : (x * cc - p * ss);
        dQKV[obase + fd * 16 + lr] = f2bf(out);
      }
    }
  }
}

// dK + dV pass; fused inverse-RoPE on dK; prefetch-under-compute
__global__ __launch_bounds__(256) void k_attn_bwd_kv3(const unsigned short* __restrict__ QKV,
                                                      const unsigned short* __restrict__ dO,
                                                      const float* __restrict__ MB,
                                                      const float* __restrict__ LB,
                                                      const float* __restrict__ DB,
                                                      const float* __restrict__ Cs,
                                                      const float* __restrict__ Sn,
                                                      unsigned short* __restrict__ dQKV) {
  __shared__ unsigned short Qs[64][PT_];
  __shared__ unsigned short dOs[64][PT_];
  __shared__ unsigned short QT[64][PT_];
  __shared__ unsigned short dOT[64][PT_];
  __shared__ unsigned short Ps[4][16][PT_];
  __shared__ float sM[64], sL[64], sD[64];
  int tid = threadIdx.x;
  int h = blockIdx.y, b = blockIdx.z;
  int w = tid >> 6, lane = tid & 63;
  int lr = lane & 15, lg = lane >> 4;
  int k0w = blockIdx.x * 64 + w * 16;
  size_t sbase = ((size_t)b * NH_ + h) * S_;
  int sr = tid >> 2, sc0 = (tid & 3) * 16;
  int vd0 = (tid & 15) * 4, vk0 = (tid >> 4) * 4;

  bh8 kf[2], vf[2];
  {
    int kr = k0w + lr; if (kr >= S_) kr = S_ - 1;
    const unsigned short* kp = &QKV[((size_t)(b * S_ + kr) * 24 + 8 + h) * 64 + lg * 8];
    kf[0] = *(const bh8*)kp;        kf[1] = *(const bh8*)(kp + 32);
    vf[0] = *(const bh8*)(kp + 512); vf[1] = *(const bh8*)(kp + 544);
  }
  f32x4 accK[4] = {}, accV[4] = {};

  bfu pA, pB, pC{}, pD{};
  us4 rq[4], rd[4];
  float stM = 0.f, stL = 0.f, stD = 0.f;
  {
    int src = sr;
    bool vld = src < S_;
    size_t ts = (size_t)b * S_ + (vld ? src : S_ - 1);
    const unsigned short* qp = &QKV[(ts * 24 + h) * 64 + sc0];
    const unsigned short* dp = &dO[ts * H_ + h * 64 + sc0];
    pA.v = *(const bh8*)qp;
    pB.v = *(const bh8*)(qp + 8);
    if (vld) {
      pC.v = *(const bh8*)dp;
      pD.v = *(const bh8*)(dp + 8);
    }
#pragma unroll
    for (int j = 0; j < 4; ++j) {
      int s2 = vk0 + j;
      bool v2 = s2 < S_;
      size_t t2 = (size_t)b * S_ + (v2 ? s2 : S_ - 1);
      rq[j] = *(const us4*)&QKV[(t2 * 24 + h) * 64 + vd0];
      us4 td = *(const us4*)&dO[t2 * H_ + h * 64 + vd0];
      if (!v2) td = us4{0, 0, 0, 0};
      rd[j] = td;
    }
    if (tid < 64) {
      bool v2 = tid < S_;
      int sc = v2 ? tid : S_ - 1;
      stM = MB[sbase + sc];
      stL = LB[sbase + sc];
      stD = v2 ? DB[sbase + sc] : 0.f;
    }
  }

  for (int qt = 0; qt < S_; qt += 64) {
    __syncthreads();
    sts16(&Qs[sr][sc0], pA);  sts16(&Qs[sr][sc0 + 8], pB);
    sts16(&dOs[sr][sc0], pC); sts16(&dOs[sr][sc0 + 8], pD);
#pragma unroll
    for (int dd = 0; dd < 4; ++dd) {
      us4 pq = {rq[0][dd], rq[1][dd], rq[2][dd], rq[3][dd]};
      us4 pd = {rd[0][dd], rd[1][dd], rd[2][dd], rd[3][dd]};
      *(us4*)&QT[vd0 + dd][vk0] = pq;
      *(us4*)&dOT[vd0 + dd][vk0] = pd;
    }
    if (tid < 64) {
      sM[tid] = stM;
      sL[tid] = stL;
      sD[tid] = stD;
    }
    __syncthreads();
    if (qt + 64 < S_) {
      int src = qt + 64 + sr;
      bool vld = src < S_;
      size_t ts = (size_t)b * S_ + (vld ? src : S_ - 1);
      const unsigned short* qp = &QKV[(ts * 24 + h) * 64 + sc0];
      const unsigned short* dp = &dO[ts * H_ + h * 64 + sc0];
      pA.v = *(const bh8*)qp;
      pB.v = *(const bh8*)(qp + 8);
      pC = bfu{}; pD = bfu{};
      if (vld) {
        pC.v = *(const bh8*)dp;
        pD.v = *(const bh8*)(dp + 8);
      }
#pragma unroll
      for (int j = 0; j < 4; ++j) {
        int s2 = qt + 64 + vk0 + j;
        bool v2 = s2 < S_;
        size_t t2 = (size_t)b * S_ + (v2 ? s2 : S_ - 1);
        rq[j] = *(const us4*)&QKV[(t2 * 24 + h) * 64 + vd0];
        us4 td = *(const us4*)&dO[t2 * H_ + h * 64 + vd0];
        if (!v2) td = us4{0, 0, 0, 0};
        rd[j] = td;
      }
      if (tid < 64) {
        int s2 = qt + 64 + tid;
        bool v2 = s2 < S_;
        int sc = v2 ? s2 : S_ - 1;
        stM = MB[sbase + sc];
        stL = LB[sbase + sc];
        stD = v2 ? DB[sbase + sc] : 0.f;
      }
    }
    f32x4 aS[4] = {}, aD[4] = {};
#pragma unroll
    for (int ks = 0; ks < 2; ++ks)
#pragma unroll
      for (int fq = 0; fq < 4; ++fq) {
        aS[fq] = __builtin_amdgcn_mfma_f32_16x16x32_bf16(kf[ks], lds16(&Qs[fq * 16 + lr][ks * 32 + lg * 8]), aS[fq], 0, 0, 0);
        aD[fq] = __builtin_amdgcn_mfma_f32_16x16x32_bf16(vf[ks], lds16(&dOs[fq * 16 + lr][ks * 32 + lg * 8]), aD[fq], 0, 0, 0);
      }
    float pv[4][4];
#pragma unroll
    for (int fq = 0; fq < 4; ++fq) {
      float mq = sM[fq * 16 + lr], lq = sL[fq * 16 + lr];
#pragma unroll
      for (int i = 0; i < 4; ++i) {
        float p = __expf(aS[fq][i] * SCALE_ - mq) * lq;
        pv[fq][i] = p;
        Ps[w][lg * 4 + i][fq * 16 + lr] = f2bf(p);
      }
    }
#pragma unroll
    for (int qs = 0; qs < 2; ++qs) {
      bh8 ap = lds16(&Ps[w][lr][qs * 32 + lg * 8]);
#pragma unroll
      for (int fd = 0; fd < 4; ++fd)
        accV[fd] = __builtin_amdgcn_mfma_f32_16x16x32_bf16(ap, lds16(&dOT[fd * 16 + lr][qs * 32 + lg * 8]), accV[fd], 0, 0, 0);
    }
#pragma unroll
    for (int fq = 0; fq < 4; ++fq) {
      float dq = sD[fq * 16 + lr];
#pragma unroll
      for (int i = 0; i < 4; ++i)
        Ps[w][lg * 4 + i][fq * 16 + lr] = f2bf(pv[fq][i] * (aD[fq][i] - dq));
    }
#pragma unroll
    for (int qs = 0; qs < 2; ++qs) {
      bh8 ap = lds16(&Ps[w][lr][qs * 32 + lg * 8]);
#pragma unroll
      for (int fd = 0; fd < 4; ++fd)
        accK[fd] = __builtin_amdgcn_mfma_f32_16x16x32_bf16(ap, lds16(&QT[fd * 16 + lr][qs * 32 + lg * 8]), accK[fd], 0, 0, 0);
    }
  }
#pragma unroll
  for (int i = 0; i < 4; ++i) {
    int k = k0w + lg * 4 + i;
    if (k < S_) {
      size_t obase = ((size_t)(b * S_ + k) * 24 + 8 + h) * 64;
      float c0 = Cs[k * 32 + lr], s0 = Sn[k * 32 + lr];
      float c1 = Cs[k * 32 + 16 + lr], s1 = Sn[k * 32 + 16 + lr];
#pragma unroll
      for (int fd = 0; fd < 4; ++fd) {
        float x = SCALE_ * accK[fd][i];
        float p = SCALE_ * accK[fd ^ 2][i];
        float cc = (fd & 1) ? c1 : c0;
        float ss = (fd & 1) ? s1 : s0;
        float out = (fd < 2) ? (x * cc + p * ss) : (x * cc - p * ss);
        dQKV[obase + fd * 16 + lr] = f2bf(out);
        dQKV[obase + 512 + fd * 16 + lr] = f2bf(accV[fd][i]);
      }
    }
  }
}

// ---------------- RMS norm fwd/bwd (dual fp32+bf16 outputs) ----------------

__global__ __launch_bounds__(256) void k_rms_fwd(const float* __restrict__ X, float* __restrict__ Y,
                                                 unsigned short* __restrict__ Y16) {
  int t = blockIdx.x, tid = threadIdx.x;
  float x0 = X[(size_t)t * H_ + tid], x1 = X[(size_t)t * H_ + tid + 256];
  __shared__ float red[256];
  red[tid] = x0 * x0 + x1 * x1;
  __syncthreads();
  for (int s = 128; s > 0; s >>= 1) {
    if (tid < s) red[tid] += red[tid + s];
    __syncthreads();
  }
  float r = rsqrtf(red[0] / H_ + EPS_);
  float y0 = x0 * r, y1 = x1 * r;
  Y[(size_t)t * H_ + tid] = y0;
  Y[(size_t)t * H_ + tid + 256] = y1;
  Y16[(size_t)t * H_ + tid] = f2bf(y0);
  Y16[(size_t)t * H_ + tid + 256] = f2bf(y1);
}

__global__ __launch_bounds__(256) void k_rms_bwd(const float* __restrict__ X,
                                                 const float* __restrict__ GY,
                                                 float* __restrict__ GX,
                                                 unsigned short* __restrict__ GX16) {
  int t = blockIdx.x, tid = threadIdx.x;
  float x0 = X[(size_t)t * H_ + tid], x1 = X[(size_t)t * H_ + tid + 256];
  float g0 = GY[(size_t)t * H_ + tid], g1 = GY[(size_t)t * H_ + tid + 256];
  __shared__ float r1[256], r2[256];
  r1[tid] = x0 * x0 + x1 * x1;
  r2[tid] = x0 * g0 + x1 * g1;
  __syncthreads();
  for (int s = 128; s > 0; s >>= 1) {
    if (tid < s) { r1[tid] += r1[tid + s]; r2[tid] += r2[tid + s]; }
    __syncthreads();
  }
  float r = rsqrtf(r1[0] / H_ + EPS_);
  float coef = r * r * r * r2[0] / (float)H_;
  float o0 = r * g0 - coef * x0, o1 = r * g1 - coef * x1;
  GX[(size_t)t * H_ + tid] = o0;
  GX[(size_t)t * H_ + tid + 256] = o1;
  GX16[(size_t)t * H_ + tid] = f2bf(o0);
  GX16[(size_t)t * H_ + tid + 256] = f2bf(o1);
}

// ---------------- logits update ----------------

__global__ __launch_bounds__(64) void k_logits_update(const float* __restrict__ G,
                                                      const float* __restrict__ E,
                                                      const float* __restrict__ P,
                                                      const float* __restrict__ alpha,
                                                      float* __restrict__ logits) {
  int t = blockIdx.x, lane = threadIdx.x;
  float dp[V_];
#pragma unroll
  for (int v = 0; v < V_; ++v) dp[v] = 0.f;
  for (int hh = lane; hh < H_; hh += 64) {
    float gh = G[(size_t)t * H_ + hh];
#pragma unroll
    for (int v = 0; v < V_; ++v) dp[v] += gh * E[v * H_ + hh];
  }
#pragma unroll
  for (int v = 0; v < V_; ++v) dp[v] = wave_sum64(dp[v]) * ESCALE_;
  float dot = 0.f;
  float pv[V_];
#pragma unroll
  for (int v = 0; v < V_; ++v) {
    pv[v] = P[t * V_ + v];
    dot += pv[v] * dp[v];
  }
  float a = fmaxf(alpha[0], 1e-4f);
  if (lane < V_) logits[t * V_ + lane] -= a * pv[lane] * (dp[lane] - dot);
}

// ---------------- host-side orchestration ----------------

struct Ctx {
  unsigned short *Q16, *Q016, *dQ16, *GU16, *DO16, *AO16, *AO016, *X116, *UDX16, *U016;
  float *X1, *X2, *X20, *G, *UDX, *P, *MB, *LB, *DB, *MB0, *LB0, *CS, *SN;
  const unsigned short *WTqkv[2], *WTo[2], *WTgu[2], *WTd[2];
  const unsigned short *WSqkv[2], *WSo[2], *WSgu[2], *WSd[2];
  hipStream_t st;
};

static void block_forward(Ctx& c, int l, const float* hin, const unsigned short* hin16,
                          float* hout, unsigned short* qb, unsigned short* ao,
                          float* mb, float* lb, float* x2buf, unsigned short* u16buf) {
  k_gemm<128, 0, 0, 1, 1, 0><<<dim3(3 * H_ / 128, (NTOK + 127) / 128), 256, 0, c.st>>>(
      hin16, c.WTqkv[l], nullptr, nullptr, qb, nullptr, c.CS, c.SN, NTOK, 3 * H_, H_, H_);
  k_attn_fwd3<<<dim3((S_ + 63) / 64, NH_, B_), 256, 0, c.st>>>(qb, ao, mb, lb);
  k_gemm<64, 0, 1, 0, 0, 0><<<dim3(H_ / 128, (NTOK + 63) / 64), 256, 0, c.st>>>(
      ao, c.WTo[l], hin, c.X1, nullptr, nullptr, nullptr, nullptr, NTOK, H_, H_, H_);
  k_rms_fwd<<<NTOK, 256, 0, c.st>>>(c.X1, c.UDX, u16buf);
  k_gemm<128, 0, 0, 1, 0, 0><<<dim3(2 * INNER_ / 128, (NTOK + 127) / 128), 256, 0, c.st>>>(
      u16buf, c.WTgu[l], nullptr, nullptr, c.GU16, nullptr, nullptr, nullptr, NTOK, 2 * INNER_, H_, H_);
  k_gemm<64, 1, 1, 0, 0, 0><<<dim3(H_ / 128, (NTOK + 63) / 64), 256, 0, c.st>>>(
      c.GU16, c.WTd[l], c.UDX, x2buf, nullptr, nullptr, nullptr, nullptr, NTOK, H_, INNER_, 2 * INNER_);
  if (hout) k_rms_fwd<<<NTOK, 256, 0, c.st>>>(x2buf, hout, c.UDX16);
}

static void block_backward(Ctx& c, int l, const float* hin, const unsigned short* hin16,
                           unsigned short* qb, unsigned short* ao, float* mb, float* lb,
                           bool full) {
  const float* x2src;
  if (full) {
    block_forward(c, l, hin, hin16, nullptr, qb, ao, mb, lb, c.X2, c.UDX16);
    x2src = c.X2;
  } else {
    k_gemm<64, 0, 1, 0, 0, 0><<<dim3(H_ / 128, (NTOK + 63) / 64), 256, 0, c.st>>>(
        ao, c.WTo[l], hin, c.X1, nullptr, nullptr, nullptr, nullptr, NTOK, H_, H_, H_);
    k_gemm<128, 0, 0, 1, 0, 0><<<dim3(2 * INNER_ / 128, (NTOK + 127) / 128), 256, 0, c.st>>>(
        c.U016, c.WTgu[l], nullptr, nullptr, c.GU16, nullptr, nullptr, nullptr, NTOK, 2 * INNER_, H_, H_);
    x2src = c.X20;
  }
  k_rms_bwd<<<NTOK, 256, 0, c.st>>>(x2src, c.G, c.UDX, c.UDX16);
  k_gemm<128, 0, 0, 0, 0, 1><<<dim3(INNER_ / 128, (NTOK + 127) / 128), 256, 0, c.st>>>(
      c.UDX16, c.WSd[l], nullptr, nullptr, nullptr, c.GU16, nullptr, nullptr, NTOK, INNER_, H_, H_);
  k_gemm<64, 0, 1, 0, 0, 0><<<dim3(H_ / 128, (NTOK + 63) / 64), 256, 0, c.st>>>(
      c.GU16, c.WSgu[l], c.UDX, c.G, nullptr, nullptr, nullptr, nullptr, NTOK, H_, 2 * INNER_, 2 * INNER_);
  k_rms_bwd<<<NTOK, 256, 0, c.st>>>(c.X1, c.G, c.UDX, c.UDX16);
  k_gemm<64, 0, 0, 1, 0, 0><<<dim3(H_ / 128, (NTOK + 63) / 64), 256, 0, c.st>>>(
      c.UDX16, c.WSo[l], nullptr, nullptr, c.DO16, nullptr, nullptr, nullptr, NTOK, H_, H_, H_);
  dim3 agrid((S_ + 63) / 64, NH_, B_);
  k_delta<<<agrid, 256, 0, c.st>>>(ao, c.DO16, c.DB);
  k_attn_bwd_dq3<<<agrid, 256, 0, c.st>>>(qb, c.DO16, mb, lb, c.DB, c.CS, c.SN, c.dQ16);
  k_attn_bwd_kv3<<<agrid, 256, 0, c.st>>>(qb, c.DO16, mb, lb, c.DB, c.CS, c.SN, c.dQ16);
  k_gemm<64, 0, 1, 0, 0, 0><<<dim3(H_ / 128, (NTOK + 63) / 64), 256, 0, c.st>>>(
      c.dQ16, c.WSqkv[l], c.UDX, c.G, nullptr, nullptr, nullptr, nullptr, NTOK, H_, 3 * H_, 3 * H_);
}

extern "C" void kernel_launch(void* const* d_in, const int* in_sizes, int n_in,
                              void* d_out, int out_size, void* d_ws, size_t ws_size,
                              hipStream_t stream) {
  const int* inputs = (const int*)d_in[0];
  const float* E = (const float*)d_in[2];
  const float* ew = (const float*)d_in[3];
  const float* qkvw = (const float*)d_in[4];
  const float* ow = (const float*)d_in[5];
  const float* guw = (const float*)d_in[6];
  const float* dw = (const float*)d_in[7];
  const float* alpha = (const float*)d_in[8];
  float* logits = (float*)d_out;

  const size_t WT_FLOATS = 3407872;
  const size_t NEED =
      3 * ((size_t)NTOK * 3 * H_ / 2) +
      ((size_t)NTOK * INNER_) +
      5 * ((size_t)NTOK * H_) +
      6 * ((size_t)NTOK * H_ / 2) +
      ((size_t)NTOK * V_) +
      5 * ((size_t)B_ * NH_ * S_) +
      2 * ((size_t)S_ * 32) +
      2 * WT_FLOATS;
  if (ws_size < NEED * sizeof(float)) {
    k_zero<<<(NTOK * V_ + 255) / 256, 256, 0, stream>>>(logits, NTOK * V_);
    return;
  }

  float* f = (float*)d_ws;
  Ctx c;
  c.st = stream;
  c.Q16 = (unsigned short*)f;  f += (size_t)NTOK * 3 * H_ / 2;
  c.Q016 = (unsigned short*)f; f += (size_t)NTOK * 3 * H_ / 2;
  c.dQ16 = (unsigned short*)f; f += (size_t)NTOK * 3 * H_ / 2;
  c.GU16 = (unsigned short*)f; f += (size_t)NTOK * INNER_;
  c.X1 = f;   f += (size_t)NTOK * H_;
  c.X2 = f;   f += (size_t)NTOK * H_;
  c.X20 = f;  f += (size_t)NTOK * H_;
  c.G = f;    f += (size_t)NTOK * H_;
  c.UDX = f;  f += (size_t)NTOK * H_;
  c.AO16 = (unsigned short*)f;  f += (size_t)NTOK * H_ / 2;
  c.AO016 = (unsigned short*)f; f += (size_t)NTOK * H_ / 2;
  c.DO16 = (unsigned short*)f;  f += (size_t)NTOK * H_ / 2;
  c.X116 = (unsigned short*)f;  f += (size_t)NTOK * H_ / 2;
  c.UDX16 = (unsigned short*)f; f += (size_t)NTOK * H_ / 2;
  c.U016 = (unsigned short*)f;  f += (size_t)NTOK * H_ / 2;
  c.P = f;    f += (size_t)NTOK * V_;
  c.MB = f;   f += (size_t)B_ * NH_ * S_;
  c.LB = f;   f += (size_t)B_ * NH_ * S_;
  c.DB = f;   f += (size_t)B_ * NH_ * S_;
  c.MB0 = f;  f += (size_t)B_ * NH_ * S_;
  c.LB0 = f;  f += (size_t)B_ * NH_ * S_;
  c.CS = f;   f += (size_t)S_ * 32;
  c.SN = f;   f += (size_t)S_ * 32;
  unsigned short* wt = (unsigned short*)f;

  const size_t LQKV = (size_t)H_ * 3 * H_;
  const size_t LO = (size_t)H_ * H_;
  const size_t LGU = (size_t)H_ * 2 * INNER_;
  const size_t LD = (size_t)INNER_ * H_;

  for (int l = 0; l < 2; ++l) {
    c.WTqkv[l] = wt;
    k_wt<<<dim3(3 * H_ / 32, H_ / 32), dim3(32, 8), 0, stream>>>(qkvw + l * LQKV, wt, H_, 3 * H_);
    wt += LQKV;
    c.WTo[l] = wt;
    k_wt<<<dim3(H_ / 32, H_ / 32), dim3(32, 8), 0, stream>>>(ow + l * LO, wt, H_, H_);
    wt += LO;
    c.WTgu[l] = wt;
    k_wt<<<dim3(2 * INNER_ / 32, H_ / 32), dim3(32, 8), 0, stream>>>(guw + l * LGU, wt, H_, 2 * INNER_);
    wt += LGU;
    c.WTd[l] = wt;
    k_wt<<<dim3(H_ / 32, INNER_ / 32), dim3(32, 8), 0, stream>>>(dw + l * LD, wt, INNER_, H_);
    wt += LD;
  }
  {
    unsigned short* ws = wt;
    k_cast8<<<(int)((2 * LQKV / 8 + 255) / 256), 256, 0, stream>>>(qkvw, ws, (int)(2 * LQKV / 8));
    c.WSqkv[0] = ws; c.WSqkv[1] = ws + LQKV; ws += 2 * LQKV;
    k_cast8<<<(int)((2 * LO / 8 + 255) / 256), 256, 0, stream>>>(ow, ws, (int)(2 * LO / 8));
    c.WSo[0] = ws; c.WSo[1] = ws + LO; ws += 2 * LO;
    k_cast8<<<(int)((2 * LGU / 8 + 255) / 256), 256, 0, stream>>>(guw, ws, (int)(2 * LGU / 8));
    c.WSgu[0] = ws; c.WSgu[1] = ws + LGU; ws += 2 * LGU;
    k_cast8<<<(int)((2 * LD / 8 + 255) / 256), 256, 0, stream>>>(dw, ws, (int)(2 * LD / 8));
    c.WSd[0] = ws; c.WSd[1] = ws + LD;
  }

  k_zero<<<(NTOK * V_ + 255) / 256, 256, 0, stream>>>(logits, NTOK * V_);
  k_rope_tables<<<(S_ * 32 + 255) / 256, 256, 0, stream>>>(c.CS, c.SN);

  for (int step = 0; step < STEPS_; ++step) {
    k_softmax_logits<<<(NTOK + 255) / 256, 256, 0, stream>>>(logits, c.P);
    k_h0<<<NTOK, 256, 0, stream>>>(c.P, E, inputs, c.X1, c.X116);
    block_forward(c, 0, c.X1, c.X116, c.UDX, c.Q016, c.AO016, c.MB0, c.LB0, c.X20, c.U016);
    k_gfill<<<(NTOK * H_ + 255) / 256, 256, 0, stream>>>(ew, c.G);
    block_backward(c, 1, c.UDX, c.UDX16, c.Q16, c.AO16, c.MB, c.LB, true);
    k_h0<<<NTOK, 256, 0, stream>>>(c.P, E, inputs, c.X1, c.X116);
    block_backward(c, 0, c.X1, c.X116, c.Q016, c.AO016, c.MB0, c.LB0, false);
    k_logits_update<<<NTOK, 64, 0, stream>>>(c.G, E, c.P, alpha, logits);
  }
}

// Round 15
// 2290.595 us; speedup vs baseline: 2.8524x; 1.0285x over previous
//
#include <hip/hip_runtime.h>
#include <math.h>

#define B_ 8
#define S_ 900
#define V_ 11
#define H_ 512
#define NH_ 8
#define HD_ 64
#define INNER_ 1536
#define STEPS_ 2
#define NTOK (B_*S_)
#define EPS_ 1e-5f
#define THETA_ 10000.0f
#define ESCALE_ 22.627416997969522f
#define SCALE_ 0.125f
#define PT_ 68   // attention LDS pitch (ushorts): 136B rows, 8B-aligned (b64 floor pattern)

typedef __attribute__((ext_vector_type(8))) short bh8;
typedef __attribute__((ext_vector_type(4))) float f32x4;
typedef __attribute__((ext_vector_type(4))) unsigned short us4;

union bfu { bh8 v; unsigned short s[8]; us4 q[2]; };

__device__ inline unsigned short f2bf(float x) {
  unsigned u = __builtin_bit_cast(unsigned, x);
  return (unsigned short)((u + 0x7FFFu + ((u >> 16) & 1u)) >> 16);
}
__device__ inline float b2f(unsigned short s) {
  return __builtin_bit_cast(float, (unsigned)s << 16);
}

// async global->LDS, 16B per lane; LDS dest = wave-uniform base + lane*16
__device__ inline void gld16(const unsigned short* g, unsigned short* l) {
  __builtin_amdgcn_global_load_lds(
      (const __attribute__((address_space(1))) void*)(g),
      (__attribute__((address_space(3))) void*)(l), 16, 0, 0);
}

__device__ inline bh8 lds16(const unsigned short* p) {
  bfu u;
  u.q[0] = *(const us4*)p;
  u.q[1] = *(const us4*)(p + 4);
  return u.v;
}
__device__ inline void sts16(unsigned short* p, bfu u) {
  *(us4*)p = u.q[0];
  *(us4*)(p + 4) = u.q[1];
}

__device__ inline float wave_sum64(float x) {
#pragma unroll
  for (int off = 32; off > 0; off >>= 1) x += __shfl_xor(x, off, 64);
  return x;
}

__device__ inline float quad_sum(float x) {
  x += __shfl_xor(x, 1, 64);
  x += __shfl_xor(x, 2, 64);
  return x;
}

// ---------------- small kernels ----------------

__global__ void k_zero(float* p, int n) {
  int i = blockIdx.x * blockDim.x + threadIdx.x;
  if (i < n) p[i] = 0.f;
}

__global__ void k_rope_tables(float* cs, float* sn) {
  int idx = blockIdx.x * blockDim.x + threadIdx.x;
  if (idx >= S_ * 32) return;
  int s = idx >> 5, i = idx & 31;
  float freq = powf(THETA_, -(float)i / 32.0f);
  float ang = (float)s * freq;
  cs[idx] = cosf(ang);
  sn[idx] = sinf(ang);
}

__global__ void k_softmax_logits(const float* __restrict__ logits, float* __restrict__ P) {
  int t = blockIdx.x * blockDim.x + threadIdx.x;
  if (t >= NTOK) return;
  float x[V_];
  float m = -1e30f;
#pragma unroll
  for (int v = 0; v < V_; ++v) { x[v] = logits[t * V_ + v]; m = fmaxf(m, x[v]); }
  float ssum = 0.f;
#pragma unroll
  for (int v = 0; v < V_; ++v) { x[v] = expf(x[v] - m); ssum += x[v]; }
  float inv = 1.f / ssum;
#pragma unroll
  for (int v = 0; v < V_; ++v) P[t * V_ + v] = x[v] * inv;
}

// h0 -> fp32 + bf16
__global__ void k_h0(const float* __restrict__ P, const float* __restrict__ E,
                     const int* __restrict__ inp, float* __restrict__ h0,
                     unsigned short* __restrict__ h016) {
  int t = blockIdx.x;
  int tid = threadIdx.x;
  __shared__ float p[V_];
  __shared__ int iw;
  if (tid < V_) p[tid] = P[t * V_ + tid];
  if (tid == 0) iw = inp[t];
  __syncthreads();
  for (int h = tid; h < H_; h += blockDim.x) {
    float acc = E[iw * H_ + h];
#pragma unroll
    for (int v = 0; v < V_; ++v) acc += p[v] * E[v * H_ + h];
    float val = ESCALE_ * acc;
    h0[(size_t)t * H_ + h] = val;
    h016[(size_t)t * H_ + h] = f2bf(val);
  }
}

__global__ void k_gfill(const float* __restrict__ ew, float* __restrict__ G) {
  int idx = blockIdx.x * blockDim.x + threadIdx.x;
  if (idx < NTOK * H_) G[idx] = ew[idx & (H_ - 1)];
}

// fp32 -> bf16 cast, 8 elems/thread
__global__ void k_cast8(const float* __restrict__ X, unsigned short* __restrict__ Y, int n8) {
  int i = blockIdx.x * blockDim.x + threadIdx.x;
  if (i >= n8) return;
  const float4* p = (const float4*)(X + (size_t)i * 8);
  float4 a = p[0], b = p[1];
  bfu o;
  o.s[0] = f2bf(a.x); o.s[1] = f2bf(a.y); o.s[2] = f2bf(a.z); o.s[3] = f2bf(a.w);
  o.s[4] = f2bf(b.x); o.s[5] = f2bf(b.y); o.s[6] = f2bf(b.z); o.s[7] = f2bf(b.w);
  *(bh8*)(Y + (size_t)i * 8) = o.v;
}

// ---------------- weight transpose-convert: W[K][N] fp32 -> WT[N][K] bf16 ----------------

__global__ void k_wt(const float* __restrict__ W, unsigned short* __restrict__ WT, int K, int N) {
  __shared__ float t[32][33];
  int k0 = blockIdx.y * 32, n0 = blockIdx.x * 32;
  int tx = threadIdx.x, ty = threadIdx.y;
#pragma unroll
  for (int i = 0; i < 4; ++i)
    t[ty + 8 * i][tx] = W[(size_t)(k0 + ty + 8 * i) * N + n0 + tx];
  __syncthreads();
#pragma unroll
  for (int i = 0; i < 4; ++i)
    WT[(size_t)(n0 + ty + 8 * i) * K + k0 + tx] = f2bf(t[tx][ty + 8 * i]);
}

// ---------------- MFMA GEMM: C[M,N] = A[M,K] @ B^T (A,B bf16; B stored [N][K]) ----------------
// BK=64 as TWO independent 32-col sub-tiles sharing one barrier pair.

template <int TM, int SILU_A, int ADD, int CBF, int ROPE, int SILUBWD>
__global__ __launch_bounds__(256) void k_gemm(const unsigned short* __restrict__ A16,
                                              const unsigned short* __restrict__ Bt,
                                              const float* __restrict__ Dm,
                                              float* __restrict__ Cf,
                                              unsigned short* __restrict__ C16,
                                              unsigned short* __restrict__ GU,
                                              const float* __restrict__ Cs,
                                              const float* __restrict__ Sn,
                                              int M, int N, int K, int lda) {
  __shared__ unsigned short As[2][TM][32];
  __shared__ unsigned short Bs[2][128][32];
  constexpr int FR = TM / 32;
  int tid = threadIdx.x;
  int m0 = blockIdx.y * TM, n0 = blockIdx.x * 128;
  int wid = tid >> 6, lane = tid & 63;
  int wr = (wid >> 1) * (FR * 16), wc = (wid & 1) * 64;
  int lr = lane & 15, lg = lane >> 4;
  int srow = lane >> 2, sck = (lane & 3) * 8;
  f32x4 acc[FR][4] = {};
  for (int k0 = 0; k0 < K; k0 += 64) {
    __syncthreads();
#pragma unroll
    for (int sub = 0; sub < 2; ++sub) {
      int kk = k0 + sub * 32;
#pragma unroll
      for (int half = 0; half < TM / 64; ++half) {
        if (SILU_A) {
          int row = (tid >> 2) + 64 * half;
          int ck = (tid & 3) * 8;
          int gr = m0 + row; gr = gr < M ? gr : M - 1;
          const unsigned short* src = &A16[(size_t)gr * lda + kk + ck];
          bfu pa;
#pragma unroll
          for (int j = 0; j < 8; ++j) {
            float g = b2f(src[j]), u = b2f(src[INNER_ + j]);
            pa.s[j] = f2bf((g / (1.f + __expf(-g))) * u);
          }
          *(bh8*)&As[sub][row][ck] = pa.v;
        } else {
          int gr = m0 + 64 * half + wid * 16 + srow; gr = gr < M ? gr : M - 1;
          gld16(&A16[(size_t)gr * lda + kk + sck], &As[sub][64 * half + wid * 16][0]);
        }
      }
#pragma unroll
      for (int i = 0; i < 2; ++i) {
        int bb = wid * 2 + i;
        gld16(&Bt[(size_t)(n0 + bb * 16 + srow) * K + kk + sck], &Bs[sub][bb * 16][0]);
      }
    }
    __syncthreads();
#pragma unroll
    for (int sub = 0; sub < 2; ++sub) {
      bh8 av[FR], bv[4];
#pragma unroll
      for (int fr = 0; fr < FR; ++fr) av[fr] = *(const bh8*)&As[sub][wr + fr * 16 + lr][lg * 8];
#pragma unroll
      for (int fc = 0; fc < 4; ++fc) bv[fc] = *(const bh8*)&Bs[sub][wc + fc * 16 + lr][lg * 8];
#pragma unroll
      for (int fr = 0; fr < FR; ++fr)
#pragma unroll
        for (int fc = 0; fc < 4; ++fc)
          acc[fr][fc] = __builtin_amdgcn_mfma_f32_16x16x32_bf16(av[fr], bv[fc], acc[fr][fc], 0, 0, 0);
    }
  }
  bool rope_on = ROPE && (((n0 + wc) >> 6) < 16);
#pragma unroll
  for (int fr = 0; fr < FR; ++fr) {
    int r0 = m0 + wr + fr * 16 + lg * 4;
#pragma unroll
    for (int i = 0; i < 4; ++i) {
      int gr = r0 + i;
      if (gr >= M) continue;
      float c0 = 1.f, s0 = 0.f, c1 = 1.f, s1 = 0.f;
      if (ROPE) {
        if (rope_on) {
          int s = gr % S_;
          c0 = Cs[s * 32 + lr];      s0 = Sn[s * 32 + lr];
          c1 = Cs[s * 32 + 16 + lr]; s1 = Sn[s * 32 + 16 + lr];
        }
      }
#pragma unroll
      for (int fc = 0; fc < 4; ++fc) {
        int gc = n0 + wc + fc * 16 + lr;
        float out = acc[fr][fc][i];
        if (ROPE) {
          float part = acc[fr][fc ^ 2][i];
          float cc = (fc & 1) ? c1 : c0;
          float ss = (fc & 1) ? s1 : s0;
          out = (fc < 2) ? (out * cc - part * ss) : (out * cc + part * ss);
        }
        if (ADD) out += Dm[(size_t)gr * N + gc];
        if (SILUBWD) {
          size_t gb = (size_t)gr * (size_t)(2 * INNER_) + gc;
          float g = b2f(GU[gb]), u = b2f(GU[gb + INNER_]);
          float sig = 1.f / (1.f + __expf(-g));
          GU[gb] = f2bf(out * u * sig * (1.f + g * (1.f - sig)));
          GU[gb + INNER_] = f2bf(out * g * sig);
        } else if (CBF) {
          C16[(size_t)gr * N + gc] = f2bf(out);
        } else {
          Cf[(size_t)gr * N + gc] = out;
        }
      }
    }
  }
}

// ---------------- MFMA flash attention, QBLK=128 (8 waves), role-split staging ----------------
// Waves 0-3 (tid<256) stage row-tiles; waves 4-7 stage transpose-tiles.
// Per-wave compute identical to proven 4-wave version; prefetch-under-compute kept.

__global__ __launch_bounds__(512) void k_attn_fwd3(const unsigned short* __restrict__ QKV,
                                                   unsigned short* __restrict__ AO,
                                                   float* __restrict__ MB,
                                                   float* __restrict__ LB) {
  __shared__ unsigned short Ks[64][PT_];
  __shared__ unsigned short VT[64][PT_];
  __shared__ unsigned short Ps[8][16][PT_];
  int tid = threadIdx.x;
  int h = blockIdx.y, b = blockIdx.z;
  int w = tid >> 6, lane = tid & 63;
  int lr = lane & 15, lg = lane >> 4;
  int q0 = blockIdx.x * 128 + w * 16;
  bool kRole = tid < 256;
  int t2 = kRole ? tid : tid - 256;
  int sr = t2 >> 2, sc0 = (t2 & 3) * 16;
  int vd0 = (t2 & 15) * 4, vk0 = (t2 >> 4) * 4;

  bh8 qf[2];
  {
    int qr = q0 + lr; if (qr >= S_) qr = S_ - 1;
    const unsigned short* qp = &QKV[((size_t)(b * S_ + qr) * 24 + h) * 64 + lg * 8];
    qf[0] = *(const bh8*)qp;
    qf[1] = *(const bh8*)(qp + 32);
  }
  f32x4 accO[4] = {};
  float m[4], lsum[4];
#pragma unroll
  for (int i = 0; i < 4; ++i) { m[i] = -1e30f; lsum[i] = 0.f; }

  // prefetch tile 0 (per role)
  bfu kA, kB;
  us4 vR[4];
  if (kRole) {
    int src = sr;
    size_t ts = (size_t)b * S_ + (src < S_ ? src : S_ - 1);
    const unsigned short* gp = &QKV[(ts * 24 + 8 + h) * 64 + sc0];
    kA.v = *(const bh8*)gp;
    kB.v = *(const bh8*)(gp + 8);
  } else {
#pragma unroll
    for (int j = 0; j < 4; ++j) {
      int s2 = vk0 + j;
      size_t t3 = (size_t)b * S_ + (s2 < S_ ? s2 : S_ - 1);
      vR[j] = *(const us4*)&QKV[(t3 * 24 + 16 + h) * 64 + vd0];
    }
  }

  for (int kt = 0; kt < S_; kt += 64) {
    __syncthreads();
    if (kRole) {
      sts16(&Ks[sr][sc0], kA);
      sts16(&Ks[sr][sc0 + 8], kB);
    } else {
#pragma unroll
      for (int dd = 0; dd < 4; ++dd) {
        us4 pk = {vR[0][dd], vR[1][dd], vR[2][dd], vR[3][dd]};
        *(us4*)&VT[vd0 + dd][vk0] = pk;
      }
    }
    __syncthreads();
    if (kt + 64 < S_) {  // issue next-tile loads: in flight under compute
      if (kRole) {
        int src = kt + 64 + sr;
        size_t ts = (size_t)b * S_ + (src < S_ ? src : S_ - 1);
        const unsigned short* gp = &QKV[(ts * 24 + 8 + h) * 64 + sc0];
        kA.v = *(const bh8*)gp;
        kB.v = *(const bh8*)(gp + 8);
      } else {
#pragma unroll
        for (int j = 0; j < 4; ++j) {
          int s2 = kt + 64 + vk0 + j;
          size_t t3 = (size_t)b * S_ + (s2 < S_ ? s2 : S_ - 1);
          vR[j] = *(const us4*)&QKV[(t3 * 24 + 16 + h) * 64 + vd0];
        }
      }
    }
    f32x4 accS[4] = {};
#pragma unroll
    for (int ks = 0; ks < 2; ++ks)
#pragma unroll
      for (int fk = 0; fk < 4; ++fk)
        accS[fk] = __builtin_amdgcn_mfma_f32_16x16x32_bf16(qf[ks], lds16(&Ks[fk * 16 + lr][ks * 32 + lg * 8]), accS[fk], 0, 0, 0);
    float sc[4][4], pmax[4];
#pragma unroll
    for (int i = 0; i < 4; ++i) pmax[i] = -1e30f;
#pragma unroll
    for (int fk = 0; fk < 4; ++fk)
#pragma unroll
      for (int i = 0; i < 4; ++i) {
        float s = accS[fk][i] * SCALE_;
        if (kt + fk * 16 + lr >= S_) s = -1e30f;
        sc[fk][i] = s;
        pmax[i] = fmaxf(pmax[i], s);
      }
#pragma unroll
    for (int i = 0; i < 4; ++i) {
      float v = pmax[i];
      v = fmaxf(v, __shfl_xor(v, 1, 64));
      v = fmaxf(v, __shfl_xor(v, 2, 64));
      v = fmaxf(v, __shfl_xor(v, 4, 64));
      v = fmaxf(v, __shfl_xor(v, 8, 64));
      pmax[i] = v;
    }
    float psum[4];
#pragma unroll
    for (int i = 0; i < 4; ++i) {
      float mn = fmaxf(m[i], pmax[i]);
      float eo = __expf(m[i] - mn);
      m[i] = mn;
      lsum[i] *= eo;
#pragma unroll
      for (int fd = 0; fd < 4; ++fd) accO[fd][i] *= eo;
      psum[i] = 0.f;
    }
#pragma unroll
    for (int fk = 0; fk < 4; ++fk)
#pragma unroll
      for (int i = 0; i < 4; ++i) {
        float p = __expf(sc[fk][i] - m[i]);
        sc[fk][i] = p;
        psum[i] += p;
      }
#pragma unroll
    for (int i = 0; i < 4; ++i) {
      float v = psum[i];
      v += __shfl_xor(v, 1, 64);
      v += __shfl_xor(v, 2, 64);
      v += __shfl_xor(v, 4, 64);
      v += __shfl_xor(v, 8, 64);
      lsum[i] += v;
    }
#pragma unroll
    for (int fk = 0; fk < 4; ++fk)
#pragma unroll
      for (int i = 0; i < 4; ++i)
        Ps[w][lg * 4 + i][fk * 16 + lr] = f2bf(sc[fk][i]);
#pragma unroll
    for (int ks = 0; ks < 2; ++ks) {
      bh8 ap = lds16(&Ps[w][lr][ks * 32 + lg * 8]);
#pragma unroll
      for (int fd = 0; fd < 4; ++fd)
        accO[fd] = __builtin_amdgcn_mfma_f32_16x16x32_bf16(ap, lds16(&VT[fd * 16 + lr][ks * 32 + lg * 8]), accO[fd], 0, 0, 0);
    }
  }
#pragma unroll
  for (int i = 0; i < 4; ++i) {
    int q = q0 + lg * 4 + i;
    if (q < S_) {
      float linv = 1.f / lsum[i];
      size_t obase = (size_t)(b * S_ + q) * H_ + h * 64;
#pragma unroll
      for (int fd = 0; fd < 4; ++fd) AO[obase + fd * 16 + lr] = f2bf(accO[fd][i] * linv);
      if (lr == 0) {
        MB[((size_t)b * NH_ + h) * S_ + q] = m[i];
        LB[((size_t)b * NH_ + h) * S_ + q] = linv;
      }
    }
  }
}

// delta[b,h,q] = dot(dO_row, O_row), both bf16
__global__ __launch_bounds__(256) void k_delta(const unsigned short* __restrict__ O,
                                               const unsigned short* __restrict__ dO,
                                               float* __restrict__ DB) {
  int tid = threadIdx.x;
  int h = blockIdx.y, b = blockIdx.z;
  int r = blockIdx.x * 64 + (tid >> 2), part = tid & 3;
  if (r >= S_) return;
  size_t base = (size_t)(b * S_ + r) * H_ + h * 64 + part * 16;
  bfu o0, o1, d0, d1;
  o0.v = *(const bh8*)&O[base];  o1.v = *(const bh8*)&O[base + 8];
  d0.v = *(const bh8*)&dO[base]; d1.v = *(const bh8*)&dO[base + 8];
  float s = 0.f;
#pragma unroll
  for (int j = 0; j < 8; ++j)
    s += b2f(o0.s[j]) * b2f(d0.s[j]) + b2f(o1.s[j]) * b2f(d1.s[j]);
  s = quad_sum(s);
  if (part == 0) DB[((size_t)b * NH_ + h) * S_ + r] = s;
}

// dQ pass, QBLK=128; fused inverse-RoPE on output; prefetch-under-compute
__global__ __launch_bounds__(512) void k_attn_bwd_dq3(const unsigned short* __restrict__ QKV,
                                                      const unsigned short* __restrict__ dO,
                                                      const float* __restrict__ MB,
                                                      const float* __restrict__ LB,
                                                      const float* __restrict__ DB,
                                                      const float* __restrict__ Cs,
                                                      const float* __restrict__ Sn,
                                                      unsigned short* __restrict__ dQKV) {
  __shared__ unsigned short Ks[64][PT_];
  __shared__ unsigned short Vs[64][PT_];
  __shared__ unsigned short KT[64][PT_];
  __shared__ unsigned short Ps[8][16][PT_];
  int tid = threadIdx.x;
  int h = blockIdx.y, b = blockIdx.z;
  int w = tid >> 6, lane = tid & 63;
  int lr = lane & 15, lg = lane >> 4;
  int q0 = blockIdx.x * 128 + w * 16;
  size_t sbase = ((size_t)b * NH_ + h) * S_;
  bool kRole = tid < 256;
  int t2 = kRole ? tid : tid - 256;
  int sr = t2 >> 2, sc0 = (t2 & 3) * 16;
  int vd0 = (t2 & 15) * 4, vk0 = (t2 >> 4) * 4;

  bh8 qf[2], dof[2];
  {
    int qr = q0 + lr; if (qr >= S_) qr = S_ - 1;
    const unsigned short* qp = &QKV[((size_t)(b * S_ + qr) * 24 + h) * 64 + lg * 8];
    const unsigned short* dp = &dO[(size_t)(b * S_ + qr) * H_ + h * 64 + lg * 8];
    qf[0] = *(const bh8*)qp;  qf[1] = *(const bh8*)(qp + 32);
    dof[0] = *(const bh8*)dp; dof[1] = *(const bh8*)(dp + 32);
  }
  float mrow[4], lrow[4], drow[4];
#pragma unroll
  for (int i = 0; i < 4; ++i) {
    int q = q0 + lg * 4 + i; if (q >= S_) q = S_ - 1;
    mrow[i] = MB[sbase + q];
    lrow[i] = LB[sbase + q];
    drow[i] = DB[sbase + q];
  }
  f32x4 accQ[4] = {};

  // prefetch tile 0 (per role)
  bfu pA{}, pB{}, pC{}, pD{};
  us4 rv[4];
  if (kRole) {
    int src = sr;
    bool vld = src < S_;
    size_t ts = (size_t)b * S_ + (vld ? src : S_ - 1);
    const unsigned short* kp = &QKV[(ts * 24 + 8 + h) * 64 + sc0];
    if (vld) {
      pA.v = *(const bh8*)kp;
      pB.v = *(const bh8*)(kp + 8);
      pC.v = *(const bh8*)(kp + 512);
      pD.v = *(const bh8*)(kp + 520);
    }
  } else {
#pragma unroll
    for (int j = 0; j < 4; ++j) {
      int s2 = vk0 + j;
      bool v2 = s2 < S_;
      size_t t3 = (size_t)b * S_ + (v2 ? s2 : S_ - 1);
      us4 t = *(const us4*)&QKV[(t3 * 24 + 8 + h) * 64 + vd0];
      if (!v2) t = us4{0, 0, 0, 0};
      rv[j] = t;
    }
  }

  for (int kt = 0; kt < S_; kt += 64) {
    __syncthreads();
    if (kRole) {
      sts16(&Ks[sr][sc0], pA); sts16(&Ks[sr][sc0 + 8], pB);
      sts16(&Vs[sr][sc0], pC); sts16(&Vs[sr][sc0 + 8], pD);
    } else {
#pragma unroll
      for (int dd = 0; dd < 4; ++dd) {
        us4 pk = {rv[0][dd], rv[1][dd], rv[2][dd], rv[3][dd]};
        *(us4*)&KT[vd0 + dd][vk0] = pk;
      }
    }
    __syncthreads();
    if (kt + 64 < S_) {
      if (kRole) {
        int src = kt + 64 + sr;
        bool vld = src < S_;
        size_t ts = (size_t)b * S_ + (vld ? src : S_ - 1);
        const unsigned short* kp = &QKV[(ts * 24 + 8 + h) * 64 + sc0];
        pA = bfu{}; pB = bfu{}; pC = bfu{}; pD = bfu{};
        if (vld) {
          pA.v = *(const bh8*)kp;
          pB.v = *(const bh8*)(kp + 8);
          pC.v = *(const bh8*)(kp + 512);
          pD.v = *(const bh8*)(kp + 520);
        }
      } else {
#pragma unroll
        for (int j = 0; j < 4; ++j) {
          int s2 = kt + 64 + vk0 + j;
          bool v2 = s2 < S_;
          size_t t3 = (size_t)b * S_ + (v2 ? s2 : S_ - 1);
          us4 t = *(const us4*)&QKV[(t3 * 24 + 8 + h) * 64 + vd0];
          if (!v2) t = us4{0, 0, 0, 0};
          rv[j] = t;
        }
      }
    }
    f32x4 aS[4] = {}, aD[4] = {};
#pragma unroll
    for (int ks = 0; ks < 2; ++ks)
#pragma unroll
      for (int fk = 0; fk < 4; ++fk) {
        aS[fk] = __builtin_amdgcn_mfma_f32_16x16x32_bf16(qf[ks], lds16(&Ks[fk * 16 + lr][ks * 32 + lg * 8]), aS[fk], 0, 0, 0);
        aD[fk] = __builtin_amdgcn_mfma_f32_16x16x32_bf16(dof[ks], lds16(&Vs[fk * 16 + lr][ks * 32 + lg * 8]), aD[fk], 0, 0, 0);
      }
#pragma unroll
    for (int fk = 0; fk < 4; ++fk)
#pragma unroll
      for (int i = 0; i < 4; ++i) {
        float p = __expf(aS[fk][i] * SCALE_ - mrow[i]) * lrow[i];
        float ds = p * (aD[fk][i] - drow[i]);
        Ps[w][lg * 4 + i][fk * 16 + lr] = f2bf(ds);
      }
#pragma unroll
    for (int ks = 0; ks < 2; ++ks) {
      bh8 ap = lds16(&Ps[w][lr][ks * 32 + lg * 8]);
#pragma unroll
      for (int fd = 0; fd < 4; ++fd)
        accQ[fd] = __builtin_amdgcn_mfma_f32_16x16x32_bf16(ap, lds16(&KT[fd * 16 + lr][ks * 32 + lg * 8]), accQ[fd], 0, 0, 0);
    }
  }
#pragma unroll
  for (int i = 0; i < 4; ++i) {
    int q = q0 + lg * 4 + i;
    if (q < S_) {
      size_t obase = ((size_t)(b * S_ + q) * 24 + h) * 64;
      float c0 = Cs[q * 32 + lr], s0 = Sn[q * 32 + lr];
      float c1 = Cs[q * 32 + 16 + lr], s1 = Sn[q * 32 + 16 + lr];
#pragma unroll
      for (int fd = 0; fd < 4; ++fd) {
        float x = SCALE_ * accQ[fd][i];
        float p = SCALE_ * accQ[fd ^ 2][i];
        float cc = (fd & 1) ? c1 : c0;
        float ss = (fd & 1) ? s1 : s0;
        float out = (fd < 2) ? (x * cc + p * ss) : (x * cc - p * ss);
        dQKV[obase + fd * 16 + lr] = f2bf(out);
      }
    }
  }
}

// dK + dV pass, QBLK=128; fused inverse-RoPE on dK; prefetch-under-compute
__global__ __launch_bounds__(512) void k_attn_bwd_kv3(const unsigned short* __restrict__ QKV,
                                                      const unsigned short* __restrict__ dO,
                                                      const float* __restrict__ MB,
                                                      const float* __restrict__ LB,
                                                      const float* __restrict__ DB,
                                                      const float* __restrict__ Cs,
                                                      const float* __restrict__ Sn,
                                                      unsigned short* __restrict__ dQKV) {
  __shared__ unsigned short Qs[64][PT_];
  __shared__ unsigned short dOs[64][PT_];
  __shared__ unsigned short QT[64][PT_];
  __shared__ unsigned short dOT[64][PT_];
  __shared__ unsigned short Ps[8][16][PT_];
  __shared__ float sM[64], sL[64], sD[64];
  int tid = threadIdx.x;
  int h = blockIdx.y, b = blockIdx.z;
  int w = tid >> 6, lane = tid & 63;
  int lr = lane & 15, lg = lane >> 4;
  int k0w = blockIdx.x * 128 + w * 16;
  size_t sbase = ((size_t)b * NH_ + h) * S_;
  bool kRole = tid < 256;
  int t2 = kRole ? tid : tid - 256;
  int sr = t2 >> 2, sc0 = (t2 & 3) * 16;
  int vd0 = (t2 & 15) * 4, vk0 = (t2 >> 4) * 4;

  bh8 kf[2], vf[2];
  {
    int kr = k0w + lr; if (kr >= S_) kr = S_ - 1;
    const unsigned short* kp = &QKV[((size_t)(b * S_ + kr) * 24 + 8 + h) * 64 + lg * 8];
    kf[0] = *(const bh8*)kp;        kf[1] = *(const bh8*)(kp + 32);
    vf[0] = *(const bh8*)(kp + 512); vf[1] = *(const bh8*)(kp + 544);
  }
  f32x4 accK[4] = {}, accV[4] = {};

  // prefetch tile 0 (per role)
  bfu pA{}, pB{}, pC{}, pD{};
  us4 rq[4], rd[4];
  float stM = 0.f, stL = 0.f, stD = 0.f;
  if (kRole) {
    int src = sr;
    bool vld = src < S_;
    size_t ts = (size_t)b * S_ + (vld ? src : S_ - 1);
    const unsigned short* qp = &QKV[(ts * 24 + h) * 64 + sc0];
    const unsigned short* dp = &dO[ts * H_ + h * 64 + sc0];
    pA.v = *(const bh8*)qp;
    pB.v = *(const bh8*)(qp + 8);
    if (vld) {
      pC.v = *(const bh8*)dp;
      pD.v = *(const bh8*)(dp + 8);
    }
    if (tid < 64) {
      bool v2 = tid < S_;
      int sc = v2 ? tid : S_ - 1;
      stM = MB[sbase + sc];
      stL = LB[sbase + sc];
      stD = v2 ? DB[sbase + sc] : 0.f;
    }
  } else {
#pragma unroll
    for (int j = 0; j < 4; ++j) {
      int s2 = vk0 + j;
      bool v2 = s2 < S_;
      size_t t3 = (size_t)b * S_ + (v2 ? s2 : S_ - 1);
      rq[j] = *(const us4*)&QKV[(t3 * 24 + h) * 64 + vd0];
      us4 td = *(const us4*)&dO[t3 * H_ + h * 64 + vd0];
      if (!v2) td = us4{0, 0, 0, 0};
      rd[j] = td;
    }
  }

  for (int qt = 0; qt < S_; qt += 64) {
    __syncthreads();
    if (kRole) {
      sts16(&Qs[sr][sc0], pA);  sts16(&Qs[sr][sc0 + 8], pB);
      sts16(&dOs[sr][sc0], pC); sts16(&dOs[sr][sc0 + 8], pD);
      if (tid < 64) {
        sM[tid] = stM;
        sL[tid] = stL;
        sD[tid] = stD;
      }
    } else {
#pragma unroll
      for (int dd = 0; dd < 4; ++dd) {
        us4 pq = {rq[0][dd], rq[1][dd], rq[2][dd], rq[3][dd]};
        us4 pd = {rd[0][dd], rd[1][dd], rd[2][dd], rd[3][dd]};
        *(us4*)&QT[vd0 + dd][vk0] = pq;
        *(us4*)&dOT[vd0 + dd][vk0] = pd;
      }
    }
    __syncthreads();
    if (qt + 64 < S_) {
      if (kRole) {
        int src = qt + 64 + sr;
        bool vld = src < S_;
        size_t ts = (size_t)b * S_ + (vld ? src : S_ - 1);
        const unsigned short* qp = &QKV[(ts * 24 + h) * 64 + sc0];
        const unsigned short* dp = &dO[ts * H_ + h * 64 + sc0];
        pA.v = *(const bh8*)qp;
        pB.v = *(const bh8*)(qp + 8);
        pC = bfu{}; pD = bfu{};
        if (vld) {
          pC.v = *(const bh8*)dp;
          pD.v = *(const bh8*)(dp + 8);
        }
        if (tid < 64) {
          int s2 = qt + 64 + tid;
          bool v2 = s2 < S_;
          int sc = v2 ? s2 : S_ - 1;
          stM = MB[sbase + sc];
          stL = LB[sbase + sc];
          stD = v2 ? DB[sbase + sc] : 0.f;
        }
      } else {
#pragma unroll
        for (int j = 0; j < 4; ++j) {
          int s2 = qt + 64 + vk0 + j;
          bool v2 = s2 < S_;
          size_t t3 = (size_t)b * S_ + (v2 ? s2 : S_ - 1);
          rq[j] = *(const us4*)&QKV[(t3 * 24 + h) * 64 + vd0];
          us4 td = *(const us4*)&dO[t3 * H_ + h * 64 + vd0];
          if (!v2) td = us4{0, 0, 0, 0};
          rd[j] = td;
        }
      }
    }
    f32x4 aS[4] = {}, aD[4] = {};
#pragma unroll
    for (int ks = 0; ks < 2; ++ks)
#pragma unroll
      for (int fq = 0; fq < 4; ++fq) {
        aS[fq] = __builtin_amdgcn_mfma_f32_16x16x32_bf16(kf[ks], lds16(&Qs[fq * 16 + lr][ks * 32 + lg * 8]), aS[fq], 0, 0, 0);
        aD[fq] = __builtin_amdgcn_mfma_f32_16x16x32_bf16(vf[ks], lds16(&dOs[fq * 16 + lr][ks * 32 + lg * 8]), aD[fq], 0, 0, 0);
      }
    float pv[4][4];
#pragma unroll
    for (int fq = 0; fq < 4; ++fq) {
      float mq = sM[fq * 16 + lr], lq = sL[fq * 16 + lr];
#pragma unroll
      for (int i = 0; i < 4; ++i) {
        float p = __expf(aS[fq][i] * SCALE_ - mq) * lq;
        pv[fq][i] = p;
        Ps[w][lg * 4 + i][fq * 16 + lr] = f2bf(p);
      }
    }
#pragma unroll
    for (int qs = 0; qs < 2; ++qs) {
      bh8 ap = lds16(&Ps[w][lr][qs * 32 + lg * 8]);
#pragma unroll
      for (int fd = 0; fd < 4; ++fd)
        accV[fd] = __builtin_amdgcn_mfma_f32_16x16x32_bf16(ap, lds16(&dOT[fd * 16 + lr][qs * 32 + lg * 8]), accV[fd], 0, 0, 0);
    }
#pragma unroll
    for (int fq = 0; fq < 4; ++fq) {
      float dq = sD[fq * 16 + lr];
#pragma unroll
      for (int i = 0; i < 4; ++i)
        Ps[w][lg * 4 + i][fq * 16 + lr] = f2bf(pv[fq][i] * (aD[fq][i] - dq));
    }
#pragma unroll
    for (int qs = 0; qs < 2; ++qs) {
      bh8 ap = lds16(&Ps[w][lr][qs * 32 + lg * 8]);
#pragma unroll
      for (int fd = 0; fd < 4; ++fd)
        accK[fd] = __builtin_amdgcn_mfma_f32_16x16x32_bf16(ap, lds16(&QT[fd * 16 + lr][qs * 32 + lg * 8]), accK[fd], 0, 0, 0);
    }
  }
#pragma unroll
  for (int i = 0; i < 4; ++i) {
    int k = k0w + lg * 4 + i;
    if (k < S_) {
      size_t obase = ((size_t)(b * S_ + k) * 24 + 8 + h) * 64;
      float c0 = Cs[k * 32 + lr], s0 = Sn[k * 32 + lr];
      float c1 = Cs[k * 32 + 16 + lr], s1 = Sn[k * 32 + 16 + lr];
#pragma unroll
      for (int fd = 0; fd < 4; ++fd) {
        float x = SCALE_ * accK[fd][i];
        float p = SCALE_ * accK[fd ^ 2][i];
        float cc = (fd & 1) ? c1 : c0;
        float ss = (fd & 1) ? s1 : s0;
        float out = (fd < 2) ? (x * cc + p * ss) : (x * cc - p * ss);
        dQKV[obase + fd * 16 + lr] = f2bf(out);
        dQKV[obase + 512 + fd * 16 + lr] = f2bf(accV[fd][i]);
      }
    }
  }
}

// ---------------- RMS norm fwd/bwd (dual fp32+bf16 outputs) ----------------

__global__ __launch_bounds__(256) void k_rms_fwd(const float* __restrict__ X, float* __restrict__ Y,
                                                 unsigned short* __restrict__ Y16) {
  int t = blockIdx.x, tid = threadIdx.x;
  float x0 = X[(size_t)t * H_ + tid], x1 = X[(size_t)t * H_ + tid + 256];
  __shared__ float red[256];
  red[tid] = x0 * x0 + x1 * x1;
  __syncthreads();
  for (int s = 128; s > 0; s >>= 1) {
    if (tid < s) red[tid] += red[tid + s];
    __syncthreads();
  }
  float r = rsqrtf(red[0] / H_ + EPS_);
  float y0 = x0 * r, y1 = x1 * r;
  Y[(size_t)t * H_ + tid] = y0;
  Y[(size_t)t * H_ + tid + 256] = y1;
  Y16[(size_t)t * H_ + tid] = f2bf(y0);
  Y16[(size_t)t * H_ + tid + 256] = f2bf(y1);
}

__global__ __launch_bounds__(256) void k_rms_bwd(const float* __restrict__ X,
                                                 const float* __restrict__ GY,
                                                 float* __restrict__ GX,
                                                 unsigned short* __restrict__ GX16) {
  int t = blockIdx.x, tid = threadIdx.x;
  float x0 = X[(size_t)t * H_ + tid], x1 = X[(size_t)t * H_ + tid + 256];
  float g0 = GY[(size_t)t * H_ + tid], g1 = GY[(size_t)t * H_ + tid + 256];
  __shared__ float r1[256], r2[256];
  r1[tid] = x0 * x0 + x1 * x1;
  r2[tid] = x0 * g0 + x1 * g1;
  __syncthreads();
  for (int s = 128; s > 0; s >>= 1) {
    if (tid < s) { r1[tid] += r1[tid + s]; r2[tid] += r2[tid + s]; }
    __syncthreads();
  }
  float r = rsqrtf(r1[0] / H_ + EPS_);
  float coef = r * r * r * r2[0] / (float)H_;
  float o0 = r * g0 - coef * x0, o1 = r * g1 - coef * x1;
  GX[(size_t)t * H_ + tid] = o0;
  GX[(size_t)t * H_ + tid + 256] = o1;
  GX16[(size_t)t * H_ + tid] = f2bf(o0);
  GX16[(size_t)t * H_ + tid + 256] = f2bf(o1);
}

// ---------------- logits update ----------------

__global__ __launch_bounds__(64) void k_logits_update(const float* __restrict__ G,
                                                      const float* __restrict__ E,
                                                      const float* __restrict__ P,
                                                      const float* __restrict__ alpha,
                                                      float* __restrict__ logits) {
  int t = blockIdx.x, lane = threadIdx.x;
  float dp[V_];
#pragma unroll
  for (int v = 0; v < V_; ++v) dp[v] = 0.f;
  for (int hh = lane; hh < H_; hh += 64) {
    float gh = G[(size_t)t * H_ + hh];
#pragma unroll
    for (int v = 0; v < V_; ++v) dp[v] += gh * E[v * H_ + hh];
  }
#pragma unroll
  for (int v = 0; v < V_; ++v) dp[v] = wave_sum64(dp[v]) * ESCALE_;
  float dot = 0.f;
  float pv[V_];
#pragma unroll
  for (int v = 0; v < V_; ++v) {
    pv[v] = P[t * V_ + v];
    dot += pv[v] * dp[v];
  }
  float a = fmaxf(alpha[0], 1e-4f);
  if (lane < V_) logits[t * V_ + lane] -= a * pv[lane] * (dp[lane] - dot);
}

// ---------------- host-side orchestration ----------------

struct Ctx {
  unsigned short *Q16, *Q016, *dQ16, *GU16, *DO16, *AO16, *AO016, *X116, *UDX16, *U016;
  float *X1, *X2, *X20, *G, *UDX, *P, *MB, *LB, *DB, *MB0, *LB0, *CS, *SN;
  const unsigned short *WTqkv[2], *WTo[2], *WTgu[2], *WTd[2];
  const unsigned short *WSqkv[2], *WSo[2], *WSgu[2], *WSd[2];
  hipStream_t st;
};

static void block_forward(Ctx& c, int l, const float* hin, const unsigned short* hin16,
                          float* hout, unsigned short* qb, unsigned short* ao,
                          float* mb, float* lb, float* x2buf, unsigned short* u16buf) {
  k_gemm<128, 0, 0, 1, 1, 0><<<dim3(3 * H_ / 128, (NTOK + 127) / 128), 256, 0, c.st>>>(
      hin16, c.WTqkv[l], nullptr, nullptr, qb, nullptr, c.CS, c.SN, NTOK, 3 * H_, H_, H_);
  k_attn_fwd3<<<dim3((S_ + 127) / 128, NH_, B_), 512, 0, c.st>>>(qb, ao, mb, lb);
  k_gemm<64, 0, 1, 0, 0, 0><<<dim3(H_ / 128, (NTOK + 63) / 64), 256, 0, c.st>>>(
      ao, c.WTo[l], hin, c.X1, nullptr, nullptr, nullptr, nullptr, NTOK, H_, H_, H_);
  k_rms_fwd<<<NTOK, 256, 0, c.st>>>(c.X1, c.UDX, u16buf);
  k_gemm<128, 0, 0, 1, 0, 0><<<dim3(2 * INNER_ / 128, (NTOK + 127) / 128), 256, 0, c.st>>>(
      u16buf, c.WTgu[l], nullptr, nullptr, c.GU16, nullptr, nullptr, nullptr, NTOK, 2 * INNER_, H_, H_);
  k_gemm<64, 1, 1, 0, 0, 0><<<dim3(H_ / 128, (NTOK + 63) / 64), 256, 0, c.st>>>(
      c.GU16, c.WTd[l], c.UDX, x2buf, nullptr, nullptr, nullptr, nullptr, NTOK, H_, INNER_, 2 * INNER_);
  if (hout) k_rms_fwd<<<NTOK, 256, 0, c.st>>>(x2buf, hout, c.UDX16);
}

static void block_backward(Ctx& c, int l, const float* hin, const unsigned short* hin16,
                           unsigned short* qb, unsigned short* ao, float* mb, float* lb,
                           bool full) {
  const float* x2src;
  if (full) {
    block_forward(c, l, hin, hin16, nullptr, qb, ao, mb, lb, c.X2, c.UDX16);
    x2src = c.X2;
  } else {
    k_gemm<64, 0, 1, 0, 0, 0><<<dim3(H_ / 128, (NTOK + 63) / 64), 256, 0, c.st>>>(
        ao, c.WTo[l], hin, c.X1, nullptr, nullptr, nullptr, nullptr, NTOK, H_, H_, H_);
    k_gemm<128, 0, 0, 1, 0, 0><<<dim3(2 * INNER_ / 128, (NTOK + 127) / 128), 256, 0, c.st>>>(
        c.U016, c.WTgu[l], nullptr, nullptr, c.GU16, nullptr, nullptr, nullptr, NTOK, 2 * INNER_, H_, H_);
    x2src = c.X20;
  }
  k_rms_bwd<<<NTOK, 256, 0, c.st>>>(x2src, c.G, c.UDX, c.UDX16);
  k_gemm<128, 0, 0, 0, 0, 1><<<dim3(INNER_ / 128, (NTOK + 127) / 128), 256, 0, c.st>>>(
      c.UDX16, c.WSd[l], nullptr, nullptr, nullptr, c.GU16, nullptr, nullptr, NTOK, INNER_, H_, H_);
  k_gemm<64, 0, 1, 0, 0, 0><<<dim3(H_ / 128, (NTOK + 63) / 64), 256, 0, c.st>>>(
      c.GU16, c.WSgu[l], c.UDX, c.G, nullptr, nullptr, nullptr, nullptr, NTOK, H_, 2 * INNER_, 2 * INNER_);
  k_rms_bwd<<<NTOK, 256, 0, c.st>>>(c.X1, c.G, c.UDX, c.UDX16);
  k_gemm<64, 0, 0, 1, 0, 0><<<dim3(H_ / 128, (NTOK + 63) / 64), 256, 0, c.st>>>(
      c.UDX16, c.WSo[l], nullptr, nullptr, c.DO16, nullptr, nullptr, nullptr, NTOK, H_, H_, H_);
  dim3 agrid64((S_ + 63) / 64, NH_, B_);
  dim3 agrid128((S_ + 127) / 128, NH_, B_);
  k_delta<<<agrid64, 256, 0, c.st>>>(ao, c.DO16, c.DB);
  k_attn_bwd_dq3<<<agrid128, 512, 0, c.st>>>(qb, c.DO16, mb, lb, c.DB, c.CS, c.SN, c.dQ16);
  k_attn_bwd_kv3<<<agrid128, 512, 0, c.st>>>(qb, c.DO16, mb, lb, c.DB, c.CS, c.SN, c.dQ16);
  k_gemm<64, 0, 1, 0, 0, 0><<<dim3(H_ / 128, (NTOK + 63) / 64), 256, 0, c.st>>>(
      c.dQ16, c.WSqkv[l], c.UDX, c.G, nullptr, nullptr, nullptr, nullptr, NTOK, H_, 3 * H_, 3 * H_);
}

extern "C" void kernel_launch(void* const* d_in, const int* in_sizes, int n_in,
                              void* d_out, int out_size, void* d_ws, size_t ws_size,
                              hipStream_t stream) {
  const int* inputs = (const int*)d_in[0];
  const float* E = (const float*)d_in[2];
  const float* ew = (const float*)d_in[3];
  const float* qkvw = (const float*)d_in[4];
  const float* ow = (const float*)d_in[5];
  const float* guw = (const float*)d_in[6];
  const float* dw = (const float*)d_in[7];
  const float* alpha = (const float*)d_in[8];
  float* logits = (float*)d_out;

  const size_t WT_FLOATS = 3407872;
  const size_t NEED =
      3 * ((size_t)NTOK * 3 * H_ / 2) +
      ((size_t)NTOK * INNER_) +
      5 * ((size_t)NTOK * H_) +
      6 * ((size_t)NTOK * H_ / 2) +
      ((size_t)NTOK * V_) +
      5 * ((size_t)B_ * NH_ * S_) +
      2 * ((size_t)S_ * 32) +
      2 * WT_FLOATS;
  if (ws_size < NEED * sizeof(float)) {
    k_zero<<<(NTOK * V_ + 255) / 256, 256, 0, stream>>>(logits, NTOK * V_);
    return;
  }

  float* f = (float*)d_ws;
  Ctx c;
  c.st = stream;
  c.Q16 = (unsigned short*)f;  f += (size_t)NTOK * 3 * H_ / 2;
  c.Q016 = (unsigned short*)f; f += (size_t)NTOK * 3 * H_ / 2;
  c.dQ16 = (unsigned short*)f; f += (size_t)NTOK * 3 * H_ / 2;
  c.GU16 = (unsigned short*)f; f += (size_t)NTOK * INNER_;
  c.X1 = f;   f += (size_t)NTOK * H_;
  c.X2 = f;   f += (size_t)NTOK * H_;
  c.X20 = f;  f += (size_t)NTOK * H_;
  c.G = f;    f += (size_t)NTOK * H_;
  c.UDX = f;  f += (size_t)NTOK * H_;
  c.AO16 = (unsigned short*)f;  f += (size_t)NTOK * H_ / 2;
  c.AO016 = (unsigned short*)f; f += (size_t)NTOK * H_ / 2;
  c.DO16 = (unsigned short*)f;  f += (size_t)NTOK * H_ / 2;
  c.X116 = (unsigned short*)f;  f += (size_t)NTOK * H_ / 2;
  c.UDX16 = (unsigned short*)f; f += (size_t)NTOK * H_ / 2;
  c.U016 = (unsigned short*)f;  f += (size_t)NTOK * H_ / 2;
  c.P = f;    f += (size_t)NTOK * V_;
  c.MB = f;   f += (size_t)B_ * NH_ * S_;
  c.LB = f;   f += (size_t)B_ * NH_ * S_;
  c.DB = f;   f += (size_t)B_ * NH_ * S_;
  c.MB0 = f;  f += (size_t)B_ * NH_ * S_;
  c.LB0 = f;  f += (size_t)B_ * NH_ * S_;
  c.CS = f;   f += (size_t)S_ * 32;
  c.SN = f;   f += (size_t)S_ * 32;
  unsigned short* wt = (unsigned short*)f;

  const size_t LQKV = (size_t)H_ * 3 * H_;
  const size_t LO = (size_t)H_ * H_;
  const size_t LGU = (size_t)H_ * 2 * INNER_;
  const size_t LD = (size_t)INNER_ * H_;

  for (int l = 0; l < 2; ++l) {
    c.WTqkv[l] = wt;
    k_wt<<<dim3(3 * H_ / 32, H_ / 32), dim3(32, 8), 0, stream>>>(qkvw + l * LQKV, wt, H_, 3 * H_);
    wt += LQKV;
    c.WTo[l] = wt;
    k_wt<<<dim3(H_ / 32, H_ / 32), dim3(32, 8), 0, stream>>>(ow + l * LO, wt, H_, H_);
    wt += LO;
    c.WTgu[l] = wt;
    k_wt<<<dim3(2 * INNER_ / 32, H_ / 32), dim3(32, 8), 0, stream>>>(guw + l * LGU, wt, H_, 2 * INNER_);
    wt += LGU;
    c.WTd[l] = wt;
    k_wt<<<dim3(H_ / 32, INNER_ / 32), dim3(32, 8), 0, stream>>>(dw + l * LD, wt, INNER_, H_);
    wt += LD;
  }
  {
    unsigned short* ws = wt;
    k_cast8<<<(int)((2 * LQKV / 8 + 255) / 256), 256, 0, stream>>>(qkvw, ws, (int)(2 * LQKV / 8));
    c.WSqkv[0] = ws; c.WSqkv[1] = ws + LQKV; ws += 2 * LQKV;
    k_cast8<<<(int)((2 * LO / 8 + 255) / 256), 256, 0, stream>>>(ow, ws, (int)(2 * LO / 8));
    c.WSo[0] = ws; c.WSo[1] = ws + LO; ws += 2 * LO;
    k_cast8<<<(int)((2 * LGU / 8 + 255) / 256), 256, 0, stream>>>(guw, ws, (int)(2 * LGU / 8));
    c.WSgu[0] = ws; c.WSgu[1] = ws + LGU; ws += 2 * LGU;
    k_cast8<<<(int)((2 * LD / 8 + 255) / 256), 256, 0, stream>>>(dw, ws, (int)(2 * LD / 8));
    c.WSd[0] = ws; c.WSd[1] = ws + LD;
  }

  k_zero<<<(NTOK * V_ + 255) / 256, 256, 0, stream>>>(logits, NTOK * V_);
  k_rope_tables<<<(S_ * 32 + 255) / 256, 256, 0, stream>>>(c.CS, c.SN);

  for (int step = 0; step < STEPS_; ++step) {
    k_softmax_logits<<<(NTOK + 255) / 256, 256, 0, stream>>>(logits, c.P);
    k_h0<<<NTOK, 256, 0, stream>>>(c.P, E, inputs, c.X1, c.X116);
    block_forward(c, 0, c.X1, c.X116, c.UDX, c.Q016, c.AO016, c.MB0, c.LB0, c.X20, c.U016);
    k_gfill<<<(NTOK * H_ + 255) / 256, 256, 0, stream>>>(ew, c.G);
    block_backward(c, 1, c.UDX, c.UDX16, c.Q16, c.AO16, c.MB, c.LB, true);
    k_h0<<<NTOK, 256, 0, stream>>>(c.P, E, inputs, c.X1, c.X116);
    block_backward(c, 0, c.X1, c.X116, c.Q016, c.AO016, c.MB0, c.LB0, false);
    k_logits_update<<<NTOK, 64, 0, stream>>>(c.G, E, c.P, alpha, logits);
  }
}

// Round 16
// 2263.552 us; speedup vs baseline: 2.8864x; 1.0119x over previous
//
#include <hip/hip_runtime.h>
#include <math.h>

#define B_ 8
#define S_ 900
#define V_ 11
#define H_ 512
#define NH_ 8
#define HD_ 64
#define INNER_ 1536
#define STEPS_ 2
#define NTOK (B_*S_)
#define EPS_ 1e-5f
#define THETA_ 10000.0f
#define ESCALE_ 22.627416997969522f
#define SCALE_ 0.125f
#define PT_ 68   // attention LDS pitch (ushorts): 136B rows, 8B-aligned (b64 floor pattern)

typedef __attribute__((ext_vector_type(8))) short bh8;
typedef __attribute__((ext_vector_type(4))) float f32x4;
typedef __attribute__((ext_vector_type(4))) unsigned short us4;

union bfu { bh8 v; unsigned short s[8]; us4 q[2]; };

__device__ inline unsigned short f2bf(float x) {
  unsigned u = __builtin_bit_cast(unsigned, x);
  return (unsigned short)((u + 0x7FFFu + ((u >> 16) & 1u)) >> 16);
}
__device__ inline float b2f(unsigned short s) {
  return __builtin_bit_cast(float, (unsigned)s << 16);
}

// async global->LDS, 16B per lane; LDS dest = wave-uniform base + lane*16
__device__ inline void gld16(const unsigned short* g, unsigned short* l) {
  __builtin_amdgcn_global_load_lds(
      (const __attribute__((address_space(1))) void*)(g),
      (__attribute__((address_space(3))) void*)(l), 16, 0, 0);
}

__device__ inline bh8 lds16(const unsigned short* p) {
  bfu u;
  u.q[0] = *(const us4*)p;
  u.q[1] = *(const us4*)(p + 4);
  return u.v;
}
__device__ inline void sts16(unsigned short* p, bfu u) {
  *(us4*)p = u.q[0];
  *(us4*)(p + 4) = u.q[1];
}

__device__ inline float wave_sum64(float x) {
#pragma unroll
  for (int off = 32; off > 0; off >>= 1) x += __shfl_xor(x, off, 64);
  return x;
}

// ---------------- small kernels ----------------

__global__ void k_zero(float* p, int n) {
  int i = blockIdx.x * blockDim.x + threadIdx.x;
  if (i < n) p[i] = 0.f;
}

__global__ void k_rope_tables(float* cs, float* sn) {
  int idx = blockIdx.x * blockDim.x + threadIdx.x;
  if (idx >= S_ * 32) return;
  int s = idx >> 5, i = idx & 31;
  float freq = powf(THETA_, -(float)i / 32.0f);
  float ang = (float)s * freq;
  cs[idx] = cosf(ang);
  sn[idx] = sinf(ang);
}

// h0 -> fp32 + bf16; DOSM: compute P from logits in-block (and store P)
template <int DOSM>
__global__ void k_h0(const float* __restrict__ logits, float* __restrict__ P,
                     const float* __restrict__ E,
                     const int* __restrict__ inp, float* __restrict__ h0,
                     unsigned short* __restrict__ h016) {
  int t = blockIdx.x;
  int tid = threadIdx.x;
  __shared__ float p[V_];
  __shared__ int iw;
  if (DOSM) {
    if (tid == 0) {
      float x[V_];
      float m = -1e30f;
#pragma unroll
      for (int v = 0; v < V_; ++v) { x[v] = logits[t * V_ + v]; m = fmaxf(m, x[v]); }
      float ssum = 0.f;
#pragma unroll
      for (int v = 0; v < V_; ++v) { x[v] = __expf(x[v] - m); ssum += x[v]; }
      float inv = 1.f / ssum;
#pragma unroll
      for (int v = 0; v < V_; ++v) {
        float pv = x[v] * inv;
        p[v] = pv;
        P[t * V_ + v] = pv;
      }
    }
  } else {
    if (tid < V_) p[tid] = P[t * V_ + tid];
  }
  if (tid == 0) iw = inp[t];
  __syncthreads();
  for (int h = tid; h < H_; h += blockDim.x) {
    float acc = E[iw * H_ + h];
#pragma unroll
    for (int v = 0; v < V_; ++v) acc += p[v] * E[v * H_ + h];
    float val = ESCALE_ * acc;
    h0[(size_t)t * H_ + h] = val;
    h016[(size_t)t * H_ + h] = f2bf(val);
  }
}

// fp32 -> bf16 cast, 8 elems/thread
__global__ void k_cast8(const float* __restrict__ X, unsigned short* __restrict__ Y, int n8) {
  int i = blockIdx.x * blockDim.x + threadIdx.x;
  if (i >= n8) return;
  const float4* p = (const float4*)(X + (size_t)i * 8);
  float4 a = p[0], b = p[1];
  bfu o;
  o.s[0] = f2bf(a.x); o.s[1] = f2bf(a.y); o.s[2] = f2bf(a.z); o.s[3] = f2bf(a.w);
  o.s[4] = f2bf(b.x); o.s[5] = f2bf(b.y); o.s[6] = f2bf(b.z); o.s[7] = f2bf(b.w);
  *(bh8*)(Y + (size_t)i * 8) = o.v;
}

// ---------------- weight transpose-convert: W[K][N] fp32 -> WT[N][K] bf16 ----------------

__global__ void k_wt(const float* __restrict__ W, unsigned short* __restrict__ WT, int K, int N) {
  __shared__ float t[32][33];
  int k0 = blockIdx.y * 32, n0 = blockIdx.x * 32;
  int tx = threadIdx.x, ty = threadIdx.y;
#pragma unroll
  for (int i = 0; i < 4; ++i)
    t[ty + 8 * i][tx] = W[(size_t)(k0 + ty + 8 * i) * N + n0 + tx];
  __syncthreads();
#pragma unroll
  for (int i = 0; i < 4; ++i)
    WT[(size_t)(n0 + ty + 8 * i) * K + k0 + tx] = f2bf(t[tx][ty + 8 * i]);
}

// ---------------- MFMA GEMM: C[M,N] = A[M,K] @ B^T (A,B bf16; B stored [N][K]) ----------------
// BK=64 as TWO independent 32-col sub-tiles sharing one barrier pair.

template <int TM, int SILU_A, int ADD, int CBF, int ROPE, int SILUBWD>
__global__ __launch_bounds__(256) void k_gemm(const unsigned short* __restrict__ A16,
                                              const unsigned short* __restrict__ Bt,
                                              const float* __restrict__ Dm,
                                              float* __restrict__ Cf,
                                              unsigned short* __restrict__ C16,
                                              unsigned short* __restrict__ GU,
                                              const float* __restrict__ Cs,
                                              const float* __restrict__ Sn,
                                              int M, int N, int K, int lda) {
  __shared__ unsigned short As[2][TM][32];
  __shared__ unsigned short Bs[2][128][32];
  constexpr int FR = TM / 32;
  int tid = threadIdx.x;
  int m0 = blockIdx.y * TM, n0 = blockIdx.x * 128;
  int wid = tid >> 6, lane = tid & 63;
  int wr = (wid >> 1) * (FR * 16), wc = (wid & 1) * 64;
  int lr = lane & 15, lg = lane >> 4;
  int srow = lane >> 2, sck = (lane & 3) * 8;
  f32x4 acc[FR][4] = {};
  for (int k0 = 0; k0 < K; k0 += 64) {
    __syncthreads();
#pragma unroll
    for (int sub = 0; sub < 2; ++sub) {
      int kk = k0 + sub * 32;
#pragma unroll
      for (int half = 0; half < TM / 64; ++half) {
        if (SILU_A) {
          int row = (tid >> 2) + 64 * half;
          int ck = (tid & 3) * 8;
          int gr = m0 + row; gr = gr < M ? gr : M - 1;
          const unsigned short* src = &A16[(size_t)gr * lda + kk + ck];
          bfu pa;
#pragma unroll
          for (int j = 0; j < 8; ++j) {
            float g = b2f(src[j]), u = b2f(src[INNER_ + j]);
            pa.s[j] = f2bf((g / (1.f + __expf(-g))) * u);
          }
          *(bh8*)&As[sub][row][ck] = pa.v;
        } else {
          int gr = m0 + 64 * half + wid * 16 + srow; gr = gr < M ? gr : M - 1;
          gld16(&A16[(size_t)gr * lda + kk + sck], &As[sub][64 * half + wid * 16][0]);
        }
      }
#pragma unroll
      for (int i = 0; i < 2; ++i) {
        int bb = wid * 2 + i;
        gld16(&Bt[(size_t)(n0 + bb * 16 + srow) * K + kk + sck], &Bs[sub][bb * 16][0]);
      }
    }
    __syncthreads();
#pragma unroll
    for (int sub = 0; sub < 2; ++sub) {
      bh8 av[FR], bv[4];
#pragma unroll
      for (int fr = 0; fr < FR; ++fr) av[fr] = *(const bh8*)&As[sub][wr + fr * 16 + lr][lg * 8];
#pragma unroll
      for (int fc = 0; fc < 4; ++fc) bv[fc] = *(const bh8*)&Bs[sub][wc + fc * 16 + lr][lg * 8];
#pragma unroll
      for (int fr = 0; fr < FR; ++fr)
#pragma unroll
        for (int fc = 0; fc < 4; ++fc)
          acc[fr][fc] = __builtin_amdgcn_mfma_f32_16x16x32_bf16(av[fr], bv[fc], acc[fr][fc], 0, 0, 0);
    }
  }
  bool rope_on = ROPE && (((n0 + wc) >> 6) < 16);
#pragma unroll
  for (int fr = 0; fr < FR; ++fr) {
    int r0 = m0 + wr + fr * 16 + lg * 4;
#pragma unroll
    for (int i = 0; i < 4; ++i) {
      int gr = r0 + i;
      if (gr >= M) continue;
      float c0 = 1.f, s0 = 0.f, c1 = 1.f, s1 = 0.f;
      if (ROPE) {
        if (rope_on) {
          int s = gr % S_;
          c0 = Cs[s * 32 + lr];      s0 = Sn[s * 32 + lr];
          c1 = Cs[s * 32 + 16 + lr]; s1 = Sn[s * 32 + 16 + lr];
        }
      }
#pragma unroll
      for (int fc = 0; fc < 4; ++fc) {
        int gc = n0 + wc + fc * 16 + lr;
        float out = acc[fr][fc][i];
        if (ROPE) {
          float part = acc[fr][fc ^ 2][i];
          float cc = (fc & 1) ? c1 : c0;
          float ss = (fc & 1) ? s1 : s0;
          out = (fc < 2) ? (out * cc - part * ss) : (out * cc + part * ss);
        }
        if (ADD) out += Dm[(size_t)gr * N + gc];
        if (SILUBWD) {
          size_t gb = (size_t)gr * (size_t)(2 * INNER_) + gc;
          float g = b2f(GU[gb]), u = b2f(GU[gb + INNER_]);
          float sig = 1.f / (1.f + __expf(-g));
          GU[gb] = f2bf(out * u * sig * (1.f + g * (1.f - sig)));
          GU[gb + INNER_] = f2bf(out * g * sig);
        } else if (CBF) {
          C16[(size_t)gr * N + gc] = f2bf(out);
        } else {
          Cf[(size_t)gr * N + gc] = out;
        }
      }
    }
  }
}

// ---------------- MFMA flash attention, QBLK=128 (8 waves), role-split staging ----------------

__global__ __launch_bounds__(512) void k_attn_fwd3(const unsigned short* __restrict__ QKV,
                                                   unsigned short* __restrict__ AO,
                                                   float* __restrict__ MB,
                                                   float* __restrict__ LB) {
  __shared__ unsigned short Ks[64][PT_];
  __shared__ unsigned short VT[64][PT_];
  __shared__ unsigned short Ps[8][16][PT_];
  int tid = threadIdx.x;
  int h = blockIdx.y, b = blockIdx.z;
  int w = tid >> 6, lane = tid & 63;
  int lr = lane & 15, lg = lane >> 4;
  int q0 = blockIdx.x * 128 + w * 16;
  bool kRole = tid < 256;
  int t2 = kRole ? tid : tid - 256;
  int sr = t2 >> 2, sc0 = (t2 & 3) * 16;
  int vd0 = (t2 & 15) * 4, vk0 = (t2 >> 4) * 4;

  bh8 qf[2];
  {
    int qr = q0 + lr; if (qr >= S_) qr = S_ - 1;
    const unsigned short* qp = &QKV[((size_t)(b * S_ + qr) * 24 + h) * 64 + lg * 8];
    qf[0] = *(const bh8*)qp;
    qf[1] = *(const bh8*)(qp + 32);
  }
  f32x4 accO[4] = {};
  float m[4], lsum[4];
#pragma unroll
  for (int i = 0; i < 4; ++i) { m[i] = -1e30f; lsum[i] = 0.f; }

  bfu kA, kB;
  us4 vR[4];
  if (kRole) {
    int src = sr;
    size_t ts = (size_t)b * S_ + (src < S_ ? src : S_ - 1);
    const unsigned short* gp = &QKV[(ts * 24 + 8 + h) * 64 + sc0];
    kA.v = *(const bh8*)gp;
    kB.v = *(const bh8*)(gp + 8);
  } else {
#pragma unroll
    for (int j = 0; j < 4; ++j) {
      int s2 = vk0 + j;
      size_t t3 = (size_t)b * S_ + (s2 < S_ ? s2 : S_ - 1);
      vR[j] = *(const us4*)&QKV[(t3 * 24 + 16 + h) * 64 + vd0];
    }
  }

  for (int kt = 0; kt < S_; kt += 64) {
    __syncthreads();
    if (kRole) {
      sts16(&Ks[sr][sc0], kA);
      sts16(&Ks[sr][sc0 + 8], kB);
    } else {
#pragma unroll
      for (int dd = 0; dd < 4; ++dd) {
        us4 pk = {vR[0][dd], vR[1][dd], vR[2][dd], vR[3][dd]};
        *(us4*)&VT[vd0 + dd][vk0] = pk;
      }
    }
    __syncthreads();
    if (kt + 64 < S_) {
      if (kRole) {
        int src = kt + 64 + sr;
        size_t ts = (size_t)b * S_ + (src < S_ ? src : S_ - 1);
        const unsigned short* gp = &QKV[(ts * 24 + 8 + h) * 64 + sc0];
        kA.v = *(const bh8*)gp;
        kB.v = *(const bh8*)(gp + 8);
      } else {
#pragma unroll
        for (int j = 0; j < 4; ++j) {
          int s2 = kt + 64 + vk0 + j;
          size_t t3 = (size_t)b * S_ + (s2 < S_ ? s2 : S_ - 1);
          vR[j] = *(const us4*)&QKV[(t3 * 24 + 16 + h) * 64 + vd0];
        }
      }
    }
    f32x4 accS[4] = {};
#pragma unroll
    for (int ks = 0; ks < 2; ++ks)
#pragma unroll
      for (int fk = 0; fk < 4; ++fk)
        accS[fk] = __builtin_amdgcn_mfma_f32_16x16x32_bf16(qf[ks], lds16(&Ks[fk * 16 + lr][ks * 32 + lg * 8]), accS[fk], 0, 0, 0);
    float sc[4][4], pmax[4];
#pragma unroll
    for (int i = 0; i < 4; ++i) pmax[i] = -1e30f;
#pragma unroll
    for (int fk = 0; fk < 4; ++fk)
#pragma unroll
      for (int i = 0; i < 4; ++i) {
        float s = accS[fk][i] * SCALE_;
        if (kt + fk * 16 + lr >= S_) s = -1e30f;
        sc[fk][i] = s;
        pmax[i] = fmaxf(pmax[i], s);
      }
#pragma unroll
    for (int i = 0; i < 4; ++i) {
      float v = pmax[i];
      v = fmaxf(v, __shfl_xor(v, 1, 64));
      v = fmaxf(v, __shfl_xor(v, 2, 64));
      v = fmaxf(v, __shfl_xor(v, 4, 64));
      v = fmaxf(v, __shfl_xor(v, 8, 64));
      pmax[i] = v;
    }
    float psum[4];
#pragma unroll
    for (int i = 0; i < 4; ++i) {
      float mn = fmaxf(m[i], pmax[i]);
      float eo = __expf(m[i] - mn);
      m[i] = mn;
      lsum[i] *= eo;
#pragma unroll
      for (int fd = 0; fd < 4; ++fd) accO[fd][i] *= eo;
      psum[i] = 0.f;
    }
#pragma unroll
    for (int fk = 0; fk < 4; ++fk)
#pragma unroll
      for (int i = 0; i < 4; ++i) {
        float p = __expf(sc[fk][i] - m[i]);
        sc[fk][i] = p;
        psum[i] += p;
      }
#pragma unroll
    for (int i = 0; i < 4; ++i) {
      float v = psum[i];
      v += __shfl_xor(v, 1, 64);
      v += __shfl_xor(v, 2, 64);
      v += __shfl_xor(v, 4, 64);
      v += __shfl_xor(v, 8, 64);
      lsum[i] += v;
    }
#pragma unroll
    for (int fk = 0; fk < 4; ++fk)
#pragma unroll
      for (int i = 0; i < 4; ++i)
        Ps[w][lg * 4 + i][fk * 16 + lr] = f2bf(sc[fk][i]);
#pragma unroll
    for (int ks = 0; ks < 2; ++ks) {
      bh8 ap = lds16(&Ps[w][lr][ks * 32 + lg * 8]);
#pragma unroll
      for (int fd = 0; fd < 4; ++fd)
        accO[fd] = __builtin_amdgcn_mfma_f32_16x16x32_bf16(ap, lds16(&VT[fd * 16 + lr][ks * 32 + lg * 8]), accO[fd], 0, 0, 0);
    }
  }
#pragma unroll
  for (int i = 0; i < 4; ++i) {
    int q = q0 + lg * 4 + i;
    if (q < S_) {
      float linv = 1.f / lsum[i];
      size_t obase = (size_t)(b * S_ + q) * H_ + h * 64;
#pragma unroll
      for (int fd = 0; fd < 4; ++fd) AO[obase + fd * 16 + lr] = f2bf(accO[fd][i] * linv);
      if (lr == 0) {
        MB[((size_t)b * NH_ + h) * S_ + q] = m[i];
        LB[((size_t)b * NH_ + h) * S_ + q] = linv;
      }
    }
  }
}

// dQ pass, QBLK=128; fused delta (writes DB for kv3) + inverse-RoPE on output
__global__ __launch_bounds__(512) void k_attn_bwd_dq3(const unsigned short* __restrict__ QKV,
                                                      const unsigned short* __restrict__ O16,
                                                      const unsigned short* __restrict__ dO,
                                                      const float* __restrict__ MB,
                                                      const float* __restrict__ LB,
                                                      float* __restrict__ DB,
                                                      const float* __restrict__ Cs,
                                                      const float* __restrict__ Sn,
                                                      unsigned short* __restrict__ dQKV) {
  __shared__ unsigned short Ks[64][PT_];
  __shared__ unsigned short Vs[64][PT_];
  __shared__ unsigned short KT[64][PT_];
  __shared__ unsigned short Ps[8][16][PT_];
  int tid = threadIdx.x;
  int h = blockIdx.y, b = blockIdx.z;
  int w = tid >> 6, lane = tid & 63;
  int lr = lane & 15, lg = lane >> 4;
  int q0 = blockIdx.x * 128 + w * 16;
  size_t sbase = ((size_t)b * NH_ + h) * S_;
  bool kRole = tid < 256;
  int t2 = kRole ? tid : tid - 256;
  int sr = t2 >> 2, sc0 = (t2 & 3) * 16;
  int vd0 = (t2 & 15) * 4, vk0 = (t2 >> 4) * 4;

  bh8 qf[2], dof[2];
  float pd = 0.f;
  {
    int qr = q0 + lr; if (qr >= S_) qr = S_ - 1;
    const unsigned short* qp = &QKV[((size_t)(b * S_ + qr) * 24 + h) * 64 + lg * 8];
    const unsigned short* dp = &dO[(size_t)(b * S_ + qr) * H_ + h * 64 + lg * 8];
    const unsigned short* op = &O16[(size_t)(b * S_ + qr) * H_ + h * 64 + lg * 8];
    qf[0] = *(const bh8*)qp;  qf[1] = *(const bh8*)(qp + 32);
    dof[0] = *(const bh8*)dp; dof[1] = *(const bh8*)(dp + 32);
    bfu o0, o1, d0, d1;
    o0.v = *(const bh8*)op; o1.v = *(const bh8*)(op + 32);
    d0.v = dof[0]; d1.v = dof[1];
#pragma unroll
    for (int j = 0; j < 8; ++j)
      pd += b2f(o0.s[j]) * b2f(d0.s[j]) + b2f(o1.s[j]) * b2f(d1.s[j]);
    pd += __shfl_xor(pd, 16, 64);
    pd += __shfl_xor(pd, 32, 64);
    if (lg == 0 && q0 + lr < S_) DB[sbase + q0 + lr] = pd;
  }
  float mrow[4], lrow[4], drow[4];
#pragma unroll
  for (int i = 0; i < 4; ++i) {
    int q = q0 + lg * 4 + i; if (q >= S_) q = S_ - 1;
    mrow[i] = MB[sbase + q];
    lrow[i] = LB[sbase + q];
    drow[i] = __shfl(pd, lg * 4 + i, 64);
  }
  f32x4 accQ[4] = {};

  bfu pA{}, pB{}, pC{}, pD{};
  us4 rv[4];
  if (kRole) {
    int src = sr;
    bool vld = src < S_;
    size_t ts = (size_t)b * S_ + (vld ? src : S_ - 1);
    const unsigned short* kp = &QKV[(ts * 24 + 8 + h) * 64 + sc0];
    if (vld) {
      pA.v = *(const bh8*)kp;
      pB.v = *(const bh8*)(kp + 8);
      pC.v = *(const bh8*)(kp + 512);
      pD.v = *(const bh8*)(kp + 520);
    }
  } else {
#pragma unroll
    for (int j = 0; j < 4; ++j) {
      int s2 = vk0 + j;
      bool v2 = s2 < S_;
      size_t t3 = (size_t)b * S_ + (v2 ? s2 : S_ - 1);
      us4 t = *(const us4*)&QKV[(t3 * 24 + 8 + h) * 64 + vd0];
      if (!v2) t = us4{0, 0, 0, 0};
      rv[j] = t;
    }
  }

  for (int kt = 0; kt < S_; kt += 64) {
    __syncthreads();
    if (kRole) {
      sts16(&Ks[sr][sc0], pA); sts16(&Ks[sr][sc0 + 8], pB);
      sts16(&Vs[sr][sc0], pC); sts16(&Vs[sr][sc0 + 8], pD);
    } else {
#pragma unroll
      for (int dd = 0; dd < 4; ++dd) {
        us4 pk = {rv[0][dd], rv[1][dd], rv[2][dd], rv[3][dd]};
        *(us4*)&KT[vd0 + dd][vk0] = pk;
      }
    }
    __syncthreads();
    if (kt + 64 < S_) {
      if (kRole) {
        int src = kt + 64 + sr;
        bool vld = src < S_;
        size_t ts = (size_t)b * S_ + (vld ? src : S_ - 1);
        const unsigned short* kp = &QKV[(ts * 24 + 8 + h) * 64 + sc0];
        pA = bfu{}; pB = bfu{}; pC = bfu{}; pD = bfu{};
        if (vld) {
          pA.v = *(const bh8*)kp;
          pB.v = *(const bh8*)(kp + 8);
          pC.v = *(const bh8*)(kp + 512);
          pD.v = *(const bh8*)(kp + 520);
        }
      } else {
#pragma unroll
        for (int j = 0; j < 4; ++j) {
          int s2 = kt + 64 + vk0 + j;
          bool v2 = s2 < S_;
          size_t t3 = (size_t)b * S_ + (v2 ? s2 : S_ - 1);
          us4 t = *(const us4*)&QKV[(t3 * 24 + 8 + h) * 64 + vd0];
          if (!v2) t = us4{0, 0, 0, 0};
          rv[j] = t;
        }
      }
    }
    f32x4 aS[4] = {}, aD[4] = {};
#pragma unroll
    for (int ks = 0; ks < 2; ++ks)
#pragma unroll
      for (int fk = 0; fk < 4; ++fk) {
        aS[fk] = __builtin_amdgcn_mfma_f32_16x16x32_bf16(qf[ks], lds16(&Ks[fk * 16 + lr][ks * 32 + lg * 8]), aS[fk], 0, 0, 0);
        aD[fk] = __builtin_amdgcn_mfma_f32_16x16x32_bf16(dof[ks], lds16(&Vs[fk * 16 + lr][ks * 32 + lg * 8]), aD[fk], 0, 0, 0);
      }
#pragma unroll
    for (int fk = 0; fk < 4; ++fk)
#pragma unroll
      for (int i = 0; i < 4; ++i) {
        float p = __expf(aS[fk][i] * SCALE_ - mrow[i]) * lrow[i];
        float ds = p * (aD[fk][i] - drow[i]);
        Ps[w][lg * 4 + i][fk * 16 + lr] = f2bf(ds);
      }
#pragma unroll
    for (int ks = 0; ks < 2; ++ks) {
      bh8 ap = lds16(&Ps[w][lr][ks * 32 + lg * 8]);
#pragma unroll
      for (int fd = 0; fd < 4; ++fd)
        accQ[fd] = __builtin_amdgcn_mfma_f32_16x16x32_bf16(ap, lds16(&KT[fd * 16 + lr][ks * 32 + lg * 8]), accQ[fd], 0, 0, 0);
    }
  }
#pragma unroll
  for (int i = 0; i < 4; ++i) {
    int q = q0 + lg * 4 + i;
    if (q < S_) {
      size_t obase = ((size_t)(b * S_ + q) * 24 + h) * 64;
      float c0 = Cs[q * 32 + lr], s0 = Sn[q * 32 + lr];
      float c1 = Cs[q * 32 + 16 + lr], s1 = Sn[q * 32 + 16 + lr];
#pragma unroll
      for (int fd = 0; fd < 4; ++fd) {
        float x = SCALE_ * accQ[fd][i];
        float p = SCALE_ * accQ[fd ^ 2][i];
        float cc = (fd & 1) ? c1 : c0;
        float ss = (fd & 1) ? s1 : s0;
        float out = (fd < 2) ? (x * cc + p * ss) : (x * cc - p * ss);
        dQKV[obase + fd * 16 + lr] = f2bf(out);
      }
    }
  }
}

// dK + dV pass, QBLK=128; fused inverse-RoPE on dK; prefetch-under-compute
__global__ __launch_bounds__(512) void k_attn_bwd_kv3(const unsigned short* __restrict__ QKV,
                                                      const unsigned short* __restrict__ dO,
                                                      const float* __restrict__ MB,
                                                      const float* __restrict__ LB,
                                                      const float* __restrict__ DB,
                                                      const float* __restrict__ Cs,
                                                      const float* __restrict__ Sn,
                                                      unsigned short* __restrict__ dQKV) {
  __shared__ unsigned short Qs[64][PT_];
  __shared__ unsigned short dOs[64][PT_];
  __shared__ unsigned short QT[64][PT_];
  __shared__ unsigned short dOT[64][PT_];
  __shared__ unsigned short Ps[8][16][PT_];
  __shared__ float sM[64], sL[64], sD[64];
  int tid = threadIdx.x;
  int h = blockIdx.y, b = blockIdx.z;
  int w = tid >> 6, lane = tid & 63;
  int lr = lane & 15, lg = lane >> 4;
  int k0w = blockIdx.x * 128 + w * 16;
  size_t sbase = ((size_t)b * NH_ + h) * S_;
  bool kRole = tid < 256;
  int t2 = kRole ? tid : tid - 256;
  int sr = t2 >> 2, sc0 = (t2 & 3) * 16;
  int vd0 = (t2 & 15) * 4, vk0 = (t2 >> 4) * 4;

  bh8 kf[2], vf[2];
  {
    int kr = k0w + lr; if (kr >= S_) kr = S_ - 1;
    const unsigned short* kp = &QKV[((size_t)(b * S_ + kr) * 24 + 8 + h) * 64 + lg * 8];
    kf[0] = *(const bh8*)kp;        kf[1] = *(const bh8*)(kp + 32);
    vf[0] = *(const bh8*)(kp + 512); vf[1] = *(const bh8*)(kp + 544);
  }
  f32x4 accK[4] = {}, accV[4] = {};

  bfu pA{}, pB{}, pC{}, pD{};
  us4 rq[4], rd[4];
  float stM = 0.f, stL = 0.f, stD = 0.f;
  if (kRole) {
    int src = sr;
    bool vld = src < S_;
    size_t ts = (size_t)b * S_ + (vld ? src : S_ - 1);
    const unsigned short* qp = &QKV[(ts * 24 + h) * 64 + sc0];
    const unsigned short* dp = &dO[ts * H_ + h * 64 + sc0];
    pA.v = *(const bh8*)qp;
    pB.v = *(const bh8*)(qp + 8);
    if (vld) {
      pC.v = *(const bh8*)dp;
      pD.v = *(const bh8*)(dp + 8);
    }
    if (tid < 64) {
      bool v2 = tid < S_;
      int sc = v2 ? tid : S_ - 1;
      stM = MB[sbase + sc];
      stL = LB[sbase + sc];
      stD = v2 ? DB[sbase + sc] : 0.f;
    }
  } else {
#pragma unroll
    for (int j = 0; j < 4; ++j) {
      int s2 = vk0 + j;
      bool v2 = s2 < S_;
      size_t t3 = (size_t)b * S_ + (v2 ? s2 : S_ - 1);
      rq[j] = *(const us4*)&QKV[(t3 * 24 + h) * 64 + vd0];
      us4 td = *(const us4*)&dO[t3 * H_ + h * 64 + vd0];
      if (!v2) td = us4{0, 0, 0, 0};
      rd[j] = td;
    }
  }

  for (int qt = 0; qt < S_; qt += 64) {
    __syncthreads();
    if (kRole) {
      sts16(&Qs[sr][sc0], pA);  sts16(&Qs[sr][sc0 + 8], pB);
      sts16(&dOs[sr][sc0], pC); sts16(&dOs[sr][sc0 + 8], pD);
      if (tid < 64) {
        sM[tid] = stM;
        sL[tid] = stL;
        sD[tid] = stD;
      }
    } else {
#pragma unroll
      for (int dd = 0; dd < 4; ++dd) {
        us4 pq = {rq[0][dd], rq[1][dd], rq[2][dd], rq[3][dd]};
        us4 pd = {rd[0][dd], rd[1][dd], rd[2][dd], rd[3][dd]};
        *(us4*)&QT[vd0 + dd][vk0] = pq;
        *(us4*)&dOT[vd0 + dd][vk0] = pd;
      }
    }
    __syncthreads();
    if (qt + 64 < S_) {
      if (kRole) {
        int src = qt + 64 + sr;
        bool vld = src < S_;
        size_t ts = (size_t)b * S_ + (vld ? src : S_ - 1);
        const unsigned short* qp = &QKV[(ts * 24 + h) * 64 + sc0];
        const unsigned short* dp = &dO[ts * H_ + h * 64 + sc0];
        pA.v = *(const bh8*)qp;
        pB.v = *(const bh8*)(qp + 8);
        pC = bfu{}; pD = bfu{};
        if (vld) {
          pC.v = *(const bh8*)dp;
          pD.v = *(const bh8*)(dp + 8);
        }
        if (tid < 64) {
          int s2 = qt + 64 + tid;
          bool v2 = s2 < S_;
          int sc = v2 ? s2 : S_ - 1;
          stM = MB[sbase + sc];
          stL = LB[sbase + sc];
          stD = v2 ? DB[sbase + sc] : 0.f;
        }
      } else {
#pragma unroll
        for (int j = 0; j < 4; ++j) {
          int s2 = qt + 64 + vk0 + j;
          bool v2 = s2 < S_;
          size_t t3 = (size_t)b * S_ + (v2 ? s2 : S_ - 1);
          rq[j] = *(const us4*)&QKV[(t3 * 24 + h) * 64 + vd0];
          us4 td = *(const us4*)&dO[t3 * H_ + h * 64 + vd0];
          if (!v2) td = us4{0, 0, 0, 0};
          rd[j] = td;
        }
      }
    }
    f32x4 aS[4] = {}, aD[4] = {};
#pragma unroll
    for (int ks = 0; ks < 2; ++ks)
#pragma unroll
      for (int fq = 0; fq < 4; ++fq) {
        aS[fq] = __builtin_amdgcn_mfma_f32_16x16x32_bf16(kf[ks], lds16(&Qs[fq * 16 + lr][ks * 32 + lg * 8]), aS[fq], 0, 0, 0);
        aD[fq] = __builtin_amdgcn_mfma_f32_16x16x32_bf16(vf[ks], lds16(&dOs[fq * 16 + lr][ks * 32 + lg * 8]), aD[fq], 0, 0, 0);
      }
    float pv[4][4];
#pragma unroll
    for (int fq = 0; fq < 4; ++fq) {
      float mq = sM[fq * 16 + lr], lq = sL[fq * 16 + lr];
#pragma unroll
      for (int i = 0; i < 4; ++i) {
        float p = __expf(aS[fq][i] * SCALE_ - mq) * lq;
        pv[fq][i] = p;
        Ps[w][lg * 4 + i][fq * 16 + lr] = f2bf(p);
      }
    }
#pragma unroll
    for (int qs = 0; qs < 2; ++qs) {
      bh8 ap = lds16(&Ps[w][lr][qs * 32 + lg * 8]);
#pragma unroll
      for (int fd = 0; fd < 4; ++fd)
        accV[fd] = __builtin_amdgcn_mfma_f32_16x16x32_bf16(ap, lds16(&dOT[fd * 16 + lr][qs * 32 + lg * 8]), accV[fd], 0, 0, 0);
    }
#pragma unroll
    for (int fq = 0; fq < 4; ++fq) {
      float dq = sD[fq * 16 + lr];
#pragma unroll
      for (int i = 0; i < 4; ++i)
        Ps[w][lg * 4 + i][fq * 16 + lr] = f2bf(pv[fq][i] * (aD[fq][i] - dq));
    }
#pragma unroll
    for (int qs = 0; qs < 2; ++qs) {
      bh8 ap = lds16(&Ps[w][lr][qs * 32 + lg * 8]);
#pragma unroll
      for (int fd = 0; fd < 4; ++fd)
        accK[fd] = __builtin_amdgcn_mfma_f32_16x16x32_bf16(ap, lds16(&QT[fd * 16 + lr][qs * 32 + lg * 8]), accK[fd], 0, 0, 0);
    }
  }
#pragma unroll
  for (int i = 0; i < 4; ++i) {
    int k = k0w + lg * 4 + i;
    if (k < S_) {
      size_t obase = ((size_t)(b * S_ + k) * 24 + 8 + h) * 64;
      float c0 = Cs[k * 32 + lr], s0 = Sn[k * 32 + lr];
      float c1 = Cs[k * 32 + 16 + lr], s1 = Sn[k * 32 + 16 + lr];
#pragma unroll
      for (int fd = 0; fd < 4; ++fd) {
        float x = SCALE_ * accK[fd][i];
        float p = SCALE_ * accK[fd ^ 2][i];
        float cc = (fd & 1) ? c1 : c0;
        float ss = (fd & 1) ? s1 : s0;
        float out = (fd < 2) ? (x * cc + p * ss) : (x * cc - p * ss);
        dQKV[obase + fd * 16 + lr] = f2bf(out);
        dQKV[obase + 512 + fd * 16 + lr] = f2bf(accV[fd][i]);
      }
    }
  }
}

// ---------------- RMS norm fwd/bwd (dual fp32+bf16 outputs) ----------------

__global__ __launch_bounds__(256) void k_rms_fwd(const float* __restrict__ X, float* __restrict__ Y,
                                                 unsigned short* __restrict__ Y16) {
  int t = blockIdx.x, tid = threadIdx.x;
  float x0 = X[(size_t)t * H_ + tid], x1 = X[(size_t)t * H_ + tid + 256];
  __shared__ float red[256];
  red[tid] = x0 * x0 + x1 * x1;
  __syncthreads();
  for (int s = 128; s > 0; s >>= 1) {
    if (tid < s) red[tid] += red[tid + s];
    __syncthreads();
  }
  float r = rsqrtf(red[0] / H_ + EPS_);
  float y0 = x0 * r, y1 = x1 * r;
  Y[(size_t)t * H_ + tid] = y0;
  Y[(size_t)t * H_ + tid + 256] = y1;
  Y16[(size_t)t * H_ + tid] = f2bf(y0);
  Y16[(size_t)t * H_ + tid + 256] = f2bf(y1);
}

// EWB: incoming gradient is the broadcast energy vector ew[col] (topmost layer)
template <int EWB>
__global__ __launch_bounds__(256) void k_rms_bwd(const float* __restrict__ X,
                                                 const float* __restrict__ GY,
                                                 const float* __restrict__ EW,
                                                 float* __restrict__ GX,
                                                 unsigned short* __restrict__ GX16) {
  int t = blockIdx.x, tid = threadIdx.x;
  float x0 = X[(size_t)t * H_ + tid], x1 = X[(size_t)t * H_ + tid + 256];
  float g0, g1;
  if (EWB) {
    g0 = EW[tid];
    g1 = EW[tid + 256];
  } else {
    g0 = GY[(size_t)t * H_ + tid];
    g1 = GY[(size_t)t * H_ + tid + 256];
  }
  __shared__ float r1[256], r2[256];
  r1[tid] = x0 * x0 + x1 * x1;
  r2[tid] = x0 * g0 + x1 * g1;
  __syncthreads();
  for (int s = 128; s > 0; s >>= 1) {
    if (tid < s) { r1[tid] += r1[tid + s]; r2[tid] += r2[tid + s]; }
    __syncthreads();
  }
  float r = rsqrtf(r1[0] / H_ + EPS_);
  float coef = r * r * r * r2[0] / (float)H_;
  float o0 = r * g0 - coef * x0, o1 = r * g1 - coef * x1;
  GX[(size_t)t * H_ + tid] = o0;
  GX[(size_t)t * H_ + tid + 256] = o1;
  GX16[(size_t)t * H_ + tid] = f2bf(o0);
  GX16[(size_t)t * H_ + tid + 256] = f2bf(o1);
}

// ---------------- logits update ----------------

__global__ __launch_bounds__(64) void k_logits_update(const float* __restrict__ G,
                                                      const float* __restrict__ E,
                                                      const float* __restrict__ P,
                                                      const float* __restrict__ alpha,
                                                      float* __restrict__ logits) {
  int t = blockIdx.x, lane = threadIdx.x;
  float dp[V_];
#pragma unroll
  for (int v = 0; v < V_; ++v) dp[v] = 0.f;
  for (int hh = lane; hh < H_; hh += 64) {
    float gh = G[(size_t)t * H_ + hh];
#pragma unroll
    for (int v = 0; v < V_; ++v) dp[v] += gh * E[v * H_ + hh];
  }
#pragma unroll
  for (int v = 0; v < V_; ++v) dp[v] = wave_sum64(dp[v]) * ESCALE_;
  float dot = 0.f;
  float pv[V_];
#pragma unroll
  for (int v = 0; v < V_; ++v) {
    pv[v] = P[t * V_ + v];
    dot += pv[v] * dp[v];
  }
  float a = fmaxf(alpha[0], 1e-4f);
  if (lane < V_) logits[t * V_ + lane] -= a * pv[lane] * (dp[lane] - dot);
}

// ---------------- host-side orchestration ----------------

struct Ctx {
  unsigned short *Q16, *Q016, *dQ16, *GU16, *DO16, *AO16, *AO016, *X116, *UDX16, *U016;
  float *X1, *X2, *X20, *G, *UDX, *P, *MB, *LB, *DB, *MB0, *LB0, *CS, *SN;
  const float* EW;
  const unsigned short *WTqkv[2], *WTo[2], *WTgu[2], *WTd[2];
  const unsigned short *WSqkv[2], *WSo[2], *WSgu[2], *WSd[2];
  hipStream_t st;
};

static void block_forward(Ctx& c, int l, const float* hin, const unsigned short* hin16,
                          float* hout, unsigned short* qb, unsigned short* ao,
                          float* mb, float* lb, float* x2buf, unsigned short* u16buf) {
  k_gemm<128, 0, 0, 1, 1, 0><<<dim3(3 * H_ / 128, (NTOK + 127) / 128), 256, 0, c.st>>>(
      hin16, c.WTqkv[l], nullptr, nullptr, qb, nullptr, c.CS, c.SN, NTOK, 3 * H_, H_, H_);
  k_attn_fwd3<<<dim3((S_ + 127) / 128, NH_, B_), 512, 0, c.st>>>(qb, ao, mb, lb);
  k_gemm<64, 0, 1, 0, 0, 0><<<dim3(H_ / 128, (NTOK + 63) / 64), 256, 0, c.st>>>(
      ao, c.WTo[l], hin, c.X1, nullptr, nullptr, nullptr, nullptr, NTOK, H_, H_, H_);
  k_rms_fwd<<<NTOK, 256, 0, c.st>>>(c.X1, c.UDX, u16buf);
  k_gemm<128, 0, 0, 1, 0, 0><<<dim3(2 * INNER_ / 128, (NTOK + 127) / 128), 256, 0, c.st>>>(
      u16buf, c.WTgu[l], nullptr, nullptr, c.GU16, nullptr, nullptr, nullptr, NTOK, 2 * INNER_, H_, H_);
  k_gemm<64, 1, 1, 0, 0, 0><<<dim3(H_ / 128, (NTOK + 63) / 64), 256, 0, c.st>>>(
      c.GU16, c.WTd[l], c.UDX, x2buf, nullptr, nullptr, nullptr, nullptr, NTOK, H_, INNER_, 2 * INNER_);
  if (hout) k_rms_fwd<<<NTOK, 256, 0, c.st>>>(x2buf, hout, c.UDX16);
}

static void block_backward(Ctx& c, int l, const float* hin, const unsigned short* hin16,
                           unsigned short* qb, unsigned short* ao, float* mb, float* lb,
                           bool full) {
  const float* x2src;
  if (full) {
    block_forward(c, l, hin, hin16, nullptr, qb, ao, mb, lb, c.X2, c.UDX16);
    x2src = c.X2;
  } else {
    k_gemm<64, 0, 1, 0, 0, 0><<<dim3(H_ / 128, (NTOK + 63) / 64), 256, 0, c.st>>>(
        ao, c.WTo[l], hin, c.X1, nullptr, nullptr, nullptr, nullptr, NTOK, H_, H_, H_);
    k_gemm<128, 0, 0, 1, 0, 0><<<dim3(2 * INNER_ / 128, (NTOK + 127) / 128), 256, 0, c.st>>>(
        c.U016, c.WTgu[l], nullptr, nullptr, c.GU16, nullptr, nullptr, nullptr, NTOK, 2 * INNER_, H_, H_);
    x2src = c.X20;
  }
  // topmost layer (full==true, L1) receives broadcast ew as incoming gradient
  if (full)
    k_rms_bwd<1><<<NTOK, 256, 0, c.st>>>(x2src, nullptr, c.EW, c.UDX, c.UDX16);
  else
    k_rms_bwd<0><<<NTOK, 256, 0, c.st>>>(x2src, c.G, nullptr, c.UDX, c.UDX16);
  k_gemm<128, 0, 0, 0, 0, 1><<<dim3(INNER_ / 128, (NTOK + 127) / 128), 256, 0, c.st>>>(
      c.UDX16, c.WSd[l], nullptr, nullptr, nullptr, c.GU16, nullptr, nullptr, NTOK, INNER_, H_, H_);
  k_gemm<64, 0, 1, 0, 0, 0><<<dim3(H_ / 128, (NTOK + 63) / 64), 256, 0, c.st>>>(
      c.GU16, c.WSgu[l], c.UDX, c.G, nullptr, nullptr, nullptr, nullptr, NTOK, H_, 2 * INNER_, 2 * INNER_);
  k_rms_bwd<0><<<NTOK, 256, 0, c.st>>>(c.X1, c.G, nullptr, c.UDX, c.UDX16);
  k_gemm<64, 0, 0, 1, 0, 0><<<dim3(H_ / 128, (NTOK + 63) / 64), 256, 0, c.st>>>(
      c.UDX16, c.WSo[l], nullptr, nullptr, c.DO16, nullptr, nullptr, nullptr, NTOK, H_, H_, H_);
  dim3 agrid128((S_ + 127) / 128, NH_, B_);
  k_attn_bwd_dq3<<<agrid128, 512, 0, c.st>>>(qb, ao, c.DO16, mb, lb, c.DB, c.CS, c.SN, c.dQ16);
  k_attn_bwd_kv3<<<agrid128, 512, 0, c.st>>>(qb, c.DO16, mb, lb, c.DB, c.CS, c.SN, c.dQ16);
  k_gemm<64, 0, 1, 0, 0, 0><<<dim3(H_ / 128, (NTOK + 63) / 64), 256, 0, c.st>>>(
      c.dQ16, c.WSqkv[l], c.UDX, c.G, nullptr, nullptr, nullptr, nullptr, NTOK, H_, 3 * H_, 3 * H_);
}

extern "C" void kernel_launch(void* const* d_in, const int* in_sizes, int n_in,
                              void* d_out, int out_size, void* d_ws, size_t ws_size,
                              hipStream_t stream) {
  const int* inputs = (const int*)d_in[0];
  const float* E = (const float*)d_in[2];
  const float* ew = (const float*)d_in[3];
  const float* qkvw = (const float*)d_in[4];
  const float* ow = (const float*)d_in[5];
  const float* guw = (const float*)d_in[6];
  const float* dw = (const float*)d_in[7];
  const float* alpha = (const float*)d_in[8];
  float* logits = (float*)d_out;

  const size_t WT_FLOATS = 3407872;
  const size_t NEED =
      3 * ((size_t)NTOK * 3 * H_ / 2) +
      ((size_t)NTOK * INNER_) +
      5 * ((size_t)NTOK * H_) +
      6 * ((size_t)NTOK * H_ / 2) +
      ((size_t)NTOK * V_) +
      5 * ((size_t)B_ * NH_ * S_) +
      2 * ((size_t)S_ * 32) +
      2 * WT_FLOATS;
  if (ws_size < NEED * sizeof(float)) {
    k_zero<<<(NTOK * V_ + 255) / 256, 256, 0, stream>>>(logits, NTOK * V_);
    return;
  }

  float* f = (float*)d_ws;
  Ctx c;
  c.st = stream;
  c.EW = ew;
  c.Q16 = (unsigned short*)f;  f += (size_t)NTOK * 3 * H_ / 2;
  c.Q016 = (unsigned short*)f; f += (size_t)NTOK * 3 * H_ / 2;
  c.dQ16 = (unsigned short*)f; f += (size_t)NTOK * 3 * H_ / 2;
  c.GU16 = (unsigned short*)f; f += (size_t)NTOK * INNER_;
  c.X1 = f;   f += (size_t)NTOK * H_;
  c.X2 = f;   f += (size_t)NTOK * H_;
  c.X20 = f;  f += (size_t)NTOK * H_;
  c.G = f;    f += (size_t)NTOK * H_;
  c.UDX = f;  f += (size_t)NTOK * H_;
  c.AO16 = (unsigned short*)f;  f += (size_t)NTOK * H_ / 2;
  c.AO016 = (unsigned short*)f; f += (size_t)NTOK * H_ / 2;
  c.DO16 = (unsigned short*)f;  f += (size_t)NTOK * H_ / 2;
  c.X116 = (unsigned short*)f;  f += (size_t)NTOK * H_ / 2;
  c.UDX16 = (unsigned short*)f; f += (size_t)NTOK * H_ / 2;
  c.U016 = (unsigned short*)f;  f += (size_t)NTOK * H_ / 2;
  c.P = f;    f += (size_t)NTOK * V_;
  c.MB = f;   f += (size_t)B_ * NH_ * S_;
  c.LB = f;   f += (size_t)B_ * NH_ * S_;
  c.DB = f;   f += (size_t)B_ * NH_ * S_;
  c.MB0 = f;  f += (size_t)B_ * NH_ * S_;
  c.LB0 = f;  f += (size_t)B_ * NH_ * S_;
  c.CS = f;   f += (size_t)S_ * 32;
  c.SN = f;   f += (size_t)S_ * 32;
  unsigned short* wt = (unsigned short*)f;

  const size_t LQKV = (size_t)H_ * 3 * H_;
  const size_t LO = (size_t)H_ * H_;
  const size_t LGU = (size_t)H_ * 2 * INNER_;
  const size_t LD = (size_t)INNER_ * H_;

  for (int l = 0; l < 2; ++l) {
    c.WTqkv[l] = wt;
    k_wt<<<dim3(3 * H_ / 32, H_ / 32), dim3(32, 8), 0, stream>>>(qkvw + l * LQKV, wt, H_, 3 * H_);
    wt += LQKV;
    c.WTo[l] = wt;
    k_wt<<<dim3(H_ / 32, H_ / 32), dim3(32, 8), 0, stream>>>(ow + l * LO, wt, H_, H_);
    wt += LO;
    c.WTgu[l] = wt;
    k_wt<<<dim3(2 * INNER_ / 32, H_ / 32), dim3(32, 8), 0, stream>>>(guw + l * LGU, wt, H_, 2 * INNER_);
    wt += LGU;
    c.WTd[l] = wt;
    k_wt<<<dim3(H_ / 32, INNER_ / 32), dim3(32, 8), 0, stream>>>(dw + l * LD, wt, INNER_, H_);
    wt += LD;
  }
  {
    unsigned short* ws = wt;
    k_cast8<<<(int)((2 * LQKV / 8 + 255) / 256), 256, 0, stream>>>(qkvw, ws, (int)(2 * LQKV / 8));
    c.WSqkv[0] = ws; c.WSqkv[1] = ws + LQKV; ws += 2 * LQKV;
    k_cast8<<<(int)((2 * LO / 8 + 255) / 256), 256, 0, stream>>>(ow, ws, (int)(2 * LO / 8));
    c.WSo[0] = ws; c.WSo[1] = ws + LO; ws += 2 * LO;
    k_cast8<<<(int)((2 * LGU / 8 + 255) / 256), 256, 0, stream>>>(guw, ws, (int)(2 * LGU / 8));
    c.WSgu[0] = ws; c.WSgu[1] = ws + LGU; ws += 2 * LGU;
    k_cast8<<<(int)((2 * LD / 8 + 255) / 256), 256, 0, stream>>>(dw, ws, (int)(2 * LD / 8));
    c.WSd[0] = ws; c.WSd[1] = ws + LD;
  }

  k_zero<<<(NTOK * V_ + 255) / 256, 256, 0, stream>>>(logits, NTOK * V_);
  k_rope_tables<<<(S_ * 32 + 255) / 256, 256, 0, stream>>>(c.CS, c.SN);

  for (int step = 0; step < STEPS_; ++step) {
    // h0 (+ fused softmax -> P) -> X1
    k_h0<1><<<NTOK, 256, 0, stream>>>(logits, c.P, E, inputs, c.X1, c.X116);
    block_forward(c, 0, c.X1, c.X116, c.UDX, c.Q016, c.AO016, c.MB0, c.LB0, c.X20, c.U016);
    block_backward(c, 1, c.UDX, c.UDX16, c.Q16, c.AO16, c.MB, c.LB, true);
    k_h0<0><<<NTOK, 256, 0, stream>>>(nullptr, c.P, E, inputs, c.X1, c.X116);
    block_backward(c, 0, c.X1, c.X116, c.Q016, c.AO016, c.MB0, c.LB0, false);
    k_logits_update<<<NTOK, 64, 0, stream>>>(c.G, E, c.P, alpha, logits);
  }
}

// Round 17
// 2246.879 us; speedup vs baseline: 2.9079x; 1.0074x over previous
//
#include <hip/hip_runtime.h>
#include <math.h>

#define B_ 8
#define S_ 900
#define V_ 11
#define H_ 512
#define NH_ 8
#define HD_ 64
#define INNER_ 1536
#define STEPS_ 2
#define NTOK (B_*S_)
#define EPS_ 1e-5f
#define THETA_ 10000.0f
#define ESCALE_ 22.627416997969522f
#define SCALE_ 0.125f
#define PT_ 68   // attention LDS pitch (ushorts): 136B rows, 8B-aligned (b64 floor pattern)

typedef __attribute__((ext_vector_type(8))) short bh8;
typedef __attribute__((ext_vector_type(4))) float f32x4;
typedef __attribute__((ext_vector_type(4))) unsigned short us4;

union bfu { bh8 v; unsigned short s[8]; us4 q[2]; };

__device__ inline unsigned short f2bf(float x) {
  unsigned u = __builtin_bit_cast(unsigned, x);
  return (unsigned short)((u + 0x7FFFu + ((u >> 16) & 1u)) >> 16);
}
__device__ inline float b2f(unsigned short s) {
  return __builtin_bit_cast(float, (unsigned)s << 16);
}

// async global->LDS, 16B per lane; LDS dest = wave-uniform base + lane*16
__device__ inline void gld16(const unsigned short* g, unsigned short* l) {
  __builtin_amdgcn_global_load_lds(
      (const __attribute__((address_space(1))) void*)(g),
      (__attribute__((address_space(3))) void*)(l), 16, 0, 0);
}

__device__ inline bh8 lds16(const unsigned short* p) {
  bfu u;
  u.q[0] = *(const us4*)p;
  u.q[1] = *(const us4*)(p + 4);
  return u.v;
}
__device__ inline void sts16(unsigned short* p, bfu u) {
  *(us4*)p = u.q[0];
  *(us4*)(p + 4) = u.q[1];
}

__device__ inline float wave_sum64(float x) {
#pragma unroll
  for (int off = 32; off > 0; off >>= 1) x += __shfl_xor(x, off, 64);
  return x;
}

// ---------------- small kernels ----------------

__global__ void k_zero(float* p, int n) {
  int i = blockIdx.x * blockDim.x + threadIdx.x;
  if (i < n) p[i] = 0.f;
}

__global__ void k_rope_tables(float* cs, float* sn) {
  int idx = blockIdx.x * blockDim.x + threadIdx.x;
  if (idx >= S_ * 32) return;
  int s = idx >> 5, i = idx & 31;
  float freq = powf(THETA_, -(float)i / 32.0f);
  float ang = (float)s * freq;
  cs[idx] = cosf(ang);
  sn[idx] = sinf(ang);
}

// h0 -> fp32 + bf16; DOSM: compute P from logits in-block (and store P)
template <int DOSM>
__global__ void k_h0(const float* __restrict__ logits, float* __restrict__ P,
                     const float* __restrict__ E,
                     const int* __restrict__ inp, float* __restrict__ h0,
                     unsigned short* __restrict__ h016) {
  int t = blockIdx.x;
  int tid = threadIdx.x;
  __shared__ float p[V_];
  __shared__ int iw;
  if (DOSM) {
    if (tid == 0) {
      float x[V_];
      float m = -1e30f;
#pragma unroll
      for (int v = 0; v < V_; ++v) { x[v] = logits[t * V_ + v]; m = fmaxf(m, x[v]); }
      float ssum = 0.f;
#pragma unroll
      for (int v = 0; v < V_; ++v) { x[v] = __expf(x[v] - m); ssum += x[v]; }
      float inv = 1.f / ssum;
#pragma unroll
      for (int v = 0; v < V_; ++v) {
        float pv = x[v] * inv;
        p[v] = pv;
        P[t * V_ + v] = pv;
      }
    }
  } else {
    if (tid < V_) p[tid] = P[t * V_ + tid];
  }
  if (tid == 0) iw = inp[t];
  __syncthreads();
  for (int h = tid; h < H_; h += blockDim.x) {
    float acc = E[iw * H_ + h];
#pragma unroll
    for (int v = 0; v < V_; ++v) acc += p[v] * E[v * H_ + h];
    float val = ESCALE_ * acc;
    h0[(size_t)t * H_ + h] = val;
    h016[(size_t)t * H_ + h] = f2bf(val);
  }
}

// fp32 -> bf16 cast, 8 elems/thread
__global__ void k_cast8(const float* __restrict__ X, unsigned short* __restrict__ Y, int n8) {
  int i = blockIdx.x * blockDim.x + threadIdx.x;
  if (i >= n8) return;
  const float4* p = (const float4*)(X + (size_t)i * 8);
  float4 a = p[0], b = p[1];
  bfu o;
  o.s[0] = f2bf(a.x); o.s[1] = f2bf(a.y); o.s[2] = f2bf(a.z); o.s[3] = f2bf(a.w);
  o.s[4] = f2bf(b.x); o.s[5] = f2bf(b.y); o.s[6] = f2bf(b.z); o.s[7] = f2bf(b.w);
  *(bh8*)(Y + (size_t)i * 8) = o.v;
}

// ---------------- weight transpose-convert: W[K][N] fp32 -> WT[N][K] bf16 ----------------

__global__ void k_wt(const float* __restrict__ W, unsigned short* __restrict__ WT, int K, int N) {
  __shared__ float t[32][33];
  int k0 = blockIdx.y * 32, n0 = blockIdx.x * 32;
  int tx = threadIdx.x, ty = threadIdx.y;
#pragma unroll
  for (int i = 0; i < 4; ++i)
    t[ty + 8 * i][tx] = W[(size_t)(k0 + ty + 8 * i) * N + n0 + tx];
  __syncthreads();
#pragma unroll
  for (int i = 0; i < 4; ++i)
    WT[(size_t)(n0 + ty + 8 * i) * K + k0 + tx] = f2bf(t[tx][ty + 8 * i]);
}

// ---------------- MFMA GEMM: C[M,N] = A[M,K] @ B^T (A,B bf16; B stored [N][K]) ----------------
// Stage-ahead double-buffer at BK=32: issue next tile's loads BEFORE compute so the
// barrier's vmcnt(0) drain waits on loads that had the MFMA phase in flight.
// LDS identical to the previous 2-sub-tile layout (no occupancy change).

template <int TM, int SILU_A, int ADD, int CBF, int ROPE, int SILUBWD>
__global__ __launch_bounds__(256) void k_gemm(const unsigned short* __restrict__ A16,
                                              const unsigned short* __restrict__ Bt,
                                              const float* __restrict__ Dm,
                                              float* __restrict__ Cf,
                                              unsigned short* __restrict__ C16,
                                              unsigned short* __restrict__ GU,
                                              const float* __restrict__ Cs,
                                              const float* __restrict__ Sn,
                                              int M, int N, int K, int lda) {
  __shared__ unsigned short As[2][TM][32];
  __shared__ unsigned short Bs[2][128][32];
  constexpr int FR = TM / 32;
  int tid = threadIdx.x;
  int m0 = blockIdx.y * TM, n0 = blockIdx.x * 128;
  int wid = tid >> 6, lane = tid & 63;
  int wr = (wid >> 1) * (FR * 16), wc = (wid & 1) * 64;
  int lr = lane & 15, lg = lane >> 4;
  int srow = lane >> 2, sck = (lane & 3) * 8;
  f32x4 acc[FR][4] = {};

  auto stage = [&](int buf, int kk) {
#pragma unroll
    for (int half = 0; half < TM / 64; ++half) {
      if (SILU_A) {
        int row = (tid >> 2) + 64 * half;
        int ck = (tid & 3) * 8;
        int gr = m0 + row; gr = gr < M ? gr : M - 1;
        const unsigned short* src = &A16[(size_t)gr * lda + kk + ck];
        bfu pa;
#pragma unroll
        for (int j = 0; j < 8; ++j) {
          float g = b2f(src[j]), u = b2f(src[INNER_ + j]);
          pa.s[j] = f2bf((g / (1.f + __expf(-g))) * u);
        }
        *(bh8*)&As[buf][row][ck] = pa.v;
      } else {
        int gr = m0 + 64 * half + wid * 16 + srow; gr = gr < M ? gr : M - 1;
        gld16(&A16[(size_t)gr * lda + kk + sck], &As[buf][64 * half + wid * 16][0]);
      }
    }
#pragma unroll
    for (int i = 0; i < 2; ++i) {
      int bb = wid * 2 + i;
      gld16(&Bt[(size_t)(n0 + bb * 16 + srow) * K + kk + sck], &Bs[buf][bb * 16][0]);
    }
  };

  stage(0, 0);
  __syncthreads();  // prologue drain (once)
  int nk = K >> 5;
  for (int t = 0; t < nk; ++t) {
    int cur = t & 1;
    if (t + 1 < nk) stage(cur ^ 1, (t + 1) << 5);   // in flight under compute
    bh8 av[FR], bv[4];
#pragma unroll
    for (int fr = 0; fr < FR; ++fr) av[fr] = *(const bh8*)&As[cur][wr + fr * 16 + lr][lg * 8];
#pragma unroll
    for (int fc = 0; fc < 4; ++fc) bv[fc] = *(const bh8*)&Bs[cur][wc + fc * 16 + lr][lg * 8];
#pragma unroll
    for (int fr = 0; fr < FR; ++fr)
#pragma unroll
      for (int fc = 0; fc < 4; ++fc)
        acc[fr][fc] = __builtin_amdgcn_mfma_f32_16x16x32_bf16(av[fr], bv[fc], acc[fr][fc], 0, 0, 0);
    __syncthreads();  // drains next-tile loads (covered by the MFMA phase)
  }
  bool rope_on = ROPE && (((n0 + wc) >> 6) < 16);
#pragma unroll
  for (int fr = 0; fr < FR; ++fr) {
    int r0 = m0 + wr + fr * 16 + lg * 4;
#pragma unroll
    for (int i = 0; i < 4; ++i) {
      int gr = r0 + i;
      if (gr >= M) continue;
      float c0 = 1.f, s0 = 0.f, c1 = 1.f, s1 = 0.f;
      if (ROPE) {
        if (rope_on) {
          int s = gr % S_;
          c0 = Cs[s * 32 + lr];      s0 = Sn[s * 32 + lr];
          c1 = Cs[s * 32 + 16 + lr]; s1 = Sn[s * 32 + 16 + lr];
        }
      }
#pragma unroll
      for (int fc = 0; fc < 4; ++fc) {
        int gc = n0 + wc + fc * 16 + lr;
        float out = acc[fr][fc][i];
        if (ROPE) {
          float part = acc[fr][fc ^ 2][i];
          float cc = (fc & 1) ? c1 : c0;
          float ss = (fc & 1) ? s1 : s0;
          out = (fc < 2) ? (out * cc - part * ss) : (out * cc + part * ss);
        }
        if (ADD) out += Dm[(size_t)gr * N + gc];
        if (SILUBWD) {
          size_t gb = (size_t)gr * (size_t)(2 * INNER_) + gc;
          float g = b2f(GU[gb]), u = b2f(GU[gb + INNER_]);
          float sig = 1.f / (1.f + __expf(-g));
          GU[gb] = f2bf(out * u * sig * (1.f + g * (1.f - sig)));
          GU[gb + INNER_] = f2bf(out * g * sig);
        } else if (CBF) {
          C16[(size_t)gr * N + gc] = f2bf(out);
        } else {
          Cf[(size_t)gr * N + gc] = out;
        }
      }
    }
  }
}

// ---------------- MFMA flash attention, QBLK=128 (8 waves), role-split staging ----------------

__global__ __launch_bounds__(512) void k_attn_fwd3(const unsigned short* __restrict__ QKV,
                                                   unsigned short* __restrict__ AO,
                                                   float* __restrict__ MB,
                                                   float* __restrict__ LB) {
  __shared__ unsigned short Ks[64][PT_];
  __shared__ unsigned short VT[64][PT_];
  __shared__ unsigned short Ps[8][16][PT_];
  int tid = threadIdx.x;
  int h = blockIdx.y, b = blockIdx.z;
  int w = tid >> 6, lane = tid & 63;
  int lr = lane & 15, lg = lane >> 4;
  int q0 = blockIdx.x * 128 + w * 16;
  bool kRole = tid < 256;
  int t2 = kRole ? tid : tid - 256;
  int sr = t2 >> 2, sc0 = (t2 & 3) * 16;
  int vd0 = (t2 & 15) * 4, vk0 = (t2 >> 4) * 4;

  bh8 qf[2];
  {
    int qr = q0 + lr; if (qr >= S_) qr = S_ - 1;
    const unsigned short* qp = &QKV[((size_t)(b * S_ + qr) * 24 + h) * 64 + lg * 8];
    qf[0] = *(const bh8*)qp;
    qf[1] = *(const bh8*)(qp + 32);
  }
  f32x4 accO[4] = {};
  float m[4], lsum[4];
#pragma unroll
  for (int i = 0; i < 4; ++i) { m[i] = -1e30f; lsum[i] = 0.f; }

  bfu kA, kB;
  us4 vR[4];
  if (kRole) {
    int src = sr;
    size_t ts = (size_t)b * S_ + (src < S_ ? src : S_ - 1);
    const unsigned short* gp = &QKV[(ts * 24 + 8 + h) * 64 + sc0];
    kA.v = *(const bh8*)gp;
    kB.v = *(const bh8*)(gp + 8);
  } else {
#pragma unroll
    for (int j = 0; j < 4; ++j) {
      int s2 = vk0 + j;
      size_t t3 = (size_t)b * S_ + (s2 < S_ ? s2 : S_ - 1);
      vR[j] = *(const us4*)&QKV[(t3 * 24 + 16 + h) * 64 + vd0];
    }
  }

  for (int kt = 0; kt < S_; kt += 64) {
    __syncthreads();
    if (kRole) {
      sts16(&Ks[sr][sc0], kA);
      sts16(&Ks[sr][sc0 + 8], kB);
    } else {
#pragma unroll
      for (int dd = 0; dd < 4; ++dd) {
        us4 pk = {vR[0][dd], vR[1][dd], vR[2][dd], vR[3][dd]};
        *(us4*)&VT[vd0 + dd][vk0] = pk;
      }
    }
    __syncthreads();
    if (kt + 64 < S_) {
      if (kRole) {
        int src = kt + 64 + sr;
        size_t ts = (size_t)b * S_ + (src < S_ ? src : S_ - 1);
        const unsigned short* gp = &QKV[(ts * 24 + 8 + h) * 64 + sc0];
        kA.v = *(const bh8*)gp;
        kB.v = *(const bh8*)(gp + 8);
      } else {
#pragma unroll
        for (int j = 0; j < 4; ++j) {
          int s2 = kt + 64 + vk0 + j;
          size_t t3 = (size_t)b * S_ + (s2 < S_ ? s2 : S_ - 1);
          vR[j] = *(const us4*)&QKV[(t3 * 24 + 16 + h) * 64 + vd0];
        }
      }
    }
    f32x4 accS[4] = {};
#pragma unroll
    for (int ks = 0; ks < 2; ++ks)
#pragma unroll
      for (int fk = 0; fk < 4; ++fk)
        accS[fk] = __builtin_amdgcn_mfma_f32_16x16x32_bf16(qf[ks], lds16(&Ks[fk * 16 + lr][ks * 32 + lg * 8]), accS[fk], 0, 0, 0);
    float sc[4][4], pmax[4];
#pragma unroll
    for (int i = 0; i < 4; ++i) pmax[i] = -1e30f;
#pragma unroll
    for (int fk = 0; fk < 4; ++fk)
#pragma unroll
      for (int i = 0; i < 4; ++i) {
        float s = accS[fk][i] * SCALE_;
        if (kt + fk * 16 + lr >= S_) s = -1e30f;
        sc[fk][i] = s;
        pmax[i] = fmaxf(pmax[i], s);
      }
#pragma unroll
    for (int i = 0; i < 4; ++i) {
      float v = pmax[i];
      v = fmaxf(v, __shfl_xor(v, 1, 64));
      v = fmaxf(v, __shfl_xor(v, 2, 64));
      v = fmaxf(v, __shfl_xor(v, 4, 64));
      v = fmaxf(v, __shfl_xor(v, 8, 64));
      pmax[i] = v;
    }
    float psum[4];
#pragma unroll
    for (int i = 0; i < 4; ++i) {
      float mn = fmaxf(m[i], pmax[i]);
      float eo = __expf(m[i] - mn);
      m[i] = mn;
      lsum[i] *= eo;
#pragma unroll
      for (int fd = 0; fd < 4; ++fd) accO[fd][i] *= eo;
      psum[i] = 0.f;
    }
#pragma unroll
    for (int fk = 0; fk < 4; ++fk)
#pragma unroll
      for (int i = 0; i < 4; ++i) {
        float p = __expf(sc[fk][i] - m[i]);
        sc[fk][i] = p;
        psum[i] += p;
      }
#pragma unroll
    for (int i = 0; i < 4; ++i) {
      float v = psum[i];
      v += __shfl_xor(v, 1, 64);
      v += __shfl_xor(v, 2, 64);
      v += __shfl_xor(v, 4, 64);
      v += __shfl_xor(v, 8, 64);
      lsum[i] += v;
    }
#pragma unroll
    for (int fk = 0; fk < 4; ++fk)
#pragma unroll
      for (int i = 0; i < 4; ++i)
        Ps[w][lg * 4 + i][fk * 16 + lr] = f2bf(sc[fk][i]);
#pragma unroll
    for (int ks = 0; ks < 2; ++ks) {
      bh8 ap = lds16(&Ps[w][lr][ks * 32 + lg * 8]);
#pragma unroll
      for (int fd = 0; fd < 4; ++fd)
        accO[fd] = __builtin_amdgcn_mfma_f32_16x16x32_bf16(ap, lds16(&VT[fd * 16 + lr][ks * 32 + lg * 8]), accO[fd], 0, 0, 0);
    }
  }
#pragma unroll
  for (int i = 0; i < 4; ++i) {
    int q = q0 + lg * 4 + i;
    if (q < S_) {
      float linv = 1.f / lsum[i];
      size_t obase = (size_t)(b * S_ + q) * H_ + h * 64;
#pragma unroll
      for (int fd = 0; fd < 4; ++fd) AO[obase + fd * 16 + lr] = f2bf(accO[fd][i] * linv);
      if (lr == 0) {
        MB[((size_t)b * NH_ + h) * S_ + q] = m[i];
        LB[((size_t)b * NH_ + h) * S_ + q] = linv;
      }
    }
  }
}

// dQ pass, QBLK=128; fused delta (writes DB for kv3) + inverse-RoPE on output
__global__ __launch_bounds__(512) void k_attn_bwd_dq3(const unsigned short* __restrict__ QKV,
                                                      const unsigned short* __restrict__ O16,
                                                      const unsigned short* __restrict__ dO,
                                                      const float* __restrict__ MB,
                                                      const float* __restrict__ LB,
                                                      float* __restrict__ DB,
                                                      const float* __restrict__ Cs,
                                                      const float* __restrict__ Sn,
                                                      unsigned short* __restrict__ dQKV) {
  __shared__ unsigned short Ks[64][PT_];
  __shared__ unsigned short Vs[64][PT_];
  __shared__ unsigned short KT[64][PT_];
  __shared__ unsigned short Ps[8][16][PT_];
  int tid = threadIdx.x;
  int h = blockIdx.y, b = blockIdx.z;
  int w = tid >> 6, lane = tid & 63;
  int lr = lane & 15, lg = lane >> 4;
  int q0 = blockIdx.x * 128 + w * 16;
  size_t sbase = ((size_t)b * NH_ + h) * S_;
  bool kRole = tid < 256;
  int t2 = kRole ? tid : tid - 256;
  int sr = t2 >> 2, sc0 = (t2 & 3) * 16;
  int vd0 = (t2 & 15) * 4, vk0 = (t2 >> 4) * 4;

  bh8 qf[2], dof[2];
  float pd = 0.f;
  {
    int qr = q0 + lr; if (qr >= S_) qr = S_ - 1;
    const unsigned short* qp = &QKV[((size_t)(b * S_ + qr) * 24 + h) * 64 + lg * 8];
    const unsigned short* dp = &dO[(size_t)(b * S_ + qr) * H_ + h * 64 + lg * 8];
    const unsigned short* op = &O16[(size_t)(b * S_ + qr) * H_ + h * 64 + lg * 8];
    qf[0] = *(const bh8*)qp;  qf[1] = *(const bh8*)(qp + 32);
    dof[0] = *(const bh8*)dp; dof[1] = *(const bh8*)(dp + 32);
    bfu o0, o1, d0, d1;
    o0.v = *(const bh8*)op; o1.v = *(const bh8*)(op + 32);
    d0.v = dof[0]; d1.v = dof[1];
#pragma unroll
    for (int j = 0; j < 8; ++j)
      pd += b2f(o0.s[j]) * b2f(d0.s[j]) + b2f(o1.s[j]) * b2f(d1.s[j]);
    pd += __shfl_xor(pd, 16, 64);
    pd += __shfl_xor(pd, 32, 64);
    if (lg == 0 && q0 + lr < S_) DB[sbase + q0 + lr] = pd;
  }
  float mrow[4], lrow[4], drow[4];
#pragma unroll
  for (int i = 0; i < 4; ++i) {
    int q = q0 + lg * 4 + i; if (q >= S_) q = S_ - 1;
    mrow[i] = MB[sbase + q];
    lrow[i] = LB[sbase + q];
    drow[i] = __shfl(pd, lg * 4 + i, 64);
  }
  f32x4 accQ[4] = {};

  bfu pA{}, pB{}, pC{}, pD{};
  us4 rv[4];
  if (kRole) {
    int src = sr;
    bool vld = src < S_;
    size_t ts = (size_t)b * S_ + (vld ? src : S_ - 1);
    const unsigned short* kp = &QKV[(ts * 24 + 8 + h) * 64 + sc0];
    if (vld) {
      pA.v = *(const bh8*)kp;
      pB.v = *(const bh8*)(kp + 8);
      pC.v = *(const bh8*)(kp + 512);
      pD.v = *(const bh8*)(kp + 520);
    }
  } else {
#pragma unroll
    for (int j = 0; j < 4; ++j) {
      int s2 = vk0 + j;
      bool v2 = s2 < S_;
      size_t t3 = (size_t)b * S_ + (v2 ? s2 : S_ - 1);
      us4 t = *(const us4*)&QKV[(t3 * 24 + 8 + h) * 64 + vd0];
      if (!v2) t = us4{0, 0, 0, 0};
      rv[j] = t;
    }
  }

  for (int kt = 0; kt < S_; kt += 64) {
    __syncthreads();
    if (kRole) {
      sts16(&Ks[sr][sc0], pA); sts16(&Ks[sr][sc0 + 8], pB);
      sts16(&Vs[sr][sc0], pC); sts16(&Vs[sr][sc0 + 8], pD);
    } else {
#pragma unroll
      for (int dd = 0; dd < 4; ++dd) {
        us4 pk = {rv[0][dd], rv[1][dd], rv[2][dd], rv[3][dd]};
        *(us4*)&KT[vd0 + dd][vk0] = pk;
      }
    }
    __syncthreads();
    if (kt + 64 < S_) {
      if (kRole) {
        int src = kt + 64 + sr;
        bool vld = src < S_;
        size_t ts = (size_t)b * S_ + (vld ? src : S_ - 1);
        const unsigned short* kp = &QKV[(ts * 24 + 8 + h) * 64 + sc0];
        pA = bfu{}; pB = bfu{}; pC = bfu{}; pD = bfu{};
        if (vld) {
          pA.v = *(const bh8*)kp;
          pB.v = *(const bh8*)(kp + 8);
          pC.v = *(const bh8*)(kp + 512);
          pD.v = *(const bh8*)(kp + 520);
        }
      } else {
#pragma unroll
        for (int j = 0; j < 4; ++j) {
          int s2 = kt + 64 + vk0 + j;
          bool v2 = s2 < S_;
          size_t t3 = (size_t)b * S_ + (v2 ? s2 : S_ - 1);
          us4 t = *(const us4*)&QKV[(t3 * 24 + 8 + h) * 64 + vd0];
          if (!v2) t = us4{0, 0, 0, 0};
          rv[j] = t;
        }
      }
    }
    f32x4 aS[4] = {}, aD[4] = {};
#pragma unroll
    for (int ks = 0; ks < 2; ++ks)
#pragma unroll
      for (int fk = 0; fk < 4; ++fk) {
        aS[fk] = __builtin_amdgcn_mfma_f32_16x16x32_bf16(qf[ks], lds16(&Ks[fk * 16 + lr][ks * 32 + lg * 8]), aS[fk], 0, 0, 0);
        aD[fk] = __builtin_amdgcn_mfma_f32_16x16x32_bf16(dof[ks], lds16(&Vs[fk * 16 + lr][ks * 32 + lg * 8]), aD[fk], 0, 0, 0);
      }
#pragma unroll
    for (int fk = 0; fk < 4; ++fk)
#pragma unroll
      for (int i = 0; i < 4; ++i) {
        float p = __expf(aS[fk][i] * SCALE_ - mrow[i]) * lrow[i];
        float ds = p * (aD[fk][i] - drow[i]);
        Ps[w][lg * 4 + i][fk * 16 + lr] = f2bf(ds);
      }
#pragma unroll
    for (int ks = 0; ks < 2; ++ks) {
      bh8 ap = lds16(&Ps[w][lr][ks * 32 + lg * 8]);
#pragma unroll
      for (int fd = 0; fd < 4; ++fd)
        accQ[fd] = __builtin_amdgcn_mfma_f32_16x16x32_bf16(ap, lds16(&KT[fd * 16 + lr][ks * 32 + lg * 8]), accQ[fd], 0, 0, 0);
    }
  }
#pragma unroll
  for (int i = 0; i < 4; ++i) {
    int q = q0 + lg * 4 + i;
    if (q < S_) {
      size_t obase = ((size_t)(b * S_ + q) * 24 + h) * 64;
      float c0 = Cs[q * 32 + lr], s0 = Sn[q * 32 + lr];
      float c1 = Cs[q * 32 + 16 + lr], s1 = Sn[q * 32 + 16 + lr];
#pragma unroll
      for (int fd = 0; fd < 4; ++fd) {
        float x = SCALE_ * accQ[fd][i];
        float p = SCALE_ * accQ[fd ^ 2][i];
        float cc = (fd & 1) ? c1 : c0;
        float ss = (fd & 1) ? s1 : s0;
        float out = (fd < 2) ? (x * cc + p * ss) : (x * cc - p * ss);
        dQKV[obase + fd * 16 + lr] = f2bf(out);
      }
    }
  }
}

// dK + dV pass, QBLK=128; dual P/D LDS buffers so both MFMA clusters run back-to-back
__global__ __launch_bounds__(512) void k_attn_bwd_kv3(const unsigned short* __restrict__ QKV,
                                                      const unsigned short* __restrict__ dO,
                                                      const float* __restrict__ MB,
                                                      const float* __restrict__ LB,
                                                      const float* __restrict__ DB,
                                                      const float* __restrict__ Cs,
                                                      const float* __restrict__ Sn,
                                                      unsigned short* __restrict__ dQKV) {
  __shared__ unsigned short Qs[64][PT_];
  __shared__ unsigned short dOs[64][PT_];
  __shared__ unsigned short QT[64][PT_];
  __shared__ unsigned short dOT[64][PT_];
  __shared__ unsigned short Ps[8][16][PT_];
  __shared__ unsigned short Ds[8][16][PT_];
  __shared__ float sM[64], sL[64], sD[64];
  int tid = threadIdx.x;
  int h = blockIdx.y, b = blockIdx.z;
  int w = tid >> 6, lane = tid & 63;
  int lr = lane & 15, lg = lane >> 4;
  int k0w = blockIdx.x * 128 + w * 16;
  size_t sbase = ((size_t)b * NH_ + h) * S_;
  bool kRole = tid < 256;
  int t2 = kRole ? tid : tid - 256;
  int sr = t2 >> 2, sc0 = (t2 & 3) * 16;
  int vd0 = (t2 & 15) * 4, vk0 = (t2 >> 4) * 4;

  bh8 kf[2], vf[2];
  {
    int kr = k0w + lr; if (kr >= S_) kr = S_ - 1;
    const unsigned short* kp = &QKV[((size_t)(b * S_ + kr) * 24 + 8 + h) * 64 + lg * 8];
    kf[0] = *(const bh8*)kp;        kf[1] = *(const bh8*)(kp + 32);
    vf[0] = *(const bh8*)(kp + 512); vf[1] = *(const bh8*)(kp + 544);
  }
  f32x4 accK[4] = {}, accV[4] = {};

  bfu pA{}, pB{}, pC{}, pD{};
  us4 rq[4], rd[4];
  float stM = 0.f, stL = 0.f, stD = 0.f;
  if (kRole) {
    int src = sr;
    bool vld = src < S_;
    size_t ts = (size_t)b * S_ + (vld ? src : S_ - 1);
    const unsigned short* qp = &QKV[(ts * 24 + h) * 64 + sc0];
    const unsigned short* dp = &dO[ts * H_ + h * 64 + sc0];
    pA.v = *(const bh8*)qp;
    pB.v = *(const bh8*)(qp + 8);
    if (vld) {
      pC.v = *(const bh8*)dp;
      pD.v = *(const bh8*)(dp + 8);
    }
    if (tid < 64) {
      bool v2 = tid < S_;
      int sc = v2 ? tid : S_ - 1;
      stM = MB[sbase + sc];
      stL = LB[sbase + sc];
      stD = v2 ? DB[sbase + sc] : 0.f;
    }
  } else {
#pragma unroll
    for (int j = 0; j < 4; ++j) {
      int s2 = vk0 + j;
      bool v2 = s2 < S_;
      size_t t3 = (size_t)b * S_ + (v2 ? s2 : S_ - 1);
      rq[j] = *(const us4*)&QKV[(t3 * 24 + h) * 64 + vd0];
      us4 td = *(const us4*)&dO[t3 * H_ + h * 64 + vd0];
      if (!v2) td = us4{0, 0, 0, 0};
      rd[j] = td;
    }
  }

  for (int qt = 0; qt < S_; qt += 64) {
    __syncthreads();
    if (kRole) {
      sts16(&Qs[sr][sc0], pA);  sts16(&Qs[sr][sc0 + 8], pB);
      sts16(&dOs[sr][sc0], pC); sts16(&dOs[sr][sc0 + 8], pD);
      if (tid < 64) {
        sM[tid] = stM;
        sL[tid] = stL;
        sD[tid] = stD;
      }
    } else {
#pragma unroll
      for (int dd = 0; dd < 4; ++dd) {
        us4 pq = {rq[0][dd], rq[1][dd], rq[2][dd], rq[3][dd]};
        us4 pd = {rd[0][dd], rd[1][dd], rd[2][dd], rd[3][dd]};
        *(us4*)&QT[vd0 + dd][vk0] = pq;
        *(us4*)&dOT[vd0 + dd][vk0] = pd;
      }
    }
    __syncthreads();
    if (qt + 64 < S_) {
      if (kRole) {
        int src = qt + 64 + sr;
        bool vld = src < S_;
        size_t ts = (size_t)b * S_ + (vld ? src : S_ - 1);
        const unsigned short* qp = &QKV[(ts * 24 + h) * 64 + sc0];
        const unsigned short* dp = &dO[ts * H_ + h * 64 + sc0];
        pA.v = *(const bh8*)qp;
        pB.v = *(const bh8*)(qp + 8);
        pC = bfu{}; pD = bfu{};
        if (vld) {
          pC.v = *(const bh8*)dp;
          pD.v = *(const bh8*)(dp + 8);
        }
        if (tid < 64) {
          int s2 = qt + 64 + tid;
          bool v2 = s2 < S_;
          int sc = v2 ? s2 : S_ - 1;
          stM = MB[sbase + sc];
          stL = LB[sbase + sc];
          stD = v2 ? DB[sbase + sc] : 0.f;
        }
      } else {
#pragma unroll
        for (int j = 0; j < 4; ++j) {
          int s2 = qt + 64 + vk0 + j;
          bool v2 = s2 < S_;
          size_t t3 = (size_t)b * S_ + (v2 ? s2 : S_ - 1);
          rq[j] = *(const us4*)&QKV[(t3 * 24 + h) * 64 + vd0];
          us4 td = *(const us4*)&dO[t3 * H_ + h * 64 + vd0];
          if (!v2) td = us4{0, 0, 0, 0};
          rd[j] = td;
        }
      }
    }
    f32x4 aS[4] = {}, aD[4] = {};
#pragma unroll
    for (int ks = 0; ks < 2; ++ks)
#pragma unroll
      for (int fq = 0; fq < 4; ++fq) {
        aS[fq] = __builtin_amdgcn_mfma_f32_16x16x32_bf16(kf[ks], lds16(&Qs[fq * 16 + lr][ks * 32 + lg * 8]), aS[fq], 0, 0, 0);
        aD[fq] = __builtin_amdgcn_mfma_f32_16x16x32_bf16(vf[ks], lds16(&dOs[fq * 16 + lr][ks * 32 + lg * 8]), aD[fq], 0, 0, 0);
      }
    // write BOTH P^T and dS^T, then run both MFMA clusters back-to-back
#pragma unroll
    for (int fq = 0; fq < 4; ++fq) {
      float mq = sM[fq * 16 + lr], lq = sL[fq * 16 + lr], dq = sD[fq * 16 + lr];
#pragma unroll
      for (int i = 0; i < 4; ++i) {
        float p = __expf(aS[fq][i] * SCALE_ - mq) * lq;
        Ps[w][lg * 4 + i][fq * 16 + lr] = f2bf(p);
        Ds[w][lg * 4 + i][fq * 16 + lr] = f2bf(p * (aD[fq][i] - dq));
      }
    }
#pragma unroll
    for (int qs = 0; qs < 2; ++qs) {
      bh8 ap = lds16(&Ps[w][lr][qs * 32 + lg * 8]);
      bh8 ad = lds16(&Ds[w][lr][qs * 32 + lg * 8]);
#pragma unroll
      for (int fd = 0; fd < 4; ++fd) {
        accV[fd] = __builtin_amdgcn_mfma_f32_16x16x32_bf16(ap, lds16(&dOT[fd * 16 + lr][qs * 32 + lg * 8]), accV[fd], 0, 0, 0);
        accK[fd] = __builtin_amdgcn_mfma_f32_16x16x32_bf16(ad, lds16(&QT[fd * 16 + lr][qs * 32 + lg * 8]), accK[fd], 0, 0, 0);
      }
    }
  }
#pragma unroll
  for (int i = 0; i < 4; ++i) {
    int k = k0w + lg * 4 + i;
    if (k < S_) {
      size_t obase = ((size_t)(b * S_ + k) * 24 + 8 + h) * 64;
      float c0 = Cs[k * 32 + lr], s0 = Sn[k * 32 + lr];
      float c1 = Cs[k * 32 + 16 + lr], s1 = Sn[k * 32 + 16 + lr];
#pragma unroll
      for (int fd = 0; fd < 4; ++fd) {
        float x = SCALE_ * accK[fd][i];
        float p = SCALE_ * accK[fd ^ 2][i];
        float cc = (fd & 1) ? c1 : c0;
        float ss = (fd & 1) ? s1 : s0;
        float out = (fd < 2) ? (x * cc + p * ss) : (x * cc - p * ss);
        dQKV[obase + fd * 16 + lr] = f2bf(out);
        dQKV[obase + 512 + fd * 16 + lr] = f2bf(accV[fd][i]);
      }
    }
  }
}

// ---------------- RMS norm fwd/bwd (dual fp32+bf16 outputs) ----------------

__global__ __launch_bounds__(256) void k_rms_fwd(const float* __restrict__ X, float* __restrict__ Y,
                                                 unsigned short* __restrict__ Y16) {
  int t = blockIdx.x, tid = threadIdx.x;
  float x0 = X[(size_t)t * H_ + tid], x1 = X[(size_t)t * H_ + tid + 256];
  __shared__ float red[256];
  red[tid] = x0 * x0 + x1 * x1;
  __syncthreads();
  for (int s = 128; s > 0; s >>= 1) {
    if (tid < s) red[tid] += red[tid + s];
    __syncthreads();
  }
  float r = rsqrtf(red[0] / H_ + EPS_);
  float y0 = x0 * r, y1 = x1 * r;
  Y[(size_t)t * H_ + tid] = y0;
  Y[(size_t)t * H_ + tid + 256] = y1;
  Y16[(size_t)t * H_ + tid] = f2bf(y0);
  Y16[(size_t)t * H_ + tid + 256] = f2bf(y1);
}

// EWB: incoming gradient is the broadcast energy vector ew[col] (topmost layer)
template <int EWB>
__global__ __launch_bounds__(256) void k_rms_bwd(const float* __restrict__ X,
                                                 const float* __restrict__ GY,
                                                 const float* __restrict__ EW,
                                                 float* __restrict__ GX,
                                                 unsigned short* __restrict__ GX16) {
  int t = blockIdx.x, tid = threadIdx.x;
  float x0 = X[(size_t)t * H_ + tid], x1 = X[(size_t)t * H_ + tid + 256];
  float g0, g1;
  if (EWB) {
    g0 = EW[tid];
    g1 = EW[tid + 256];
  } else {
    g0 = GY[(size_t)t * H_ + tid];
    g1 = GY[(size_t)t * H_ + tid + 256];
  }
  __shared__ float r1[256], r2[256];
  r1[tid] = x0 * x0 + x1 * x1;
  r2[tid] = x0 * g0 + x1 * g1;
  __syncthreads();
  for (int s = 128; s > 0; s >>= 1) {
    if (tid < s) { r1[tid] += r1[tid + s]; r2[tid] += r2[tid + s]; }
    __syncthreads();
  }
  float r = rsqrtf(r1[0] / H_ + EPS_);
  float coef = r * r * r * r2[0] / (float)H_;
  float o0 = r * g0 - coef * x0, o1 = r * g1 - coef * x1;
  GX[(size_t)t * H_ + tid] = o0;
  GX[(size_t)t * H_ + tid + 256] = o1;
  GX16[(size_t)t * H_ + tid] = f2bf(o0);
  GX16[(size_t)t * H_ + tid + 256] = f2bf(o1);
}

// ---------------- logits update ----------------

__global__ __launch_bounds__(64) void k_logits_update(const float* __restrict__ G,
                                                      const float* __restrict__ E,
                                                      const float* __restrict__ P,
                                                      const float* __restrict__ alpha,
                                                      float* __restrict__ logits) {
  int t = blockIdx.x, lane = threadIdx.x;
  float dp[V_];
#pragma unroll
  for (int v = 0; v < V_; ++v) dp[v] = 0.f;
  for (int hh = lane; hh < H_; hh += 64) {
    float gh = G[(size_t)t * H_ + hh];
#pragma unroll
    for (int v = 0; v < V_; ++v) dp[v] += gh * E[v * H_ + hh];
  }
#pragma unroll
  for (int v = 0; v < V_; ++v) dp[v] = wave_sum64(dp[v]) * ESCALE_;
  float dot = 0.f;
  float pv[V_];
#pragma unroll
  for (int v = 0; v < V_; ++v) {
    pv[v] = P[t * V_ + v];
    dot += pv[v] * dp[v];
  }
  float a = fmaxf(alpha[0], 1e-4f);
  if (lane < V_) logits[t * V_ + lane] -= a * pv[lane] * (dp[lane] - dot);
}

// ---------------- host-side orchestration ----------------

struct Ctx {
  unsigned short *Q16, *Q016, *dQ16, *GU16, *DO16, *AO16, *AO016, *X116, *UDX16, *U016;
  float *X1, *X2, *X20, *G, *UDX, *P, *MB, *LB, *DB, *MB0, *LB0, *CS, *SN;
  const float* EW;
  const unsigned short *WTqkv[2], *WTo[2], *WTgu[2], *WTd[2];
  const unsigned short *WSqkv[2], *WSo[2], *WSgu[2], *WSd[2];
  hipStream_t st;
};

static void block_forward(Ctx& c, int l, const float* hin, const unsigned short* hin16,
                          float* hout, unsigned short* qb, unsigned short* ao,
                          float* mb, float* lb, float* x2buf, unsigned short* u16buf) {
  k_gemm<128, 0, 0, 1, 1, 0><<<dim3(3 * H_ / 128, (NTOK + 127) / 128), 256, 0, c.st>>>(
      hin16, c.WTqkv[l], nullptr, nullptr, qb, nullptr, c.CS, c.SN, NTOK, 3 * H_, H_, H_);
  k_attn_fwd3<<<dim3((S_ + 127) / 128, NH_, B_), 512, 0, c.st>>>(qb, ao, mb, lb);
  k_gemm<64, 0, 1, 0, 0, 0><<<dim3(H_ / 128, (NTOK + 63) / 64), 256, 0, c.st>>>(
      ao, c.WTo[l], hin, c.X1, nullptr, nullptr, nullptr, nullptr, NTOK, H_, H_, H_);
  k_rms_fwd<<<NTOK, 256, 0, c.st>>>(c.X1, c.UDX, u16buf);
  k_gemm<128, 0, 0, 1, 0, 0><<<dim3(2 * INNER_ / 128, (NTOK + 127) / 128), 256, 0, c.st>>>(
      u16buf, c.WTgu[l], nullptr, nullptr, c.GU16, nullptr, nullptr, nullptr, NTOK, 2 * INNER_, H_, H_);
  k_gemm<64, 1, 1, 0, 0, 0><<<dim3(H_ / 128, (NTOK + 63) / 64), 256, 0, c.st>>>(
      c.GU16, c.WTd[l], c.UDX, x2buf, nullptr, nullptr, nullptr, nullptr, NTOK, H_, INNER_, 2 * INNER_);
  if (hout) k_rms_fwd<<<NTOK, 256, 0, c.st>>>(x2buf, hout, c.UDX16);
}

static void block_backward(Ctx& c, int l, const float* hin, const unsigned short* hin16,
                           unsigned short* qb, unsigned short* ao, float* mb, float* lb,
                           bool full) {
  const float* x2src;
  if (full) {
    block_forward(c, l, hin, hin16, nullptr, qb, ao, mb, lb, c.X2, c.UDX16);
    x2src = c.X2;
  } else {
    k_gemm<64, 0, 1, 0, 0, 0><<<dim3(H_ / 128, (NTOK + 63) / 64), 256, 0, c.st>>>(
        ao, c.WTo[l], hin, c.X1, nullptr, nullptr, nullptr, nullptr, NTOK, H_, H_, H_);
    k_gemm<128, 0, 0, 1, 0, 0><<<dim3(2 * INNER_ / 128, (NTOK + 127) / 128), 256, 0, c.st>>>(
        c.U016, c.WTgu[l], nullptr, nullptr, c.GU16, nullptr, nullptr, nullptr, NTOK, 2 * INNER_, H_, H_);
    x2src = c.X20;
  }
  if (full)
    k_rms_bwd<1><<<NTOK, 256, 0, c.st>>>(x2src, nullptr, c.EW, c.UDX, c.UDX16);
  else
    k_rms_bwd<0><<<NTOK, 256, 0, c.st>>>(x2src, c.G, nullptr, c.UDX, c.UDX16);
  k_gemm<128, 0, 0, 0, 0, 1><<<dim3(INNER_ / 128, (NTOK + 127) / 128), 256, 0, c.st>>>(
      c.UDX16, c.WSd[l], nullptr, nullptr, nullptr, c.GU16, nullptr, nullptr, NTOK, INNER_, H_, H_);
  k_gemm<64, 0, 1, 0, 0, 0><<<dim3(H_ / 128, (NTOK + 63) / 64), 256, 0, c.st>>>(
      c.GU16, c.WSgu[l], c.UDX, c.G, nullptr, nullptr, nullptr, nullptr, NTOK, H_, 2 * INNER_, 2 * INNER_);
  k_rms_bwd<0><<<NTOK, 256, 0, c.st>>>(c.X1, c.G, nullptr, c.UDX, c.UDX16);
  k_gemm<64, 0, 0, 1, 0, 0><<<dim3(H_ / 128, (NTOK + 63) / 64), 256, 0, c.st>>>(
      c.UDX16, c.WSo[l], nullptr, nullptr, c.DO16, nullptr, nullptr, nullptr, NTOK, H_, H_, H_);
  dim3 agrid128((S_ + 127) / 128, NH_, B_);
  k_attn_bwd_dq3<<<agrid128, 512, 0, c.st>>>(qb, ao, c.DO16, mb, lb, c.DB, c.CS, c.SN, c.dQ16);
  k_attn_bwd_kv3<<<agrid128, 512, 0, c.st>>>(qb, c.DO16, mb, lb, c.DB, c.CS, c.SN, c.dQ16);
  k_gemm<64, 0, 1, 0, 0, 0><<<dim3(H_ / 128, (NTOK + 63) / 64), 256, 0, c.st>>>(
      c.dQ16, c.WSqkv[l], c.UDX, c.G, nullptr, nullptr, nullptr, nullptr, NTOK, H_, 3 * H_, 3 * H_);
}

extern "C" void kernel_launch(void* const* d_in, const int* in_sizes, int n_in,
                              void* d_out, int out_size, void* d_ws, size_t ws_size,
                              hipStream_t stream) {
  const int* inputs = (const int*)d_in[0];
  const float* E = (const float*)d_in[2];
  const float* ew = (const float*)d_in[3];
  const float* qkvw = (const float*)d_in[4];
  const float* ow = (const float*)d_in[5];
  const float* guw = (const float*)d_in[6];
  const float* dw = (const float*)d_in[7];
  const float* alpha = (const float*)d_in[8];
  float* logits = (float*)d_out;

  const size_t WT_FLOATS = 3407872;
  const size_t NEED =
      3 * ((size_t)NTOK * 3 * H_ / 2) +
      ((size_t)NTOK * INNER_) +
      5 * ((size_t)NTOK * H_) +
      6 * ((size_t)NTOK * H_ / 2) +
      ((size_t)NTOK * V_) +
      5 * ((size_t)B_ * NH_ * S_) +
      2 * ((size_t)S_ * 32) +
      2 * WT_FLOATS;
  if (ws_size < NEED * sizeof(float)) {
    k_zero<<<(NTOK * V_ + 255) / 256, 256, 0, stream>>>(logits, NTOK * V_);
    return;
  }

  float* f = (float*)d_ws;
  Ctx c;
  c.st = stream;
  c.EW = ew;
  c.Q16 = (unsigned short*)f;  f += (size_t)NTOK * 3 * H_ / 2;
  c.Q016 = (unsigned short*)f; f += (size_t)NTOK * 3 * H_ / 2;
  c.dQ16 = (unsigned short*)f; f += (size_t)NTOK * 3 * H_ / 2;
  c.GU16 = (unsigned short*)f; f += (size_t)NTOK * INNER_;
  c.X1 = f;   f += (size_t)NTOK * H_;
  c.X2 = f;   f += (size_t)NTOK * H_;
  c.X20 = f;  f += (size_t)NTOK * H_;
  c.G = f;    f += (size_t)NTOK * H_;
  c.UDX = f;  f += (size_t)NTOK * H_;
  c.AO16 = (unsigned short*)f;  f += (size_t)NTOK * H_ / 2;
  c.AO016 = (unsigned short*)f; f += (size_t)NTOK * H_ / 2;
  c.DO16 = (unsigned short*)f;  f += (size_t)NTOK * H_ / 2;
  c.X116 = (unsigned short*)f;  f += (size_t)NTOK * H_ / 2;
  c.UDX16 = (unsigned short*)f; f += (size_t)NTOK * H_ / 2;
  c.U016 = (unsigned short*)f;  f += (size_t)NTOK * H_ / 2;
  c.P = f;    f += (size_t)NTOK * V_;
  c.MB = f;   f += (size_t)B_ * NH_ * S_;
  c.LB = f;   f += (size_t)B_ * NH_ * S_;
  c.DB = f;   f += (size_t)B_ * NH_ * S_;
  c.MB0 = f;  f += (size_t)B_ * NH_ * S_;
  c.LB0 = f;  f += (size_t)B_ * NH_ * S_;
  c.CS = f;   f += (size_t)S_ * 32;
  c.SN = f;   f += (size_t)S_ * 32;
  unsigned short* wt = (unsigned short*)f;

  const size_t LQKV = (size_t)H_ * 3 * H_;
  const size_t LO = (size_t)H_ * H_;
  const size_t LGU = (size_t)H_ * 2 * INNER_;
  const size_t LD = (size_t)INNER_ * H_;

  for (int l = 0; l < 2; ++l) {
    c.WTqkv[l] = wt;
    k_wt<<<dim3(3 * H_ / 32, H_ / 32), dim3(32, 8), 0, stream>>>(qkvw + l * LQKV, wt, H_, 3 * H_);
    wt += LQKV;
    c.WTo[l] = wt;
    k_wt<<<dim3(H_ / 32, H_ / 32), dim3(32, 8), 0, stream>>>(ow + l * LO, wt, H_, H_);
    wt += LO;
    c.WTgu[l] = wt;
    k_wt<<<dim3(2 * INNER_ / 32, H_ / 32), dim3(32, 8), 0, stream>>>(guw + l * LGU, wt, H_, 2 * INNER_);
    wt += LGU;
    c.WTd[l] = wt;
    k_wt<<<dim3(H_ / 32, INNER_ / 32), dim3(32, 8), 0, stream>>>(dw + l * LD, wt, INNER_, H_);
    wt += LD;
  }
  {
    unsigned short* ws = wt;
    k_cast8<<<(int)((2 * LQKV / 8 + 255) / 256), 256, 0, stream>>>(qkvw, ws, (int)(2 * LQKV / 8));
    c.WSqkv[0] = ws; c.WSqkv[1] = ws + LQKV; ws += 2 * LQKV;
    k_cast8<<<(int)((2 * LO / 8 + 255) / 256), 256, 0, stream>>>(ow, ws, (int)(2 * LO / 8));
    c.WSo[0] = ws; c.WSo[1] = ws + LO; ws += 2 * LO;
    k_cast8<<<(int)((2 * LGU / 8 + 255) / 256), 256, 0, stream>>>(guw, ws, (int)(2 * LGU / 8));
    c.WSgu[0] = ws; c.WSgu[1] = ws + LGU; ws += 2 * LGU;
    k_cast8<<<(int)((2 * LD / 8 + 255) / 256), 256, 0, stream>>>(dw, ws, (int)(2 * LD / 8));
    c.WSd[0] = ws; c.WSd[1] = ws + LD;
  }

  k_zero<<<(NTOK * V_ + 255) / 256, 256, 0, stream>>>(logits, NTOK * V_);
  k_rope_tables<<<(S_ * 32 + 255) / 256, 256, 0, stream>>>(c.CS, c.SN);

  for (int step = 0; step < STEPS_; ++step) {
    k_h0<1><<<NTOK, 256, 0, stream>>>(logits, c.P, E, inputs, c.X1, c.X116);
    block_forward(c, 0, c.X1, c.X116, c.UDX, c.Q016, c.AO016, c.MB0, c.LB0, c.X20, c.U016);
    block_backward(c, 1, c.UDX, c.UDX16, c.Q16, c.AO16, c.MB, c.LB, true);
    k_h0<0><<<NTOK, 256, 0, stream>>>(nullptr, c.P, E, inputs, c.X1, c.X116);
    block_backward(c, 0, c.X1, c.X116, c.Q016, c.AO016, c.MB0, c.LB0, false);
    k_logits_update<<<NTOK, 64, 0, stream>>>(c.G, E, c.P, alpha, logits);
  }
}

// Round 18
// 2225.942 us; speedup vs baseline: 2.9352x; 1.0094x over previous
//
#include <hip/hip_runtime.h>
#include <math.h>

#define B_ 8
#define S_ 900
#define V_ 11
#define H_ 512
#define NH_ 8
#define HD_ 64
#define INNER_ 1536
#define STEPS_ 2
#define NTOK (B_*S_)
#define EPS_ 1e-5f
#define THETA_ 10000.0f
#define ESCALE_ 22.627416997969522f
#define SCALE_ 0.125f
#define PT_ 68   // attention LDS pitch (ushorts): 136B rows, 8B-aligned (b64 floor pattern)

typedef __attribute__((ext_vector_type(8))) short bh8;
typedef __attribute__((ext_vector_type(4))) float f32x4;
typedef __attribute__((ext_vector_type(4))) unsigned short us4;

union bfu { bh8 v; unsigned short s[8]; us4 q[2]; };

__device__ inline unsigned short f2bf(float x) {
  unsigned u = __builtin_bit_cast(unsigned, x);
  return (unsigned short)((u + 0x7FFFu + ((u >> 16) & 1u)) >> 16);
}
__device__ inline float b2f(unsigned short s) {
  return __builtin_bit_cast(float, (unsigned)s << 16);
}

// async global->LDS, 16B per lane; LDS dest = wave-uniform base + lane*16
__device__ inline void gld16(const unsigned short* g, unsigned short* l) {
  __builtin_amdgcn_global_load_lds(
      (const __attribute__((address_space(1))) void*)(g),
      (__attribute__((address_space(3))) void*)(l), 16, 0, 0);
}

__device__ inline bh8 lds16(const unsigned short* p) {
  bfu u;
  u.q[0] = *(const us4*)p;
  u.q[1] = *(const us4*)(p + 4);
  return u.v;
}
__device__ inline void sts16(unsigned short* p, bfu u) {
  *(us4*)p = u.q[0];
  *(us4*)(p + 4) = u.q[1];
}

__device__ inline float wave_sum64(float x) {
#pragma unroll
  for (int off = 32; off > 0; off >>= 1) x += __shfl_xor(x, off, 64);
  return x;
}

// ---------------- small kernels ----------------

__global__ void k_zero(float* p, int n) {
  int i = blockIdx.x * blockDim.x + threadIdx.x;
  if (i < n) p[i] = 0.f;
}

__global__ void k_rope_tables(float* cs, float* sn) {
  int idx = blockIdx.x * blockDim.x + threadIdx.x;
  if (idx >= S_ * 32) return;
  int s = idx >> 5, i = idx & 31;
  float freq = powf(THETA_, -(float)i / 32.0f);
  float ang = (float)s * freq;
  cs[idx] = cosf(ang);
  sn[idx] = sinf(ang);
}

// h0 -> fp32 + bf16; DOSM: compute P from logits in-block (and store P)
template <int DOSM>
__global__ void k_h0(const float* __restrict__ logits, float* __restrict__ P,
                     const float* __restrict__ E,
                     const int* __restrict__ inp, float* __restrict__ h0,
                     unsigned short* __restrict__ h016) {
  int t = blockIdx.x;
  int tid = threadIdx.x;
  __shared__ float p[V_];
  __shared__ int iw;
  if (DOSM) {
    if (tid == 0) {
      float x[V_];
      float m = -1e30f;
#pragma unroll
      for (int v = 0; v < V_; ++v) { x[v] = logits[t * V_ + v]; m = fmaxf(m, x[v]); }
      float ssum = 0.f;
#pragma unroll
      for (int v = 0; v < V_; ++v) { x[v] = __expf(x[v] - m); ssum += x[v]; }
      float inv = 1.f / ssum;
#pragma unroll
      for (int v = 0; v < V_; ++v) {
        float pv = x[v] * inv;
        p[v] = pv;
        P[t * V_ + v] = pv;
      }
    }
  } else {
    if (tid < V_) p[tid] = P[t * V_ + tid];
  }
  if (tid == 0) iw = inp[t];
  __syncthreads();
  for (int h = tid; h < H_; h += blockDim.x) {
    float acc = E[iw * H_ + h];
#pragma unroll
    for (int v = 0; v < V_; ++v) acc += p[v] * E[v * H_ + h];
    float val = ESCALE_ * acc;
    h0[(size_t)t * H_ + h] = val;
    h016[(size_t)t * H_ + h] = f2bf(val);
  }
}

// fp32 -> bf16 cast, 8 elems/thread
__global__ void k_cast8(const float* __restrict__ X, unsigned short* __restrict__ Y, int n8) {
  int i = blockIdx.x * blockDim.x + threadIdx.x;
  if (i >= n8) return;
  const float4* p = (const float4*)(X + (size_t)i * 8);
  float4 a = p[0], b = p[1];
  bfu o;
  o.s[0] = f2bf(a.x); o.s[1] = f2bf(a.y); o.s[2] = f2bf(a.z); o.s[3] = f2bf(a.w);
  o.s[4] = f2bf(b.x); o.s[5] = f2bf(b.y); o.s[6] = f2bf(b.z); o.s[7] = f2bf(b.w);
  *(bh8*)(Y + (size_t)i * 8) = o.v;
}

// ---------------- weight transpose-convert: W[K][N] fp32 -> WT[N][K] bf16 ----------------

__global__ void k_wt(const float* __restrict__ W, unsigned short* __restrict__ WT, int K, int N) {
  __shared__ float t[32][33];
  int k0 = blockIdx.y * 32, n0 = blockIdx.x * 32;
  int tx = threadIdx.x, ty = threadIdx.y;
#pragma unroll
  for (int i = 0; i < 4; ++i)
    t[ty + 8 * i][tx] = W[(size_t)(k0 + ty + 8 * i) * N + n0 + tx];
  __syncthreads();
#pragma unroll
  for (int i = 0; i < 4; ++i)
    WT[(size_t)(n0 + ty + 8 * i) * K + k0 + tx] = f2bf(t[tx][ty + 8 * i]);
}

// ---------------- MFMA GEMM: C[M,N] = A[M,K] @ B^T (A,B bf16; B stored [N][K]) ----------------
// Stage-ahead double-buffer at BK=32.

template <int TM, int SILU_A, int ADD, int CBF, int ROPE, int SILUBWD>
__global__ __launch_bounds__(256) void k_gemm(const unsigned short* __restrict__ A16,
                                              const unsigned short* __restrict__ Bt,
                                              const float* __restrict__ Dm,
                                              float* __restrict__ Cf,
                                              unsigned short* __restrict__ C16,
                                              unsigned short* __restrict__ GU,
                                              const float* __restrict__ Cs,
                                              const float* __restrict__ Sn,
                                              int M, int N, int K, int lda) {
  __shared__ unsigned short As[2][TM][32];
  __shared__ unsigned short Bs[2][128][32];
  constexpr int FR = TM / 32;
  int tid = threadIdx.x;
  int m0 = blockIdx.y * TM, n0 = blockIdx.x * 128;
  int wid = tid >> 6, lane = tid & 63;
  int wr = (wid >> 1) * (FR * 16), wc = (wid & 1) * 64;
  int lr = lane & 15, lg = lane >> 4;
  int srow = lane >> 2, sck = (lane & 3) * 8;
  f32x4 acc[FR][4] = {};

  auto stage = [&](int buf, int kk) {
#pragma unroll
    for (int half = 0; half < TM / 64; ++half) {
      if (SILU_A) {
        int row = (tid >> 2) + 64 * half;
        int ck = (tid & 3) * 8;
        int gr = m0 + row; gr = gr < M ? gr : M - 1;
        const unsigned short* src = &A16[(size_t)gr * lda + kk + ck];
        bfu pa;
#pragma unroll
        for (int j = 0; j < 8; ++j) {
          float g = b2f(src[j]), u = b2f(src[INNER_ + j]);
          pa.s[j] = f2bf((g / (1.f + __expf(-g))) * u);
        }
        *(bh8*)&As[buf][row][ck] = pa.v;
      } else {
        int gr = m0 + 64 * half + wid * 16 + srow; gr = gr < M ? gr : M - 1;
        gld16(&A16[(size_t)gr * lda + kk + sck], &As[buf][64 * half + wid * 16][0]);
      }
    }
#pragma unroll
    for (int i = 0; i < 2; ++i) {
      int bb = wid * 2 + i;
      gld16(&Bt[(size_t)(n0 + bb * 16 + srow) * K + kk + sck], &Bs[buf][bb * 16][0]);
    }
  };

  stage(0, 0);
  __syncthreads();
  int nk = K >> 5;
  for (int t = 0; t < nk; ++t) {
    int cur = t & 1;
    if (t + 1 < nk) stage(cur ^ 1, (t + 1) << 5);
    bh8 av[FR], bv[4];
#pragma unroll
    for (int fr = 0; fr < FR; ++fr) av[fr] = *(const bh8*)&As[cur][wr + fr * 16 + lr][lg * 8];
#pragma unroll
    for (int fc = 0; fc < 4; ++fc) bv[fc] = *(const bh8*)&Bs[cur][wc + fc * 16 + lr][lg * 8];
#pragma unroll
    for (int fr = 0; fr < FR; ++fr)
#pragma unroll
      for (int fc = 0; fc < 4; ++fc)
        acc[fr][fc] = __builtin_amdgcn_mfma_f32_16x16x32_bf16(av[fr], bv[fc], acc[fr][fc], 0, 0, 0);
    __syncthreads();
  }
  bool rope_on = ROPE && (((n0 + wc) >> 6) < 16);
#pragma unroll
  for (int fr = 0; fr < FR; ++fr) {
    int r0 = m0 + wr + fr * 16 + lg * 4;
#pragma unroll
    for (int i = 0; i < 4; ++i) {
      int gr = r0 + i;
      if (gr >= M) continue;
      float c0 = 1.f, s0 = 0.f, c1 = 1.f, s1 = 0.f;
      if (ROPE) {
        if (rope_on) {
          int s = gr % S_;
          c0 = Cs[s * 32 + lr];      s0 = Sn[s * 32 + lr];
          c1 = Cs[s * 32 + 16 + lr]; s1 = Sn[s * 32 + 16 + lr];
        }
      }
#pragma unroll
      for (int fc = 0; fc < 4; ++fc) {
        int gc = n0 + wc + fc * 16 + lr;
        float out = acc[fr][fc][i];
        if (ROPE) {
          float part = acc[fr][fc ^ 2][i];
          float cc = (fc & 1) ? c1 : c0;
          float ss = (fc & 1) ? s1 : s0;
          out = (fc < 2) ? (out * cc - part * ss) : (out * cc + part * ss);
        }
        if (ADD) out += Dm[(size_t)gr * N + gc];
        if (SILUBWD) {
          size_t gb = (size_t)gr * (size_t)(2 * INNER_) + gc;
          float g = b2f(GU[gb]), u = b2f(GU[gb + INNER_]);
          float sig = 1.f / (1.f + __expf(-g));
          GU[gb] = f2bf(out * u * sig * (1.f + g * (1.f - sig)));
          GU[gb + INNER_] = f2bf(out * g * sig);
        } else if (CBF) {
          C16[(size_t)gr * N + gc] = f2bf(out);
        } else {
          Cf[(size_t)gr * N + gc] = out;
        }
      }
    }
  }
}

// ---------------- MFMA flash attention, QBLK=128 (8 waves), role-split staging ----------------
// T5: s_setprio(1) around MFMA clusters (role-split + 2 blocks/CU give phase diversity).

__global__ __launch_bounds__(512) void k_attn_fwd3(const unsigned short* __restrict__ QKV,
                                                   unsigned short* __restrict__ AO,
                                                   float* __restrict__ MB,
                                                   float* __restrict__ LB) {
  __shared__ unsigned short Ks[64][PT_];
  __shared__ unsigned short VT[64][PT_];
  __shared__ unsigned short Ps[8][16][PT_];
  int tid = threadIdx.x;
  int h = blockIdx.y, b = blockIdx.z;
  int w = tid >> 6, lane = tid & 63;
  int lr = lane & 15, lg = lane >> 4;
  int q0 = blockIdx.x * 128 + w * 16;
  bool kRole = tid < 256;
  int t2 = kRole ? tid : tid - 256;
  int sr = t2 >> 2, sc0 = (t2 & 3) * 16;
  int vd0 = (t2 & 15) * 4, vk0 = (t2 >> 4) * 4;

  bh8 qf[2];
  {
    int qr = q0 + lr; if (qr >= S_) qr = S_ - 1;
    const unsigned short* qp = &QKV[((size_t)(b * S_ + qr) * 24 + h) * 64 + lg * 8];
    qf[0] = *(const bh8*)qp;
    qf[1] = *(const bh8*)(qp + 32);
  }
  f32x4 accO[4] = {};
  float m[4], lsum[4];
#pragma unroll
  for (int i = 0; i < 4; ++i) { m[i] = -1e30f; lsum[i] = 0.f; }

  bfu kA, kB;
  us4 vR[4];
  if (kRole) {
    int src = sr;
    size_t ts = (size_t)b * S_ + (src < S_ ? src : S_ - 1);
    const unsigned short* gp = &QKV[(ts * 24 + 8 + h) * 64 + sc0];
    kA.v = *(const bh8*)gp;
    kB.v = *(const bh8*)(gp + 8);
  } else {
#pragma unroll
    for (int j = 0; j < 4; ++j) {
      int s2 = vk0 + j;
      size_t t3 = (size_t)b * S_ + (s2 < S_ ? s2 : S_ - 1);
      vR[j] = *(const us4*)&QKV[(t3 * 24 + 16 + h) * 64 + vd0];
    }
  }

  for (int kt = 0; kt < S_; kt += 64) {
    __syncthreads();
    if (kRole) {
      sts16(&Ks[sr][sc0], kA);
      sts16(&Ks[sr][sc0 + 8], kB);
    } else {
#pragma unroll
      for (int dd = 0; dd < 4; ++dd) {
        us4 pk = {vR[0][dd], vR[1][dd], vR[2][dd], vR[3][dd]};
        *(us4*)&VT[vd0 + dd][vk0] = pk;
      }
    }
    __syncthreads();
    if (kt + 64 < S_) {
      if (kRole) {
        int src = kt + 64 + sr;
        size_t ts = (size_t)b * S_ + (src < S_ ? src : S_ - 1);
        const unsigned short* gp = &QKV[(ts * 24 + 8 + h) * 64 + sc0];
        kA.v = *(const bh8*)gp;
        kB.v = *(const bh8*)(gp + 8);
      } else {
#pragma unroll
        for (int j = 0; j < 4; ++j) {
          int s2 = kt + 64 + vk0 + j;
          size_t t3 = (size_t)b * S_ + (s2 < S_ ? s2 : S_ - 1);
          vR[j] = *(const us4*)&QKV[(t3 * 24 + 16 + h) * 64 + vd0];
        }
      }
    }
    f32x4 accS[4] = {};
    __builtin_amdgcn_s_setprio(1);
#pragma unroll
    for (int ks = 0; ks < 2; ++ks)
#pragma unroll
      for (int fk = 0; fk < 4; ++fk)
        accS[fk] = __builtin_amdgcn_mfma_f32_16x16x32_bf16(qf[ks], lds16(&Ks[fk * 16 + lr][ks * 32 + lg * 8]), accS[fk], 0, 0, 0);
    __builtin_amdgcn_s_setprio(0);
    float sc[4][4], pmax[4];
#pragma unroll
    for (int i = 0; i < 4; ++i) pmax[i] = -1e30f;
#pragma unroll
    for (int fk = 0; fk < 4; ++fk)
#pragma unroll
      for (int i = 0; i < 4; ++i) {
        float s = accS[fk][i] * SCALE_;
        if (kt + fk * 16 + lr >= S_) s = -1e30f;
        sc[fk][i] = s;
        pmax[i] = fmaxf(pmax[i], s);
      }
#pragma unroll
    for (int i = 0; i < 4; ++i) {
      float v = pmax[i];
      v = fmaxf(v, __shfl_xor(v, 1, 64));
      v = fmaxf(v, __shfl_xor(v, 2, 64));
      v = fmaxf(v, __shfl_xor(v, 4, 64));
      v = fmaxf(v, __shfl_xor(v, 8, 64));
      pmax[i] = v;
    }
    float psum[4];
#pragma unroll
    for (int i = 0; i < 4; ++i) {
      float mn = fmaxf(m[i], pmax[i]);
      float eo = __expf(m[i] - mn);
      m[i] = mn;
      lsum[i] *= eo;
#pragma unroll
      for (int fd = 0; fd < 4; ++fd) accO[fd][i] *= eo;
      psum[i] = 0.f;
    }
#pragma unroll
    for (int fk = 0; fk < 4; ++fk)
#pragma unroll
      for (int i = 0; i < 4; ++i) {
        float p = __expf(sc[fk][i] - m[i]);
        sc[fk][i] = p;
        psum[i] += p;
      }
#pragma unroll
    for (int i = 0; i < 4; ++i) {
      float v = psum[i];
      v += __shfl_xor(v, 1, 64);
      v += __shfl_xor(v, 2, 64);
      v += __shfl_xor(v, 4, 64);
      v += __shfl_xor(v, 8, 64);
      lsum[i] += v;
    }
#pragma unroll
    for (int fk = 0; fk < 4; ++fk)
#pragma unroll
      for (int i = 0; i < 4; ++i)
        Ps[w][lg * 4 + i][fk * 16 + lr] = f2bf(sc[fk][i]);
    __builtin_amdgcn_s_setprio(1);
#pragma unroll
    for (int ks = 0; ks < 2; ++ks) {
      bh8 ap = lds16(&Ps[w][lr][ks * 32 + lg * 8]);
#pragma unroll
      for (int fd = 0; fd < 4; ++fd)
        accO[fd] = __builtin_amdgcn_mfma_f32_16x16x32_bf16(ap, lds16(&VT[fd * 16 + lr][ks * 32 + lg * 8]), accO[fd], 0, 0, 0);
    }
    __builtin_amdgcn_s_setprio(0);
  }
#pragma unroll
  for (int i = 0; i < 4; ++i) {
    int q = q0 + lg * 4 + i;
    if (q < S_) {
      float linv = 1.f / lsum[i];
      size_t obase = (size_t)(b * S_ + q) * H_ + h * 64;
#pragma unroll
      for (int fd = 0; fd < 4; ++fd) AO[obase + fd * 16 + lr] = f2bf(accO[fd][i] * linv);
      if (lr == 0) {
        MB[((size_t)b * NH_ + h) * S_ + q] = m[i];
        LB[((size_t)b * NH_ + h) * S_ + q] = linv;
      }
    }
  }
}

// dQ pass, QBLK=128; fused delta (writes DB for kv3) + inverse-RoPE on output
__global__ __launch_bounds__(512) void k_attn_bwd_dq3(const unsigned short* __restrict__ QKV,
                                                      const unsigned short* __restrict__ O16,
                                                      const unsigned short* __restrict__ dO,
                                                      const float* __restrict__ MB,
                                                      const float* __restrict__ LB,
                                                      float* __restrict__ DB,
                                                      const float* __restrict__ Cs,
                                                      const float* __restrict__ Sn,
                                                      unsigned short* __restrict__ dQKV) {
  __shared__ unsigned short Ks[64][PT_];
  __shared__ unsigned short Vs[64][PT_];
  __shared__ unsigned short KT[64][PT_];
  __shared__ unsigned short Ps[8][16][PT_];
  int tid = threadIdx.x;
  int h = blockIdx.y, b = blockIdx.z;
  int w = tid >> 6, lane = tid & 63;
  int lr = lane & 15, lg = lane >> 4;
  int q0 = blockIdx.x * 128 + w * 16;
  size_t sbase = ((size_t)b * NH_ + h) * S_;
  bool kRole = tid < 256;
  int t2 = kRole ? tid : tid - 256;
  int sr = t2 >> 2, sc0 = (t2 & 3) * 16;
  int vd0 = (t2 & 15) * 4, vk0 = (t2 >> 4) * 4;

  bh8 qf[2], dof[2];
  float pd = 0.f;
  {
    int qr = q0 + lr; if (qr >= S_) qr = S_ - 1;
    const unsigned short* qp = &QKV[((size_t)(b * S_ + qr) * 24 + h) * 64 + lg * 8];
    const unsigned short* dp = &dO[(size_t)(b * S_ + qr) * H_ + h * 64 + lg * 8];
    const unsigned short* op = &O16[(size_t)(b * S_ + qr) * H_ + h * 64 + lg * 8];
    qf[0] = *(const bh8*)qp;  qf[1] = *(const bh8*)(qp + 32);
    dof[0] = *(const bh8*)dp; dof[1] = *(const bh8*)(dp + 32);
    bfu o0, o1, d0, d1;
    o0.v = *(const bh8*)op; o1.v = *(const bh8*)(op + 32);
    d0.v = dof[0]; d1.v = dof[1];
#pragma unroll
    for (int j = 0; j < 8; ++j)
      pd += b2f(o0.s[j]) * b2f(d0.s[j]) + b2f(o1.s[j]) * b2f(d1.s[j]);
    pd += __shfl_xor(pd, 16, 64);
    pd += __shfl_xor(pd, 32, 64);
    if (lg == 0 && q0 + lr < S_) DB[sbase + q0 + lr] = pd;
  }
  float mrow[4], lrow[4], drow[4];
#pragma unroll
  for (int i = 0; i < 4; ++i) {
    int q = q0 + lg * 4 + i; if (q >= S_) q = S_ - 1;
    mrow[i] = MB[sbase + q];
    lrow[i] = LB[sbase + q];
    drow[i] = __shfl(pd, lg * 4 + i, 64);
  }
  f32x4 accQ[4] = {};

  bfu pA{}, pB{}, pC{}, pD{};
  us4 rv[4];
  if (kRole) {
    int src = sr;
    bool vld = src < S_;
    size_t ts = (size_t)b * S_ + (vld ? src : S_ - 1);
    const unsigned short* kp = &QKV[(ts * 24 + 8 + h) * 64 + sc0];
    if (vld) {
      pA.v = *(const bh8*)kp;
      pB.v = *(const bh8*)(kp + 8);
      pC.v = *(const bh8*)(kp + 512);
      pD.v = *(const bh8*)(kp + 520);
    }
  } else {
#pragma unroll
    for (int j = 0; j < 4; ++j) {
      int s2 = vk0 + j;
      bool v2 = s2 < S_;
      size_t t3 = (size_t)b * S_ + (v2 ? s2 : S_ - 1);
      us4 t = *(const us4*)&QKV[(t3 * 24 + 8 + h) * 64 + vd0];
      if (!v2) t = us4{0, 0, 0, 0};
      rv[j] = t;
    }
  }

  for (int kt = 0; kt < S_; kt += 64) {
    __syncthreads();
    if (kRole) {
      sts16(&Ks[sr][sc0], pA); sts16(&Ks[sr][sc0 + 8], pB);
      sts16(&Vs[sr][sc0], pC); sts16(&Vs[sr][sc0 + 8], pD);
    } else {
#pragma unroll
      for (int dd = 0; dd < 4; ++dd) {
        us4 pk = {rv[0][dd], rv[1][dd], rv[2][dd], rv[3][dd]};
        *(us4*)&KT[vd0 + dd][vk0] = pk;
      }
    }
    __syncthreads();
    if (kt + 64 < S_) {
      if (kRole) {
        int src = kt + 64 + sr;
        bool vld = src < S_;
        size_t ts = (size_t)b * S_ + (vld ? src : S_ - 1);
        const unsigned short* kp = &QKV[(ts * 24 + 8 + h) * 64 + sc0];
        pA = bfu{}; pB = bfu{}; pC = bfu{}; pD = bfu{};
        if (vld) {
          pA.v = *(const bh8*)kp;
          pB.v = *(const bh8*)(kp + 8);
          pC.v = *(const bh8*)(kp + 512);
          pD.v = *(const bh8*)(kp + 520);
        }
      } else {
#pragma unroll
        for (int j = 0; j < 4; ++j) {
          int s2 = kt + 64 + vk0 + j;
          bool v2 = s2 < S_;
          size_t t3 = (size_t)b * S_ + (v2 ? s2 : S_ - 1);
          us4 t = *(const us4*)&QKV[(t3 * 24 + 8 + h) * 64 + vd0];
          if (!v2) t = us4{0, 0, 0, 0};
          rv[j] = t;
        }
      }
    }
    f32x4 aS[4] = {}, aD[4] = {};
    __builtin_amdgcn_s_setprio(1);
#pragma unroll
    for (int ks = 0; ks < 2; ++ks)
#pragma unroll
      for (int fk = 0; fk < 4; ++fk) {
        aS[fk] = __builtin_amdgcn_mfma_f32_16x16x32_bf16(qf[ks], lds16(&Ks[fk * 16 + lr][ks * 32 + lg * 8]), aS[fk], 0, 0, 0);
        aD[fk] = __builtin_amdgcn_mfma_f32_16x16x32_bf16(dof[ks], lds16(&Vs[fk * 16 + lr][ks * 32 + lg * 8]), aD[fk], 0, 0, 0);
      }
    __builtin_amdgcn_s_setprio(0);
#pragma unroll
    for (int fk = 0; fk < 4; ++fk)
#pragma unroll
      for (int i = 0; i < 4; ++i) {
        float p = __expf(aS[fk][i] * SCALE_ - mrow[i]) * lrow[i];
        float ds = p * (aD[fk][i] - drow[i]);
        Ps[w][lg * 4 + i][fk * 16 + lr] = f2bf(ds);
      }
    __builtin_amdgcn_s_setprio(1);
#pragma unroll
    for (int ks = 0; ks < 2; ++ks) {
      bh8 ap = lds16(&Ps[w][lr][ks * 32 + lg * 8]);
#pragma unroll
      for (int fd = 0; fd < 4; ++fd)
        accQ[fd] = __builtin_amdgcn_mfma_f32_16x16x32_bf16(ap, lds16(&KT[fd * 16 + lr][ks * 32 + lg * 8]), accQ[fd], 0, 0, 0);
    }
    __builtin_amdgcn_s_setprio(0);
  }
#pragma unroll
  for (int i = 0; i < 4; ++i) {
    int q = q0 + lg * 4 + i;
    if (q < S_) {
      size_t obase = ((size_t)(b * S_ + q) * 24 + h) * 64;
      float c0 = Cs[q * 32 + lr], s0 = Sn[q * 32 + lr];
      float c1 = Cs[q * 32 + 16 + lr], s1 = Sn[q * 32 + 16 + lr];
#pragma unroll
      for (int fd = 0; fd < 4; ++fd) {
        float x = SCALE_ * accQ[fd][i];
        float p = SCALE_ * accQ[fd ^ 2][i];
        float cc = (fd & 1) ? c1 : c0;
        float ss = (fd & 1) ? s1 : s0;
        float out = (fd < 2) ? (x * cc + p * ss) : (x * cc - p * ss);
        dQKV[obase + fd * 16 + lr] = f2bf(out);
      }
    }
  }
}

// dK + dV pass, QBLK=128; dual P/D LDS buffers; T5 setprio
__global__ __launch_bounds__(512) void k_attn_bwd_kv3(const unsigned short* __restrict__ QKV,
                                                      const unsigned short* __restrict__ dO,
                                                      const float* __restrict__ MB,
                                                      const float* __restrict__ LB,
                                                      const float* __restrict__ DB,
                                                      const float* __restrict__ Cs,
                                                      const float* __restrict__ Sn,
                                                      unsigned short* __restrict__ dQKV) {
  __shared__ unsigned short Qs[64][PT_];
  __shared__ unsigned short dOs[64][PT_];
  __shared__ unsigned short QT[64][PT_];
  __shared__ unsigned short dOT[64][PT_];
  __shared__ unsigned short Ps[8][16][PT_];
  __shared__ unsigned short Ds[8][16][PT_];
  __shared__ float sM[64], sL[64], sD[64];
  int tid = threadIdx.x;
  int h = blockIdx.y, b = blockIdx.z;
  int w = tid >> 6, lane = tid & 63;
  int lr = lane & 15, lg = lane >> 4;
  int k0w = blockIdx.x * 128 + w * 16;
  size_t sbase = ((size_t)b * NH_ + h) * S_;
  bool kRole = tid < 256;
  int t2 = kRole ? tid : tid - 256;
  int sr = t2 >> 2, sc0 = (t2 & 3) * 16;
  int vd0 = (t2 & 15) * 4, vk0 = (t2 >> 4) * 4;

  bh8 kf[2], vf[2];
  {
    int kr = k0w + lr; if (kr >= S_) kr = S_ - 1;
    const unsigned short* kp = &QKV[((size_t)(b * S_ + kr) * 24 + 8 + h) * 64 + lg * 8];
    kf[0] = *(const bh8*)kp;        kf[1] = *(const bh8*)(kp + 32);
    vf[0] = *(const bh8*)(kp + 512); vf[1] = *(const bh8*)(kp + 544);
  }
  f32x4 accK[4] = {}, accV[4] = {};

  bfu pA{}, pB{}, pC{}, pD{};
  us4 rq[4], rd[4];
  float stM = 0.f, stL = 0.f, stD = 0.f;
  if (kRole) {
    int src = sr;
    bool vld = src < S_;
    size_t ts = (size_t)b * S_ + (vld ? src : S_ - 1);
    const unsigned short* qp = &QKV[(ts * 24 + h) * 64 + sc0];
    const unsigned short* dp = &dO[ts * H_ + h * 64 + sc0];
    pA.v = *(const bh8*)qp;
    pB.v = *(const bh8*)(qp + 8);
    if (vld) {
      pC.v = *(const bh8*)dp;
      pD.v = *(const bh8*)(dp + 8);
    }
    if (tid < 64) {
      bool v2 = tid < S_;
      int sc = v2 ? tid : S_ - 1;
      stM = MB[sbase + sc];
      stL = LB[sbase + sc];
      stD = v2 ? DB[sbase + sc] : 0.f;
    }
  } else {
#pragma unroll
    for (int j = 0; j < 4; ++j) {
      int s2 = vk0 + j;
      bool v2 = s2 < S_;
      size_t t3 = (size_t)b * S_ + (v2 ? s2 : S_ - 1);
      rq[j] = *(const us4*)&QKV[(t3 * 24 + h) * 64 + vd0];
      us4 td = *(const us4*)&dO[t3 * H_ + h * 64 + vd0];
      if (!v2) td = us4{0, 0, 0, 0};
      rd[j] = td;
    }
  }

  for (int qt = 0; qt < S_; qt += 64) {
    __syncthreads();
    if (kRole) {
      sts16(&Qs[sr][sc0], pA);  sts16(&Qs[sr][sc0 + 8], pB);
      sts16(&dOs[sr][sc0], pC); sts16(&dOs[sr][sc0 + 8], pD);
      if (tid < 64) {
        sM[tid] = stM;
        sL[tid] = stL;
        sD[tid] = stD;
      }
    } else {
#pragma unroll
      for (int dd = 0; dd < 4; ++dd) {
        us4 pq = {rq[0][dd], rq[1][dd], rq[2][dd], rq[3][dd]};
        us4 pd = {rd[0][dd], rd[1][dd], rd[2][dd], rd[3][dd]};
        *(us4*)&QT[vd0 + dd][vk0] = pq;
        *(us4*)&dOT[vd0 + dd][vk0] = pd;
      }
    }
    __syncthreads();
    if (qt + 64 < S_) {
      if (kRole) {
        int src = qt + 64 + sr;
        bool vld = src < S_;
        size_t ts = (size_t)b * S_ + (vld ? src : S_ - 1);
        const unsigned short* qp = &QKV[(ts * 24 + h) * 64 + sc0];
        const unsigned short* dp = &dO[ts * H_ + h * 64 + sc0];
        pA.v = *(const bh8*)qp;
        pB.v = *(const bh8*)(qp + 8);
        pC = bfu{}; pD = bfu{};
        if (vld) {
          pC.v = *(const bh8*)dp;
          pD.v = *(const bh8*)(dp + 8);
        }
        if (tid < 64) {
          int s2 = qt + 64 + tid;
          bool v2 = s2 < S_;
          int sc = v2 ? s2 : S_ - 1;
          stM = MB[sbase + sc];
          stL = LB[sbase + sc];
          stD = v2 ? DB[sbase + sc] : 0.f;
        }
      } else {
#pragma unroll
        for (int j = 0; j < 4; ++j) {
          int s2 = qt + 64 + vk0 + j;
          bool v2 = s2 < S_;
          size_t t3 = (size_t)b * S_ + (v2 ? s2 : S_ - 1);
          rq[j] = *(const us4*)&QKV[(t3 * 24 + h) * 64 + vd0];
          us4 td = *(const us4*)&dO[t3 * H_ + h * 64 + vd0];
          if (!v2) td = us4{0, 0, 0, 0};
          rd[j] = td;
        }
      }
    }
    f32x4 aS[4] = {}, aD[4] = {};
    __builtin_amdgcn_s_setprio(1);
#pragma unroll
    for (int ks = 0; ks < 2; ++ks)
#pragma unroll
      for (int fq = 0; fq < 4; ++fq) {
        aS[fq] = __builtin_amdgcn_mfma_f32_16x16x32_bf16(kf[ks], lds16(&Qs[fq * 16 + lr][ks * 32 + lg * 8]), aS[fq], 0, 0, 0);
        aD[fq] = __builtin_amdgcn_mfma_f32_16x16x32_bf16(vf[ks], lds16(&dOs[fq * 16 + lr][ks * 32 + lg * 8]), aD[fq], 0, 0, 0);
      }
    __builtin_amdgcn_s_setprio(0);
    // write BOTH P^T and dS^T, then run both MFMA clusters back-to-back
#pragma unroll
    for (int fq = 0; fq < 4; ++fq) {
      float mq = sM[fq * 16 + lr], lq = sL[fq * 16 + lr], dq = sD[fq * 16 + lr];
#pragma unroll
      for (int i = 0; i < 4; ++i) {
        float p = __expf(aS[fq][i] * SCALE_ - mq) * lq;
        Ps[w][lg * 4 + i][fq * 16 + lr] = f2bf(p);
        Ds[w][lg * 4 + i][fq * 16 + lr] = f2bf(p * (aD[fq][i] - dq));
      }
    }
    __builtin_amdgcn_s_setprio(1);
#pragma unroll
    for (int qs = 0; qs < 2; ++qs) {
      bh8 ap = lds16(&Ps[w][lr][qs * 32 + lg * 8]);
      bh8 ad = lds16(&Ds[w][lr][qs * 32 + lg * 8]);
#pragma unroll
      for (int fd = 0; fd < 4; ++fd) {
        accV[fd] = __builtin_amdgcn_mfma_f32_16x16x32_bf16(ap, lds16(&dOT[fd * 16 + lr][qs * 32 + lg * 8]), accV[fd], 0, 0, 0);
        accK[fd] = __builtin_amdgcn_mfma_f32_16x16x32_bf16(ad, lds16(&QT[fd * 16 + lr][qs * 32 + lg * 8]), accK[fd], 0, 0, 0);
      }
    }
    __builtin_amdgcn_s_setprio(0);
  }
#pragma unroll
  for (int i = 0; i < 4; ++i) {
    int k = k0w + lg * 4 + i;
    if (k < S_) {
      size_t obase = ((size_t)(b * S_ + k) * 24 + 8 + h) * 64;
      float c0 = Cs[k * 32 + lr], s0 = Sn[k * 32 + lr];
      float c1 = Cs[k * 32 + 16 + lr], s1 = Sn[k * 32 + 16 + lr];
#pragma unroll
      for (int fd = 0; fd < 4; ++fd) {
        float x = SCALE_ * accK[fd][i];
        float p = SCALE_ * accK[fd ^ 2][i];
        float cc = (fd & 1) ? c1 : c0;
        float ss = (fd & 1) ? s1 : s0;
        float out = (fd < 2) ? (x * cc + p * ss) : (x * cc - p * ss);
        dQKV[obase + fd * 16 + lr] = f2bf(out);
        dQKV[obase + 512 + fd * 16 + lr] = f2bf(accV[fd][i]);
      }
    }
  }
}

// ---------------- RMS norm fwd/bwd (dual fp32+bf16 outputs) ----------------

__global__ __launch_bounds__(256) void k_rms_fwd(const float* __restrict__ X, float* __restrict__ Y,
                                                 unsigned short* __restrict__ Y16) {
  int t = blockIdx.x, tid = threadIdx.x;
  float x0 = X[(size_t)t * H_ + tid], x1 = X[(size_t)t * H_ + tid + 256];
  __shared__ float red[256];
  red[tid] = x0 * x0 + x1 * x1;
  __syncthreads();
  for (int s = 128; s > 0; s >>= 1) {
    if (tid < s) red[tid] += red[tid + s];
    __syncthreads();
  }
  float r = rsqrtf(red[0] / H_ + EPS_);
  float y0 = x0 * r, y1 = x1 * r;
  Y[(size_t)t * H_ + tid] = y0;
  Y[(size_t)t * H_ + tid + 256] = y1;
  Y16[(size_t)t * H_ + tid] = f2bf(y0);
  Y16[(size_t)t * H_ + tid + 256] = f2bf(y1);
}

// EWB: incoming gradient is the broadcast energy vector ew[col] (topmost layer)
template <int EWB>
__global__ __launch_bounds__(256) void k_rms_bwd(const float* __restrict__ X,
                                                 const float* __restrict__ GY,
                                                 const float* __restrict__ EW,
                                                 float* __restrict__ GX,
                                                 unsigned short* __restrict__ GX16) {
  int t = blockIdx.x, tid = threadIdx.x;
  float x0 = X[(size_t)t * H_ + tid], x1 = X[(size_t)t * H_ + tid + 256];
  float g0, g1;
  if (EWB) {
    g0 = EW[tid];
    g1 = EW[tid + 256];
  } else {
    g0 = GY[(size_t)t * H_ + tid];
    g1 = GY[(size_t)t * H_ + tid + 256];
  }
  __shared__ float r1[256], r2[256];
  r1[tid] = x0 * x0 + x1 * x1;
  r2[tid] = x0 * g0 + x1 * g1;
  __syncthreads();
  for (int s = 128; s > 0; s >>= 1) {
    if (tid < s) { r1[tid] += r1[tid + s]; r2[tid] += r2[tid + s]; }
    __syncthreads();
  }
  float r = rsqrtf(r1[0] / H_ + EPS_);
  float coef = r * r * r * r2[0] / (float)H_;
  float o0 = r * g0 - coef * x0, o1 = r * g1 - coef * x1;
  GX[(size_t)t * H_ + tid] = o0;
  GX[(size_t)t * H_ + tid + 256] = o1;
  GX16[(size_t)t * H_ + tid] = f2bf(o0);
  GX16[(size_t)t * H_ + tid + 256] = f2bf(o1);
}

// ---------------- logits update ----------------

__global__ __launch_bounds__(64) void k_logits_update(const float* __restrict__ G,
                                                      const float* __restrict__ E,
                                                      const float* __restrict__ P,
                                                      const float* __restrict__ alpha,
                                                      float* __restrict__ logits) {
  int t = blockIdx.x, lane = threadIdx.x;
  float dp[V_];
#pragma unroll
  for (int v = 0; v < V_; ++v) dp[v] = 0.f;
  for (int hh = lane; hh < H_; hh += 64) {
    float gh = G[(size_t)t * H_ + hh];
#pragma unroll
    for (int v = 0; v < V_; ++v) dp[v] += gh * E[v * H_ + hh];
  }
#pragma unroll
  for (int v = 0; v < V_; ++v) dp[v] = wave_sum64(dp[v]) * ESCALE_;
  float dot = 0.f;
  float pv[V_];
#pragma unroll
  for (int v = 0; v < V_; ++v) {
    pv[v] = P[t * V_ + v];
    dot += pv[v] * dp[v];
  }
  float a = fmaxf(alpha[0], 1e-4f);
  if (lane < V_) logits[t * V_ + lane] -= a * pv[lane] * (dp[lane] - dot);
}

// ---------------- host-side orchestration ----------------

struct Ctx {
  unsigned short *Q16, *Q016, *dQ16, *GU16, *DO16, *AO16, *AO016, *X116, *UDX16, *U016;
  float *X1, *X2, *X20, *G, *UDX, *P, *MB, *LB, *DB, *MB0, *LB0, *CS, *SN;
  const float* EW;
  const unsigned short *WTqkv[2], *WTo[2], *WTgu[2], *WTd[2];
  const unsigned short *WSqkv[2], *WSo[2], *WSgu[2], *WSd[2];
  hipStream_t st;
};

static void block_forward(Ctx& c, int l, const float* hin, const unsigned short* hin16,
                          float* hout, unsigned short* qb, unsigned short* ao,
                          float* mb, float* lb, float* x2buf, unsigned short* u16buf) {
  k_gemm<128, 0, 0, 1, 1, 0><<<dim3(3 * H_ / 128, (NTOK + 127) / 128), 256, 0, c.st>>>(
      hin16, c.WTqkv[l], nullptr, nullptr, qb, nullptr, c.CS, c.SN, NTOK, 3 * H_, H_, H_);
  k_attn_fwd3<<<dim3((S_ + 127) / 128, NH_, B_), 512, 0, c.st>>>(qb, ao, mb, lb);
  k_gemm<64, 0, 1, 0, 0, 0><<<dim3(H_ / 128, (NTOK + 63) / 64), 256, 0, c.st>>>(
      ao, c.WTo[l], hin, c.X1, nullptr, nullptr, nullptr, nullptr, NTOK, H_, H_, H_);
  k_rms_fwd<<<NTOK, 256, 0, c.st>>>(c.X1, c.UDX, u16buf);
  k_gemm<128, 0, 0, 1, 0, 0><<<dim3(2 * INNER_ / 128, (NTOK + 127) / 128), 256, 0, c.st>>>(
      u16buf, c.WTgu[l], nullptr, nullptr, c.GU16, nullptr, nullptr, nullptr, NTOK, 2 * INNER_, H_, H_);
  k_gemm<64, 1, 1, 0, 0, 0><<<dim3(H_ / 128, (NTOK + 63) / 64), 256, 0, c.st>>>(
      c.GU16, c.WTd[l], c.UDX, x2buf, nullptr, nullptr, nullptr, nullptr, NTOK, H_, INNER_, 2 * INNER_);
  if (hout) k_rms_fwd<<<NTOK, 256, 0, c.st>>>(x2buf, hout, c.UDX16);
}

static void block_backward(Ctx& c, int l, const float* hin, const unsigned short* hin16,
                           unsigned short* qb, unsigned short* ao, float* mb, float* lb,
                           bool full) {
  const float* x2src;
  if (full) {
    block_forward(c, l, hin, hin16, nullptr, qb, ao, mb, lb, c.X2, c.UDX16);
    x2src = c.X2;
  } else {
    k_gemm<64, 0, 1, 0, 0, 0><<<dim3(H_ / 128, (NTOK + 63) / 64), 256, 0, c.st>>>(
        ao, c.WTo[l], hin, c.X1, nullptr, nullptr, nullptr, nullptr, NTOK, H_, H_, H_);
    k_gemm<128, 0, 0, 1, 0, 0><<<dim3(2 * INNER_ / 128, (NTOK + 127) / 128), 256, 0, c.st>>>(
        c.U016, c.WTgu[l], nullptr, nullptr, c.GU16, nullptr, nullptr, nullptr, NTOK, 2 * INNER_, H_, H_);
    x2src = c.X20;
  }
  if (full)
    k_rms_bwd<1><<<NTOK, 256, 0, c.st>>>(x2src, nullptr, c.EW, c.UDX, c.UDX16);
  else
    k_rms_bwd<0><<<NTOK, 256, 0, c.st>>>(x2src, c.G, nullptr, c.UDX, c.UDX16);
  k_gemm<128, 0, 0, 0, 0, 1><<<dim3(INNER_ / 128, (NTOK + 127) / 128), 256, 0, c.st>>>(
      c.UDX16, c.WSd[l], nullptr, nullptr, nullptr, c.GU16, nullptr, nullptr, NTOK, INNER_, H_, H_);
  k_gemm<64, 0, 1, 0, 0, 0><<<dim3(H_ / 128, (NTOK + 63) / 64), 256, 0, c.st>>>(
      c.GU16, c.WSgu[l], c.UDX, c.G, nullptr, nullptr, nullptr, nullptr, NTOK, H_, 2 * INNER_, 2 * INNER_);
  k_rms_bwd<0><<<NTOK, 256, 0, c.st>>>(c.X1, c.G, nullptr, c.UDX, c.UDX16);
  k_gemm<64, 0, 0, 1, 0, 0><<<dim3(H_ / 128, (NTOK + 63) / 64), 256, 0, c.st>>>(
      c.UDX16, c.WSo[l], nullptr, nullptr, c.DO16, nullptr, nullptr, nullptr, NTOK, H_, H_, H_);
  dim3 agrid128((S_ + 127) / 128, NH_, B_);
  k_attn_bwd_dq3<<<agrid128, 512, 0, c.st>>>(qb, ao, c.DO16, mb, lb, c.DB, c.CS, c.SN, c.dQ16);
  k_attn_bwd_kv3<<<agrid128, 512, 0, c.st>>>(qb, c.DO16, mb, lb, c.DB, c.CS, c.SN, c.dQ16);
  k_gemm<64, 0, 1, 0, 0, 0><<<dim3(H_ / 128, (NTOK + 63) / 64), 256, 0, c.st>>>(
      c.dQ16, c.WSqkv[l], c.UDX, c.G, nullptr, nullptr, nullptr, nullptr, NTOK, H_, 3 * H_, 3 * H_);
}

extern "C" void kernel_launch(void* const* d_in, const int* in_sizes, int n_in,
                              void* d_out, int out_size, void* d_ws, size_t ws_size,
                              hipStream_t stream) {
  const int* inputs = (const int*)d_in[0];
  const float* E = (const float*)d_in[2];
  const float* ew = (const float*)d_in[3];
  const float* qkvw = (const float*)d_in[4];
  const float* ow = (const float*)d_in[5];
  const float* guw = (const float*)d_in[6];
  const float* dw = (const float*)d_in[7];
  const float* alpha = (const float*)d_in[8];
  float* logits = (float*)d_out;

  const size_t WT_FLOATS = 3407872;
  const size_t NEED =
      3 * ((size_t)NTOK * 3 * H_ / 2) +
      ((size_t)NTOK * INNER_) +
      5 * ((size_t)NTOK * H_) +
      6 * ((size_t)NTOK * H_ / 2) +
      ((size_t)NTOK * V_) +
      5 * ((size_t)B_ * NH_ * S_) +
      2 * ((size_t)S_ * 32) +
      2 * WT_FLOATS;
  if (ws_size < NEED * sizeof(float)) {
    k_zero<<<(NTOK * V_ + 255) / 256, 256, 0, stream>>>(logits, NTOK * V_);
    return;
  }

  float* f = (float*)d_ws;
  Ctx c;
  c.st = stream;
  c.EW = ew;
  c.Q16 = (unsigned short*)f;  f += (size_t)NTOK * 3 * H_ / 2;
  c.Q016 = (unsigned short*)f; f += (size_t)NTOK * 3 * H_ / 2;
  c.dQ16 = (unsigned short*)f; f += (size_t)NTOK * 3 * H_ / 2;
  c.GU16 = (unsigned short*)f; f += (size_t)NTOK * INNER_;
  c.X1 = f;   f += (size_t)NTOK * H_;
  c.X2 = f;   f += (size_t)NTOK * H_;
  c.X20 = f;  f += (size_t)NTOK * H_;
  c.G = f;    f += (size_t)NTOK * H_;
  c.UDX = f;  f += (size_t)NTOK * H_;
  c.AO16 = (unsigned short*)f;  f += (size_t)NTOK * H_ / 2;
  c.AO016 = (unsigned short*)f; f += (size_t)NTOK * H_ / 2;
  c.DO16 = (unsigned short*)f;  f += (size_t)NTOK * H_ / 2;
  c.X116 = (unsigned short*)f;  f += (size_t)NTOK * H_ / 2;
  c.UDX16 = (unsigned short*)f; f += (size_t)NTOK * H_ / 2;
  c.U016 = (unsigned short*)f;  f += (size_t)NTOK * H_ / 2;
  c.P = f;    f += (size_t)NTOK * V_;
  c.MB = f;   f += (size_t)B_ * NH_ * S_;
  c.LB = f;   f += (size_t)B_ * NH_ * S_;
  c.DB = f;   f += (size_t)B_ * NH_ * S_;
  c.MB0 = f;  f += (size_t)B_ * NH_ * S_;
  c.LB0 = f;  f += (size_t)B_ * NH_ * S_;
  c.CS = f;   f += (size_t)S_ * 32;
  c.SN = f;   f += (size_t)S_ * 32;
  unsigned short* wt = (unsigned short*)f;

  const size_t LQKV = (size_t)H_ * 3 * H_;
  const size_t LO = (size_t)H_ * H_;
  const size_t LGU = (size_t)H_ * 2 * INNER_;
  const size_t LD = (size_t)INNER_ * H_;

  for (int l = 0; l < 2; ++l) {
    c.WTqkv[l] = wt;
    k_wt<<<dim3(3 * H_ / 32, H_ / 32), dim3(32, 8), 0, stream>>>(qkvw + l * LQKV, wt, H_, 3 * H_);
    wt += LQKV;
    c.WTo[l] = wt;
    k_wt<<<dim3(H_ / 32, H_ / 32), dim3(32, 8), 0, stream>>>(ow + l * LO, wt, H_, H_);
    wt += LO;
    c.WTgu[l] = wt;
    k_wt<<<dim3(2 * INNER_ / 32, H_ / 32), dim3(32, 8), 0, stream>>>(guw + l * LGU, wt, H_, 2 * INNER_);
    wt += LGU;
    c.WTd[l] = wt;
    k_wt<<<dim3(H_ / 32, INNER_ / 32), dim3(32, 8), 0, stream>>>(dw + l * LD, wt, INNER_, H_);
    wt += LD;
  }
  {
    unsigned short* ws = wt;
    k_cast8<<<(int)((2 * LQKV / 8 + 255) / 256), 256, 0, stream>>>(qkvw, ws, (int)(2 * LQKV / 8));
    c.WSqkv[0] = ws; c.WSqkv[1] = ws + LQKV; ws += 2 * LQKV;
    k_cast8<<<(int)((2 * LO / 8 + 255) / 256), 256, 0, stream>>>(ow, ws, (int)(2 * LO / 8));
    c.WSo[0] = ws; c.WSo[1] = ws + LO; ws += 2 * LO;
    k_cast8<<<(int)((2 * LGU / 8 + 255) / 256), 256, 0, stream>>>(guw, ws, (int)(2 * LGU / 8));
    c.WSgu[0] = ws; c.WSgu[1] = ws + LGU; ws += 2 * LGU;
    k_cast8<<<(int)((2 * LD / 8 + 255) / 256), 256, 0, stream>>>(dw, ws, (int)(2 * LD / 8));
    c.WSd[0] = ws; c.WSd[1] = ws + LD;
  }

  k_zero<<<(NTOK * V_ + 255) / 256, 256, 0, stream>>>(logits, NTOK * V_);
  k_rope_tables<<<(S_ * 32 + 255) / 256, 256, 0, stream>>>(c.CS, c.SN);

  for (int step = 0; step < STEPS_; ++step) {
    k_h0<1><<<NTOK, 256, 0, stream>>>(logits, c.P, E, inputs, c.X1, c.X116);
    block_forward(c, 0, c.X1, c.X116, c.UDX, c.Q016, c.AO016, c.MB0, c.LB0, c.X20, c.U016);
    block_backward(c, 1, c.UDX, c.UDX16, c.Q16, c.AO16, c.MB, c.LB, true);
    k_h0<0><<<NTOK, 256, 0, stream>>>(nullptr, c.P, E, inputs, c.X1, c.X116);
    block_backward(c, 0, c.X1, c.X116, c.Q016, c.AO016, c.MB0, c.LB0, false);
    k_logits_update<<<NTOK, 64, 0, stream>>>(c.G, E, c.P, alpha, logits);
  }
}